// Round 7
// baseline (601.781 us; speedup 1.0000x reference)
//
#include <hip/hip_runtime.h>
#include <hip/hip_bf16.h>

// ---------------------------------------------------------------------------
// PDNConv GNN, MI355X round 24.
// Round-23 post-mortem: three aggregate structures all neutral -> aggregate is
// gather-traffic-bound, not occupancy/ILP-bound. Round-24 bundle:
// (1) edge_mlp rolling prefetch depth 1 -> 2 (r20 structure kept; r21 proved
//     batching is bad, not depth). Halves exposed HBM latency per fragment.
// (2) DELETE csr_gather + csr_scale kernels: aggregate gathers
//     w_all4[eid]*dinv4[src] on the fly (small L2-resident tables); deg reads
//     gates via csr_se[k].y. csr_val never materialized (-2 dispatches,
//     -38MB x2 of plane traffic).
// Aggregate keeps the r23 shfl-broadcast structure (4 nodes/block).
// ---------------------------------------------------------------------------

#define NN 50000
#define EE 600000
#define GG 256
#define HID 128
#define EDIM 16
#define EHID 64
#define NL 4
#define MIN_F 200
#define MH 256
#define MOUT 128
#define PH 512
#define PIN 256
#define SCAN_B 196  // ceil(NN/256)
#define PCH 8       // pooling chunks per graph
#define EMB 128     // edges per block (edge_mlp)

typedef __hip_bfloat16 bf16;
typedef __attribute__((ext_vector_type(8))) short bf16x8;
typedef __attribute__((ext_vector_type(4))) float f32x4;

__device__ __forceinline__ float bfl(unsigned u) { return __uint_as_float(u << 16); }
__device__ __forceinline__ float bfh(unsigned u) { return __uint_as_float(u & 0xffff0000u); }
__device__ __forceinline__ float b2f(bf16 x) { return __bfloat162float(x); }
__device__ __forceinline__ float ldf(const void* p, long i, bool bf) {
  return bf ? __bfloat162float(((const bf16*)p)[i]) : ((const float*)p)[i];
}
__device__ __forceinline__ unsigned short f2bf_bits(float v) {
  bf16 h = __float2bfloat16(v);
  return *reinterpret_cast<unsigned short*>(&h);
}

// ---------------- dtype probe ------------------------------------------------
__global__ void probe_kernel(const unsigned short* __restrict__ xs, int* flag) {
  if (threadIdx.x == 0 && blockIdx.x == 0) {
    int sane = 0;
    for (int i = 0; i < 128; i++) {
      unsigned e = (xs[i] >> 7) & 0xFF;
      if (e >= 96 && e <= 159) sane++;
    }
    *flag = (sane >= 112) ? 1 : 0;  // 1 = bf16 inputs
  }
}

// ---------------- input -> bf16 conversion (8 elems/thread) -----------------
__global__ __launch_bounds__(256) void cvt_to_bf16(const void* __restrict__ in,
                                                   unsigned short* __restrict__ outp,
                                                   int n8, const int* __restrict__ flag) {
  bool bf = *flag != 0;
  int i = blockIdx.x * 256 + threadIdx.x;
  if (i >= n8) return;
  if (bf) {
    reinterpret_cast<uint4*>(outp)[i] = reinterpret_cast<const uint4*>(in)[i];
  } else {
    const float4* p = reinterpret_cast<const float4*>(in) + (size_t)i * 2;
    float4 v0 = p[0], v1 = p[1];
    ushort4 a, b;
    a.x = f2bf_bits(v0.x); a.y = f2bf_bits(v0.y);
    a.z = f2bf_bits(v0.z); a.w = f2bf_bits(v0.w);
    b.x = f2bf_bits(v1.x); b.y = f2bf_bits(v1.y);
    b.z = f2bf_bits(v1.z); b.w = f2bf_bits(v1.w);
    reinterpret_cast<ushort4*>(outp)[i * 2] = a;
    reinterpret_cast<ushort4*>(outp)[i * 2 + 1] = b;
  }
}

// ---------------- mol_features [G,200] -> padded f32 [G,256] ----------------
__global__ __launch_bounds__(256) void cvt_molf(const void* __restrict__ in,
                                                float* __restrict__ outp,
                                                const int* __restrict__ flag) {
  bool bf = *flag != 0;
  int i = blockIdx.x * 256 + threadIdx.x;  // GG*50
  if (i >= GG * 50) return;
  int row = i / 50, c4 = (i % 50) * 4;
  float4 v;
  if (bf) {
    const unsigned short* p = (const unsigned short*)in + (size_t)row * MIN_F + c4;
    uint2 u = *reinterpret_cast<const uint2*>(p);
    v.x = bfl(u.x); v.y = bfh(u.x); v.z = bfl(u.y); v.w = bfh(u.y);
  } else {
    v = *reinterpret_cast<const float4*>((const float*)in + (size_t)row * MIN_F + c4);
  }
  *reinterpret_cast<float4*>(&outp[(size_t)row * 256 + c4]) = v;
}

// ---------------- weight prep: fused W'_l = linW_l @ gW_l -> bf16 [n][k] ----
__global__ __launch_bounds__(256) void prep_fused_w(const void* __restrict__ lin_W,
                                                    const void* __restrict__ gW,
                                                    unsigned short* __restrict__ Wt,
                                                    const int* __restrict__ flag) {
  bool bf = *flag != 0;
  int idx = blockIdx.x * 256 + threadIdx.x;  // 0 .. 4*16384-1
  if (idx >= 4 * 16384) return;
  int l = idx >> 14;
  int rem = idx & 16383;
  int n = rem >> 7, k = rem & 127;  // Wt[n][k] = W'[k][n]
  float s = 0.f;
  long lb = (long)l * 16384;
  for (int m = 0; m < 128; m++)
    s += ldf(lin_W, lb + (long)k * 128 + m, bf) * ldf(gW, lb + (long)m * 128 + n, bf);
  Wt[idx] = f2bf_bits(s);
}

// b'_l[n] = gb_l[n] + sum_k cbias_l[k] * gW_l[k][n]   (f32)
__global__ __launch_bounds__(128) void prep_fused_b(const void* __restrict__ cbias,
                                                    const void* __restrict__ gW,
                                                    const void* __restrict__ gb,
                                                    float* __restrict__ bprime,
                                                    const int* __restrict__ flag) {
  bool bf = *flag != 0;
  int idx = blockIdx.x * 128 + threadIdx.x;  // 0 .. 4*128-1
  if (idx >= NL * HID) return;
  int l = idx >> 7, n = idx & 127;
  float s = ldf(gb, idx, bf);
  long lb = (long)l * 16384;
  for (int k = 0; k < 128; k++)
    s += ldf(cbias, (long)l * 128 + k, bf) * ldf(gW, lb + (long)k * 128 + n, bf);
  bprime[idx] = s;
}

// ---------------- weight prep: edge MLP W1 -> bf16 W1t[256 cols][32 K] ------
// k<16: W1; k==16: b1 (MFMA bias-fold); k>16: 0.
__global__ __launch_bounds__(256) void prep_edge_w(const void* __restrict__ mW1,
                                                   const void* __restrict__ mb1,
                                                   unsigned short* __restrict__ W1t,
                                                   const int* __restrict__ flag) {
  bool bf = *flag != 0;
  int idx = blockIdx.x * 256 + threadIdx.x;  // 256*32
  if (idx >= 256 * 32) return;
  int col = idx >> 5, k = idx & 31;
  float v = 0.f;
  if (k < EDIM) v = ldf(mW1, (long)(col >> 6) * (EDIM * EHID) + (long)k * EHID + (col & 63), bf);
  else if (k == EDIM) v = ldf(mb1, col, bf);
  W1t[idx] = f2bf_bits(v);
}

// ---------------- weight prep: tail (MLP+predictor) -> bf16 [N][Kp], K-pad --
__global__ __launch_bounds__(256) void prep_tail(
    const void* __restrict__ mlpW0, const void* __restrict__ mlpW1,
    const void* __restrict__ mlpW2, const void* __restrict__ mlpW3,
    const void* __restrict__ predW0, const void* __restrict__ predW1,
    unsigned short* __restrict__ T, const int* __restrict__ flag) {
  bool bf = *flag != 0;
  int idx = blockIdx.x * 256 + threadIdx.x;
  const void* src; int N, Kp, Ksrc, off;
  if      (idx < 65536)  { src = mlpW0;  N = 256; Kp = 256; Ksrc = 200; off = 0; }
  else if (idx < 131072) { src = mlpW1;  N = 256; Kp = 256; Ksrc = 256; off = 65536; }
  else if (idx < 196608) { src = mlpW2;  N = 256; Kp = 256; Ksrc = 256; off = 131072; }
  else if (idx < 229376) { src = mlpW3;  N = 128; Kp = 256; Ksrc = 256; off = 196608; }
  else if (idx < 360448) { src = predW0; N = 512; Kp = 256; Ksrc = 256; off = 229376; }
  else if (idx < 622592) { src = predW1; N = 512; Kp = 512; Ksrc = 512; off = 360448; }
  else return;
  int rem = idx - off;
  int n = rem / Kp, k = rem % Kp;
  float v = (k < Ksrc) ? ldf(src, (long)k * N + n, bf) : 0.f;
  T[idx] = f2bf_bits(v);
}

// ---------------- CSR build: histogram / 3-phase scan / fill ----------------
__global__ __launch_bounds__(256) void count_kernel(const int* __restrict__ ei,
                                                    int* __restrict__ cnt) {
  int e = blockIdx.x * 256 + threadIdx.x;
  if (e >= EE) return;
  int c = ei[EE + e];
  c = min(max(c, 0), NN - 1);
  atomicAdd(&cnt[c], 1);
}

__global__ __launch_bounds__(256) void scan_phase1(const int* __restrict__ cnt,
                                                   int* __restrict__ bsum) {
  __shared__ int red[256];
  int tid = threadIdx.x;
  int i = blockIdx.x * 256 + tid;
  red[tid] = (i < NN) ? cnt[i] : 0;
  __syncthreads();
  for (int off = 128; off > 0; off >>= 1) {
    if (tid < off) red[tid] += red[tid + off];
    __syncthreads();
  }
  if (tid == 0) bsum[blockIdx.x] = red[0];
}

__global__ __launch_bounds__(256) void scan_phase2(int* __restrict__ bsum,
                                                   int* __restrict__ offs) {
  __shared__ int buf[256];
  int tid = threadIdx.x;
  int v = (tid < SCAN_B) ? bsum[tid] : 0;
  buf[tid] = v;
  __syncthreads();
  for (int off = 1; off < 256; off <<= 1) {
    int t = (tid >= off) ? buf[tid - off] : 0;
    __syncthreads();
    buf[tid] += t;
    __syncthreads();
  }
  if (tid < SCAN_B) bsum[tid] = buf[tid] - v;  // exclusive block offsets
  if (tid == 255) offs[NN] = buf[255];
}

__global__ __launch_bounds__(256) void scan_phase3(const int* __restrict__ cnt,
                                                   const int* __restrict__ bsum,
                                                   int* __restrict__ offs) {
  __shared__ int buf[256];
  int tid = threadIdx.x;
  int i = blockIdx.x * 256 + tid;
  int v = (i < NN) ? cnt[i] : 0;
  buf[tid] = v;
  __syncthreads();
  for (int off = 1; off < 256; off <<= 1) {
    int t = (tid >= off) ? buf[tid - off] : 0;
    __syncthreads();
    buf[tid] += t;
    __syncthreads();
  }
  if (i < NN) offs[i] = bsum[blockIdx.x] + buf[tid] - v;
}

__global__ __launch_bounds__(256) void fill_kernel(const int* __restrict__ ei,
                                                   const int* __restrict__ offs,
                                                   int* __restrict__ cursor,
                                                   int2* __restrict__ csr_se) {
  int e = blockIdx.x * 256 + threadIdx.x;
  if (e >= EE) return;
  int c = ei[EE + e];
  c = min(max(c, 0), NN - 1);
  int pos = offs[c] + atomicAdd(&cursor[c], 1);
  pos = min(max(pos, 0), EE - 1);
  csr_se[pos] = make_int2(ei[e], e);
}

// ---------------- edge-gate MLP via MFMA: rolling prefetch depth 2 ----------
// r20 structure (swapped operands, 128 e/blk) with TWO fragments in flight.
__global__ __launch_bounds__(256) void edge_mlp_mfma(
    const void* __restrict__ eattr, const unsigned short* __restrict__ W1t,
    const void* __restrict__ mW2, const void* __restrict__ mb2,
    float* __restrict__ w_all4, const int* __restrict__ flag) {
  bool bf = *flag != 0;
  int tid = threadIdx.x;
  int wave = tid >> 6, lane = tid & 63;  // wave == layer index
  int l15 = lane & 15, quad = lane >> 4;

  // A-fragments: lane l15 = hidden row (T*16+l15) of this layer's W1^T,
  // k = quad*8..+7 (k=16 holds b1, k>16 zero).
  bf16x8 afrag[4];
#pragma unroll
  for (int t = 0; t < 4; t++)
    afrag[t] =
        *reinterpret_cast<const bf16x8*>(&W1t[((wave * 4 + t) * 16 + l15) * 32 + quad * 8]);

  // w2 per-lane: hidden h = T*16 + quad*4 + r within this layer's 64
  float w2v[16];
#pragma unroll
  for (int t = 0; t < 4; t++)
#pragma unroll
    for (int r = 0; r < 4; r++)
      w2v[t * 4 + r] = ldf(mW2, wave * 64 + t * 16 + quad * 4 + r, bf);
  float b2 = ldf(mb2, wave, bf);

  // constant part of the eattr^T B-fragment (bias lane / zero lanes)
  bf16x8 bconst = (bf16x8){0, 0, 0, 0, 0, 0, 0, 0};
  if (quad == 2) bconst[0] = (short)0x3F80;  // k=16 element = bf16(1.0)

  int ebase = blockIdx.x * EMB;
  int rowbytes = bf ? EDIM * 2 : EDIM * 4;
  const char* p = (const char*)eattr + (size_t)(ebase + l15) * rowbytes +
                  (size_t)quad * (rowbytes >> 1);
  int fragstep = 16 * rowbytes;

  auto loadb = [&](int fb, const char* pp) -> bf16x8 {
    bf16x8 v = bconst;
    if (quad < 2 && fb < EE) {
      if (bf) {
        v = *reinterpret_cast<const bf16x8*>(pp);
      } else {
        const float4* q = reinterpret_cast<const float4*>(pp);
        float4 v0 = q[0], v1 = q[1];
        v[0] = (short)f2bf_bits(v0.x); v[1] = (short)f2bf_bits(v0.y);
        v[2] = (short)f2bf_bits(v0.z); v[3] = (short)f2bf_bits(v0.w);
        v[4] = (short)f2bf_bits(v1.x); v[5] = (short)f2bf_bits(v1.y);
        v[6] = (short)f2bf_bits(v1.z); v[7] = (short)f2bf_bits(v1.w);
      }
    }
    return v;
  };

  bf16x8 bcur = loadb(ebase, p);
  bf16x8 bnx = loadb(ebase + 16, p + fragstep);
#pragma unroll 2
  for (int f = 0; f < EMB / 16; f++) {
    int fbase = ebase + f * 16;
    bf16x8 b2f_ = loadb(fbase + 32, p + 2 * fragstep);  // prefetch depth 2
    if (fbase < EE) {
      float s0 = 0.f, s1 = 0.f, s2 = 0.f, s3 = 0.f;
#define DO_T(T, S)                                                            \
  {                                                                           \
    f32x4 acc = __builtin_amdgcn_mfma_f32_16x16x32_bf16(                      \
        afrag[T], bcur, (f32x4){0.f, 0.f, 0.f, 0.f}, 0, 0, 0);                \
    S = fmaf(fmaxf(acc.x, 0.f), w2v[T * 4 + 0], S);                           \
    S = fmaf(fmaxf(acc.y, 0.f), w2v[T * 4 + 1], S);                           \
    S = fmaf(fmaxf(acc.z, 0.f), w2v[T * 4 + 2], S);                           \
    S = fmaf(fmaxf(acc.w, 0.f), w2v[T * 4 + 3], S);                           \
  }
      DO_T(0, s0) DO_T(1, s1) DO_T(2, s2) DO_T(3, s3)
#undef DO_T
      float s = (s0 + s1) + (s2 + s3);
      s += __shfl_xor(s, 16);  // combine quads 0<->1, 2<->3
      s += __shfl_xor(s, 32);  // combine halves
      if (quad == 0) {
        float g = 1.f / (1.f + __expf(-(s + b2)));
        w_all4[(size_t)(fbase + l15) * 4 + wave] = g;
      }
    }
    bcur = bnx;
    bnx = b2f_;
    p += fragstep;
  }
}

// ---------------- degree / dinv per layer (gates via csr_se.y) --------------
__global__ __launch_bounds__(256) void deg_kernel(const int* __restrict__ offs,
                                                  const int2* __restrict__ csr_se,
                                                  const float* __restrict__ w_all4,
                                                  float* __restrict__ dinv4) {
  int n = blockIdx.x * 256 + threadIdx.x;
  if (n >= NN) return;
  int s = offs[n], e = offs[n + 1];
  float d0 = 1.f, d1 = 1.f, d2 = 1.f, d3 = 1.f;  // self-loop weight 1.0
  for (int k = s; k < e; k++) {
    int eid = min(max(csr_se[k].y, 0), EE - 1);
    float4 w = reinterpret_cast<const float4*>(w_all4)[eid];
    d0 += w.x; d1 += w.y; d2 += w.z; d3 += w.w;
  }
  float4 o;
  o.x = rsqrtf(d0); o.y = rsqrtf(d1); o.z = rsqrtf(d2); o.w = rsqrtf(d3);
  reinterpret_cast<float4*>(dinv4)[n] = o;
}

// ---------------- node GEMM via MFMA: bf16 in/out, f32 bias -----------------
__global__ __launch_bounds__(256) void gemm_nodes_bf16(
    const unsigned short* __restrict__ A16, const unsigned short* __restrict__ Wt,
    const float* __restrict__ bias, unsigned short* __restrict__ out16,
    int relu) {
  __shared__ alignas(16) unsigned short sA[64 * 136];
  __shared__ alignas(16) unsigned short sW[128 * 136];
  int tid = threadIdx.x;
  int rbase = blockIdx.x * 64;

#pragma unroll
  for (int p = 0; p < 8; p++) {
    int idx8 = p * 256 + tid;
    int n = idx8 >> 4, kc = idx8 & 15;
    uint4 v = reinterpret_cast<const uint4*>(Wt)[idx8];
    *reinterpret_cast<uint4*>(&sW[n * 136 + kc * 8]) = v;
  }
#pragma unroll
  for (int p = 0; p < 4; p++) {
    int idx8 = p * 256 + tid;
    int m = idx8 >> 4, kc = idx8 & 15;
    int row = rbase + m;
    uint4 v = make_uint4(0u, 0u, 0u, 0u);
    if (row < NN)
      v = *reinterpret_cast<const uint4*>(&A16[(size_t)row * HID + kc * 8]);
    *reinterpret_cast<uint4*>(&sA[m * 136 + kc * 8]) = v;
  }
  __syncthreads();

  int wave = tid >> 6, lane = tid & 63;
  int l15 = lane & 15, quad = lane >> 4;
  int mstrip = wave * 16;

  f32x4 acc[8];
#pragma unroll
  for (int t = 0; t < 8; t++) acc[t] = (f32x4){0.f, 0.f, 0.f, 0.f};

#pragma unroll
  for (int ks = 0; ks < 4; ks++) {
    int k0 = ks * 32 + quad * 8;
    bf16x8 a = *reinterpret_cast<const bf16x8*>(&sA[(mstrip + l15) * 136 + k0]);
#pragma unroll
    for (int t = 0; t < 8; t++) {
      bf16x8 b = *reinterpret_cast<const bf16x8*>(&sW[(t * 16 + l15) * 136 + k0]);
      acc[t] = __builtin_amdgcn_mfma_f32_16x16x32_bf16(a, b, acc[t], 0, 0, 0);
    }
  }

#pragma unroll
  for (int t = 0; t < 8; t++) {
    int n = t * 16 + l15;
    float bv = bias ? bias[n] : 0.f;
#pragma unroll
    for (int r = 0; r < 4; r++) {
      int row = rbase + mstrip + quad * 4 + r;
      if (row < NN) {
        float o = acc[t][r] + bv;
        if (relu) o = fmaxf(o, 0.f);
        out16[(size_t)row * HID + n] = f2bf_bits(o);
      }
    }
  }
}

// ---------------- tail GEMM via MFMA ----------------------------------------
__global__ __launch_bounds__(256) void gemm_tail_mfma(
    const float* __restrict__ A, int lda, const unsigned short* __restrict__ Wt,
    int Kp, const void* __restrict__ bias, float* __restrict__ outp, int ldo,
    int relu, const int* __restrict__ flag) {
  __shared__ alignas(16) unsigned short sA[64 * 264];
  __shared__ alignas(16) unsigned short sW[64 * 264];
  int tid = threadIdx.x;
  int rbase = blockIdx.x * 64;
  int nbase = blockIdx.y * 64;
  int wave = tid >> 6, lane = tid & 63;
  int l15 = lane & 15, quad = lane >> 4;
  int mstrip = wave * 16;

  f32x4 acc[4];
#pragma unroll
  for (int t = 0; t < 4; t++) acc[t] = (f32x4){0.f, 0.f, 0.f, 0.f};

  for (int kc = 0; kc < Kp; kc += 256) {
#pragma unroll 4
    for (int p = 0; p < 16; p++) {
      int idx = p * 1024 + tid * 4;
      int m = idx >> 8, k = idx & 255;
      float4 v = *reinterpret_cast<const float4*>(&A[(size_t)(rbase + m) * lda + kc + k]);
      ushort4 b;
      b.x = f2bf_bits(v.x); b.y = f2bf_bits(v.y);
      b.z = f2bf_bits(v.z); b.w = f2bf_bits(v.w);
      *reinterpret_cast<ushort4*>(&sA[m * 264 + k]) = b;
    }
#pragma unroll 4
    for (int p = 0; p < 8; p++) {
      int idx8 = p * 256 + tid;
      int n = idx8 >> 5, kk = (idx8 & 31) * 8;
      uint4 v = *reinterpret_cast<const uint4*>(&Wt[(size_t)(nbase + n) * Kp + kc + kk]);
      *reinterpret_cast<uint4*>(&sW[n * 264 + kk]) = v;
    }
    __syncthreads();
#pragma unroll
    for (int ks = 0; ks < 8; ks++) {
      int k0 = ks * 32 + quad * 8;
      bf16x8 a = *reinterpret_cast<const bf16x8*>(&sA[(mstrip + l15) * 264 + k0]);
#pragma unroll
      for (int nt = 0; nt < 4; nt++) {
        bf16x8 b = *reinterpret_cast<const bf16x8*>(&sW[(nt * 16 + l15) * 264 + k0]);
        acc[nt] = __builtin_amdgcn_mfma_f32_16x16x32_bf16(a, b, acc[nt], 0, 0, 0);
      }
    }
    __syncthreads();
  }

  bool bf = *flag != 0;
#pragma unroll
  for (int nt = 0; nt < 4; nt++) {
    int col = nbase + nt * 16 + l15;
    float bv = ldf(bias, col, bf);
#pragma unroll
    for (int r = 0; r < 4; r++) {
      int row = rbase + mstrip + quad * 4 + r;
      float o = acc[nt][r] + bv;
      if (relu) o = fmaxf(o, 0.f);
      outp[(size_t)row * ldo + col] = o;
    }
  }
}

// ---------------- aggregation: 4 nodes/block, shfl bcast, fused gate*dinv ---
// Each lane loads its own edge entry (src,eid), gathers gate=w_all4[eid] and
// dinv4[src] (small L2-resident tables), val = gate*dinv_src; edge j broadcast
// via __shfl. No LDS, no barriers. csr_val is never materialized.
// out16[n] = dn*(sum_k val_k*h16[src_k]) + dn^2*h16[n]
__global__ __launch_bounds__(256) void aggregate_kernel(
    const unsigned short* __restrict__ h16, const int* __restrict__ offs,
    const int2* __restrict__ csr_se, const float* __restrict__ w_all4,
    const float* __restrict__ dinv4, int layer,
    unsigned short* __restrict__ out16) {
  int wave = threadIdx.x >> 6;
  int lane = threadIdx.x & 63;
  int n = blockIdx.x * 4 + wave;  // NN = 50000 = 4*12500, always in range
  int grp = lane >> 4;            // j-slot
  int c16 = lane & 15;            // 16B channel chunk (8 bf16)
  int start = offs[n], end = offs[n + 1];
  float a0 = 0.f, a1 = 0.f, a2 = 0.f, a3 = 0.f;
  float a4 = 0.f, a5 = 0.f, a6 = 0.f, a7 = 0.f;
  float b0 = 0.f, b1 = 0.f, b2 = 0.f, b3 = 0.f;
  float b4 = 0.f, b5 = 0.f, b6 = 0.f, b7 = 0.f;
  for (int base = start; base < end; base += 64) {
    int k = base + lane;
    float vread = 0.f;
    int sread = 0;
    if (k < end) {
      int2 se = csr_se[k];
      sread = min(max(se.x, 0), NN - 1);
      int eid = min(max(se.y, 0), EE - 1);
      vread = w_all4[(size_t)eid * 4 + layer] * dinv4[(size_t)sread * 4 + layer];
    }
    int m = min(64, end - base);
    int j = grp;
    for (; j + 4 < m; j += 8) {
      float v0 = __shfl(vread, j);
      int si0 = __shfl(sread, j);
      float v1 = __shfl(vread, j + 4);
      int si1 = __shfl(sread, j + 4);
      uint4 u0 = *reinterpret_cast<const uint4*>(&h16[(size_t)si0 * HID + c16 * 8]);
      uint4 u1 = *reinterpret_cast<const uint4*>(&h16[(size_t)si1 * HID + c16 * 8]);
      a0 = fmaf(v0, bfl(u0.x), a0); a1 = fmaf(v0, bfh(u0.x), a1);
      a2 = fmaf(v0, bfl(u0.y), a2); a3 = fmaf(v0, bfh(u0.y), a3);
      a4 = fmaf(v0, bfl(u0.z), a4); a5 = fmaf(v0, bfh(u0.z), a5);
      a6 = fmaf(v0, bfl(u0.w), a6); a7 = fmaf(v0, bfh(u0.w), a7);
      b0 = fmaf(v1, bfl(u1.x), b0); b1 = fmaf(v1, bfh(u1.x), b1);
      b2 = fmaf(v1, bfl(u1.y), b2); b3 = fmaf(v1, bfh(u1.y), b3);
      b4 = fmaf(v1, bfl(u1.z), b4); b5 = fmaf(v1, bfh(u1.z), b5);
      b6 = fmaf(v1, bfl(u1.w), b6); b7 = fmaf(v1, bfh(u1.w), b7);
    }
    if (j < m) {
      float v = __shfl(vread, j);
      int si = __shfl(sread, j);
      uint4 u = *reinterpret_cast<const uint4*>(&h16[(size_t)si * HID + c16 * 8]);
      a0 = fmaf(v, bfl(u.x), a0); a1 = fmaf(v, bfh(u.x), a1);
      a2 = fmaf(v, bfl(u.y), a2); a3 = fmaf(v, bfh(u.y), a3);
      a4 = fmaf(v, bfl(u.z), a4); a5 = fmaf(v, bfh(u.z), a5);
      a6 = fmaf(v, bfl(u.w), a6); a7 = fmaf(v, bfh(u.w), a7);
    }
  }
  // merge dual sets, then combine the 4 j-slot groups (in-wave shuffles)
  a0 += b0; a1 += b1; a2 += b2; a3 += b3;
  a4 += b4; a5 += b5; a6 += b6; a7 += b7;
  a0 += __shfl_xor(a0, 16); a1 += __shfl_xor(a1, 16);
  a2 += __shfl_xor(a2, 16); a3 += __shfl_xor(a3, 16);
  a4 += __shfl_xor(a4, 16); a5 += __shfl_xor(a5, 16);
  a6 += __shfl_xor(a6, 16); a7 += __shfl_xor(a7, 16);
  a0 += __shfl_xor(a0, 32); a1 += __shfl_xor(a1, 32);
  a2 += __shfl_xor(a2, 32); a3 += __shfl_xor(a3, 32);
  a4 += __shfl_xor(a4, 32); a5 += __shfl_xor(a5, 32);
  a6 += __shfl_xor(a6, 32); a7 += __shfl_xor(a7, 32);
  if (grp == 0) {
    float dn = dinv4[(size_t)n * 4 + layer];
    float dn2 = dn * dn;
    uint4 su = *reinterpret_cast<const uint4*>(&h16[(size_t)n * HID + c16 * 8]);
    ushort4 o0, o1v;
    o0.x  = f2bf_bits(dn * a0 + dn2 * bfl(su.x));
    o0.y  = f2bf_bits(dn * a1 + dn2 * bfh(su.x));
    o0.z  = f2bf_bits(dn * a2 + dn2 * bfl(su.y));
    o0.w  = f2bf_bits(dn * a3 + dn2 * bfh(su.y));
    o1v.x = f2bf_bits(dn * a4 + dn2 * bfl(su.z));
    o1v.y = f2bf_bits(dn * a5 + dn2 * bfh(su.z));
    o1v.z = f2bf_bits(dn * a6 + dn2 * bfl(su.w));
    o1v.w = f2bf_bits(dn * a7 + dn2 * bfh(su.w));
    *reinterpret_cast<ushort4*>(&out16[(size_t)n * HID + c16 * 8]) = o0;
    *reinterpret_cast<ushort4*>(&out16[(size_t)n * HID + c16 * 8 + 4]) = o1v;
  }
}

// ---------------- mean pool, 2-phase (bf16 input) ---------------------------
__global__ __launch_bounds__(128) void pool_partial(const unsigned short* __restrict__ h16,
                                                    const int* __restrict__ batch,
                                                    float* __restrict__ part) {
  int g = blockIdx.x, chunk = blockIdx.y, c = threadIdx.x;
  int lo = 0, hi = NN;
  while (lo < hi) { int mid = (lo + hi) >> 1; if (batch[mid] < g) lo = mid + 1; else hi = mid; }
  int start = lo;
  hi = NN;
  while (lo < hi) { int mid = (lo + hi) >> 1; if (batch[mid] < g + 1) lo = mid + 1; else hi = mid; }
  int end = lo;
  int len = end - start;
  int per = (len + PCH - 1) / PCH;
  int s = start + chunk * per;
  int e = min(s + per, end);
  float sum = 0.f;
  for (int n = s; n < e; n++) sum += bfl((unsigned)h16[(size_t)n * HID + c]);
  part[((size_t)g * PCH + chunk) * HID + c] = sum;
}

__global__ __launch_bounds__(128) void pool_combine(const float* __restrict__ part,
                                                    const int* __restrict__ batch,
                                                    float* __restrict__ cat) {
  int g = blockIdx.x, c = threadIdx.x;
  int lo = 0, hi = NN;
  while (lo < hi) { int mid = (lo + hi) >> 1; if (batch[mid] < g) lo = mid + 1; else hi = mid; }
  int start = lo;
  hi = NN;
  while (lo < hi) { int mid = (lo + hi) >> 1; if (batch[mid] < g + 1) lo = mid + 1; else hi = mid; }
  int end = lo;
  float s = 0.f;
#pragma unroll
  for (int k = 0; k < PCH; k++) s += part[((size_t)g * PCH + k) * HID + c];
  float cntf = (float)(end - start);
  cat[(size_t)g * PIN + c] = s / fmaxf(cntf, 1.f);
}

// ---------------- final [G,512] @ [512,1] + b -> out ------------------------
__global__ __launch_bounds__(64) void final_kernel(const float* __restrict__ A,
                                                   const void* __restrict__ W,
                                                   const void* __restrict__ b,
                                                   void* __restrict__ outp,
                                                   const int* __restrict__ flag) {
  bool bf = *flag != 0;
  int g = blockIdx.x, lane = threadIdx.x;
  float s = 0.f;
  for (int k = lane; k < PH; k += 64) s = fmaf(A[(size_t)g * PH + k], ldf(W, k, bf), s);
#pragma unroll
  for (int off = 32; off > 0; off >>= 1) s += __shfl_down(s, off);
  if (lane == 0) {
    float r = s + ldf(b, 0, bf);
    if (bf) ((bf16*)outp)[g] = __float2bfloat16(r);
    else    ((float*)outp)[g] = r;
  }
}

// ---------------------------------------------------------------------------
extern "C" void kernel_launch(void* const* d_in, const int* in_sizes, int n_in,
                              void* d_out, int out_size, void* d_ws, size_t ws_size,
                              hipStream_t stream) {
  const void* x      = d_in[0];
  const int*  ei     = (const int*)d_in[1];
  const void* eattr  = d_in[2];
  const int*  batch  = (const int*)d_in[3];
  const void* molf   = d_in[4];
  const void* lin_W  = d_in[5];
  const void* mW1    = d_in[6];
  const void* mb1    = d_in[7];
  const void* mW2    = d_in[8];
  const void* mb2    = d_in[9];
  const void* cbias  = d_in[10];
  const void* gW     = d_in[11];
  const void* gb     = d_in[12];
  const void* mlpW0  = d_in[13];
  const void* mlpb0  = d_in[14];
  const void* mlpW1  = d_in[15];
  const void* mlpb1  = d_in[16];
  const void* mlpW2  = d_in[17];
  const void* mlpb2  = d_in[18];
  const void* mlpW3  = d_in[19];
  const void* mlpb3  = d_in[20];
  const void* predW0 = d_in[21];
  const void* predb0 = d_in[22];
  const void* predW1 = d_in[23];
  const void* predb1 = d_in[24];
  const void* outW   = d_in[25];
  const void* outb   = d_in[26];

  char* base = (char*)d_ws;
  size_t off = 0;
  auto alloc = [&](size_t bytes) -> char* {
    char* p = base + off;
    off = (off + bytes + 255) & ~(size_t)255;
    return p;
  };
  unsigned short* h16  = (unsigned short*)alloc((size_t)NN * HID * 2);
  unsigned short* t16  = (unsigned short*)alloc((size_t)NN * HID * 2);
  float* dinv4    = (float*)alloc((size_t)NN * 4 * 4);
  int*   cnt      = (int*)alloc((size_t)NN * 4);
  int*   offs     = (int*)alloc((size_t)(NN + 1) * 4);
  int*   cursor   = (int*)alloc((size_t)NN * 4);
  int*   bsum     = (int*)alloc((size_t)256 * 4);
  int2*  csr_se   = (int2*)alloc((size_t)EE * 8);
  float* w_all4   = (float*)alloc((size_t)EE * 4 * 4);
  unsigned short* Wt    = (unsigned short*)alloc((size_t)NL * HID * HID * 2);
  float* bprime   = (float*)alloc((size_t)NL * HID * 4);
  unsigned short* tailW = (unsigned short*)alloc((size_t)622592 * 2);
  unsigned short* edgeW = (unsigned short*)alloc((size_t)256 * 32 * 2);
  int*   flag     = (int*)alloc(256);
  float* part     = (float*)alloc((size_t)GG * PCH * HID * 4);
  float* molf32   = (float*)alloc((size_t)GG * 256 * 4);
  float* m0       = (float*)alloc((size_t)GG * MH * 4);
  float* m1       = (float*)alloc((size_t)GG * MH * 4);
  float* cat      = (float*)alloc((size_t)GG * PIN * 4);
  float* p0       = (float*)alloc((size_t)GG * PH * 4);
  float* p1       = (float*)alloc((size_t)GG * PH * 4);

  hipMemsetAsync(cnt, 0, (size_t)NN * 4, stream);
  hipMemsetAsync(cursor, 0, (size_t)NN * 4, stream);
  hipMemsetAsync(molf32, 0, (size_t)GG * 256 * 4, stream);

  // dtype probe first — everything downstream branches on it
  probe_kernel<<<1, 64, 0, stream>>>((const unsigned short*)x, flag);

  // weight prep (fused layer weights + tail + edge)
  prep_fused_w<<<256, 256, 0, stream>>>(lin_W, gW, Wt, flag);
  prep_fused_b<<<NL, 128, 0, stream>>>(cbias, gW, gb, bprime, flag);
  prep_tail<<<(622592 + 255) / 256, 256, 0, stream>>>(mlpW0, mlpW1, mlpW2, mlpW3,
                                                      predW0, predW1, tailW, flag);
  prep_edge_w<<<32, 256, 0, stream>>>(mW1, mb1, edgeW, flag);

  // x -> bf16 layer state
  {
    int n8 = NN * HID / 8;
    cvt_to_bf16<<<(n8 + 255) / 256, 256, 0, stream>>>(x, h16, n8, flag);
  }
  // edge gates (MFMA, rolling prefetch depth 2)
  edge_mlp_mfma<<<(EE + EMB - 1) / EMB, 256, 0, stream>>>(eattr, edgeW, mW2, mb2,
                                                          w_all4, flag);
  // CSR build (3-phase parallel scan)
  count_kernel<<<(EE + 255) / 256, 256, 0, stream>>>(ei, cnt);
  scan_phase1<<<SCAN_B, 256, 0, stream>>>(cnt, bsum);
  scan_phase2<<<1, 256, 0, stream>>>(bsum, offs);
  scan_phase3<<<SCAN_B, 256, 0, stream>>>(cnt, bsum, offs);
  fill_kernel<<<(EE + 255) / 256, 256, 0, stream>>>(ei, offs, cursor, csr_se);
  // degrees (gates read via csr_se.y — csr_gather/csr_scale deleted)
  deg_kernel<<<(NN + 255) / 256, 256, 0, stream>>>(offs, csr_se, w_all4, dinv4);

  // GCN layers (fused): aggregate(h16)->t16; gemm(t16, W'_l, b'_l, relu)->h16
  const int gemm_blocks = (NN + 63) / 64;  // 782
  for (int l = 0; l < NL; l++) {
    aggregate_kernel<<<NN / 4, 256, 0, stream>>>(h16, offs, csr_se,
                                                 w_all4, dinv4, l, t16);
    gemm_nodes_bf16<<<gemm_blocks, 256, 0, stream>>>(
        t16, Wt + (size_t)l * HID * HID, bprime + (size_t)l * HID, h16, 1);
  }

  // pooling -> cat[:, 0:128]  (2-phase, bf16 input)
  pool_partial<<<dim3(GG, PCH), 128, 0, stream>>>(h16, batch, part);
  pool_combine<<<GG, 128, 0, stream>>>(part, batch, cat);

  // molecular MLP -> cat[:, 128:256]  (MFMA tail, K-padded weights)
  cvt_molf<<<(GG * 50 + 255) / 256, 256, 0, stream>>>(molf, molf32, flag);
  gemm_tail_mfma<<<dim3(4, 4), 256, 0, stream>>>(molf32, 256, tailW + 0,      256, mlpb0, m0, 256, 1, flag);
  gemm_tail_mfma<<<dim3(4, 4), 256, 0, stream>>>(m0,     256, tailW + 65536,  256, mlpb1, m1, 256, 1, flag);
  gemm_tail_mfma<<<dim3(4, 4), 256, 0, stream>>>(m1,     256, tailW + 131072, 256, mlpb2, m0, 256, 1, flag);
  gemm_tail_mfma<<<dim3(4, 2), 256, 0, stream>>>(m0,     256, tailW + 196608, 256, mlpb3, cat + MOUT, 256, 1, flag);

  // predictor
  gemm_tail_mfma<<<dim3(4, 8), 256, 0, stream>>>(cat, 256, tailW + 229376, 256, predb0, p0, 512, 1, flag);
  gemm_tail_mfma<<<dim3(4, 8), 256, 0, stream>>>(p0,  512, tailW + 360448, 512, predb1, p1, 512, 1, flag);
  final_kernel<<<GG, 64, 0, stream>>>(p1, outW, outb, d_out, flag);
}

// Round 8
// 575.615 us; speedup vs baseline: 1.0455x; 1.0455x over previous
//
#include <hip/hip_runtime.h>
#include <hip/hip_bf16.h>

// ---------------------------------------------------------------------------
// PDNConv GNN, MI355X round 25 — REVERT to round-20 source (best: 571.5us).
// r21 (batched prefetch): -14% | r24 (depth-2 prefetch): -7%, FETCH +2.3MB |
// r24 (csr_val fusion into aggregate): net loss | r22/r23 aggregate variants:
// neutral. Round-20 config is the measured optimum: edge_mlp = swapped-operand
// MFMA, EMB=128, depth-1 rolling prefetch; csr_val materialized via
// csr_gather/csr_scale; aggregate = 1-wave/node LDS-staged.
// ---------------------------------------------------------------------------

#define NN 50000
#define EE 600000
#define GG 256
#define HID 128
#define EDIM 16
#define EHID 64
#define NL 4
#define MIN_F 200
#define MH 256
#define MOUT 128
#define PH 512
#define PIN 256
#define SCAN_B 196  // ceil(NN/256)
#define PCH 8       // pooling chunks per graph
#define EMB 128     // edges per block (edge_mlp)

typedef __hip_bfloat16 bf16;
typedef __attribute__((ext_vector_type(8))) short bf16x8;
typedef __attribute__((ext_vector_type(4))) float f32x4;

__device__ __forceinline__ float bfl(unsigned u) { return __uint_as_float(u << 16); }
__device__ __forceinline__ float bfh(unsigned u) { return __uint_as_float(u & 0xffff0000u); }
__device__ __forceinline__ float b2f(bf16 x) { return __bfloat162float(x); }
__device__ __forceinline__ float ldf(const void* p, long i, bool bf) {
  return bf ? __bfloat162float(((const bf16*)p)[i]) : ((const float*)p)[i];
}
__device__ __forceinline__ unsigned short f2bf_bits(float v) {
  bf16 h = __float2bfloat16(v);
  return *reinterpret_cast<unsigned short*>(&h);
}

// ---------------- dtype probe ------------------------------------------------
__global__ void probe_kernel(const unsigned short* __restrict__ xs, int* flag) {
  if (threadIdx.x == 0 && blockIdx.x == 0) {
    int sane = 0;
    for (int i = 0; i < 128; i++) {
      unsigned e = (xs[i] >> 7) & 0xFF;
      if (e >= 96 && e <= 159) sane++;
    }
    *flag = (sane >= 112) ? 1 : 0;  // 1 = bf16 inputs
  }
}

// ---------------- input -> bf16 conversion (8 elems/thread) -----------------
__global__ __launch_bounds__(256) void cvt_to_bf16(const void* __restrict__ in,
                                                   unsigned short* __restrict__ outp,
                                                   int n8, const int* __restrict__ flag) {
  bool bf = *flag != 0;
  int i = blockIdx.x * 256 + threadIdx.x;
  if (i >= n8) return;
  if (bf) {
    reinterpret_cast<uint4*>(outp)[i] = reinterpret_cast<const uint4*>(in)[i];
  } else {
    const float4* p = reinterpret_cast<const float4*>(in) + (size_t)i * 2;
    float4 v0 = p[0], v1 = p[1];
    ushort4 a, b;
    a.x = f2bf_bits(v0.x); a.y = f2bf_bits(v0.y);
    a.z = f2bf_bits(v0.z); a.w = f2bf_bits(v0.w);
    b.x = f2bf_bits(v1.x); b.y = f2bf_bits(v1.y);
    b.z = f2bf_bits(v1.z); b.w = f2bf_bits(v1.w);
    reinterpret_cast<ushort4*>(outp)[i * 2] = a;
    reinterpret_cast<ushort4*>(outp)[i * 2 + 1] = b;
  }
}

// ---------------- mol_features [G,200] -> padded f32 [G,256] ----------------
__global__ __launch_bounds__(256) void cvt_molf(const void* __restrict__ in,
                                                float* __restrict__ outp,
                                                const int* __restrict__ flag) {
  bool bf = *flag != 0;
  int i = blockIdx.x * 256 + threadIdx.x;  // GG*50
  if (i >= GG * 50) return;
  int row = i / 50, c4 = (i % 50) * 4;
  float4 v;
  if (bf) {
    const unsigned short* p = (const unsigned short*)in + (size_t)row * MIN_F + c4;
    uint2 u = *reinterpret_cast<const uint2*>(p);
    v.x = bfl(u.x); v.y = bfh(u.x); v.z = bfl(u.y); v.w = bfh(u.y);
  } else {
    v = *reinterpret_cast<const float4*>((const float*)in + (size_t)row * MIN_F + c4);
  }
  *reinterpret_cast<float4*>(&outp[(size_t)row * 256 + c4]) = v;
}

// ---------------- weight prep: fused W'_l = linW_l @ gW_l -> bf16 [n][k] ----
__global__ __launch_bounds__(256) void prep_fused_w(const void* __restrict__ lin_W,
                                                    const void* __restrict__ gW,
                                                    unsigned short* __restrict__ Wt,
                                                    const int* __restrict__ flag) {
  bool bf = *flag != 0;
  int idx = blockIdx.x * 256 + threadIdx.x;  // 0 .. 4*16384-1
  if (idx >= 4 * 16384) return;
  int l = idx >> 14;
  int rem = idx & 16383;
  int n = rem >> 7, k = rem & 127;  // Wt[n][k] = W'[k][n]
  float s = 0.f;
  long lb = (long)l * 16384;
  for (int m = 0; m < 128; m++)
    s += ldf(lin_W, lb + (long)k * 128 + m, bf) * ldf(gW, lb + (long)m * 128 + n, bf);
  Wt[idx] = f2bf_bits(s);
}

// b'_l[n] = gb_l[n] + sum_k cbias_l[k] * gW_l[k][n]   (f32)
__global__ __launch_bounds__(128) void prep_fused_b(const void* __restrict__ cbias,
                                                    const void* __restrict__ gW,
                                                    const void* __restrict__ gb,
                                                    float* __restrict__ bprime,
                                                    const int* __restrict__ flag) {
  bool bf = *flag != 0;
  int idx = blockIdx.x * 128 + threadIdx.x;  // 0 .. 4*128-1
  if (idx >= NL * HID) return;
  int l = idx >> 7, n = idx & 127;
  float s = ldf(gb, idx, bf);
  long lb = (long)l * 16384;
  for (int k = 0; k < 128; k++)
    s += ldf(cbias, (long)l * 128 + k, bf) * ldf(gW, lb + (long)k * 128 + n, bf);
  bprime[idx] = s;
}

// ---------------- weight prep: edge MLP W1 -> bf16 W1t[256 cols][32 K] ------
// k<16: W1; k==16: b1 (MFMA bias-fold); k>16: 0.
__global__ __launch_bounds__(256) void prep_edge_w(const void* __restrict__ mW1,
                                                   const void* __restrict__ mb1,
                                                   unsigned short* __restrict__ W1t,
                                                   const int* __restrict__ flag) {
  bool bf = *flag != 0;
  int idx = blockIdx.x * 256 + threadIdx.x;  // 256*32
  if (idx >= 256 * 32) return;
  int col = idx >> 5, k = idx & 31;
  float v = 0.f;
  if (k < EDIM) v = ldf(mW1, (long)(col >> 6) * (EDIM * EHID) + (long)k * EHID + (col & 63), bf);
  else if (k == EDIM) v = ldf(mb1, col, bf);
  W1t[idx] = f2bf_bits(v);
}

// ---------------- weight prep: tail (MLP+predictor) -> bf16 [N][Kp], K-pad --
__global__ __launch_bounds__(256) void prep_tail(
    const void* __restrict__ mlpW0, const void* __restrict__ mlpW1,
    const void* __restrict__ mlpW2, const void* __restrict__ mlpW3,
    const void* __restrict__ predW0, const void* __restrict__ predW1,
    unsigned short* __restrict__ T, const int* __restrict__ flag) {
  bool bf = *flag != 0;
  int idx = blockIdx.x * 256 + threadIdx.x;
  const void* src; int N, Kp, Ksrc, off;
  if      (idx < 65536)  { src = mlpW0;  N = 256; Kp = 256; Ksrc = 200; off = 0; }
  else if (idx < 131072) { src = mlpW1;  N = 256; Kp = 256; Ksrc = 256; off = 65536; }
  else if (idx < 196608) { src = mlpW2;  N = 256; Kp = 256; Ksrc = 256; off = 131072; }
  else if (idx < 229376) { src = mlpW3;  N = 128; Kp = 256; Ksrc = 256; off = 196608; }
  else if (idx < 360448) { src = predW0; N = 512; Kp = 256; Ksrc = 256; off = 229376; }
  else if (idx < 622592) { src = predW1; N = 512; Kp = 512; Ksrc = 512; off = 360448; }
  else return;
  int rem = idx - off;
  int n = rem / Kp, k = rem % Kp;
  float v = (k < Ksrc) ? ldf(src, (long)k * N + n, bf) : 0.f;
  T[idx] = f2bf_bits(v);
}

// ---------------- CSR build: histogram / 3-phase scan / fill ----------------
__global__ __launch_bounds__(256) void count_kernel(const int* __restrict__ ei,
                                                    int* __restrict__ cnt) {
  int e = blockIdx.x * 256 + threadIdx.x;
  if (e >= EE) return;
  int c = ei[EE + e];
  c = min(max(c, 0), NN - 1);
  atomicAdd(&cnt[c], 1);
}

__global__ __launch_bounds__(256) void scan_phase1(const int* __restrict__ cnt,
                                                   int* __restrict__ bsum) {
  __shared__ int red[256];
  int tid = threadIdx.x;
  int i = blockIdx.x * 256 + tid;
  red[tid] = (i < NN) ? cnt[i] : 0;
  __syncthreads();
  for (int off = 128; off > 0; off >>= 1) {
    if (tid < off) red[tid] += red[tid + off];
    __syncthreads();
  }
  if (tid == 0) bsum[blockIdx.x] = red[0];
}

__global__ __launch_bounds__(256) void scan_phase2(int* __restrict__ bsum,
                                                   int* __restrict__ offs) {
  __shared__ int buf[256];
  int tid = threadIdx.x;
  int v = (tid < SCAN_B) ? bsum[tid] : 0;
  buf[tid] = v;
  __syncthreads();
  for (int off = 1; off < 256; off <<= 1) {
    int t = (tid >= off) ? buf[tid - off] : 0;
    __syncthreads();
    buf[tid] += t;
    __syncthreads();
  }
  if (tid < SCAN_B) bsum[tid] = buf[tid] - v;  // exclusive block offsets
  if (tid == 255) offs[NN] = buf[255];
}

__global__ __launch_bounds__(256) void scan_phase3(const int* __restrict__ cnt,
                                                   const int* __restrict__ bsum,
                                                   int* __restrict__ offs) {
  __shared__ int buf[256];
  int tid = threadIdx.x;
  int i = blockIdx.x * 256 + tid;
  int v = (i < NN) ? cnt[i] : 0;
  buf[tid] = v;
  __syncthreads();
  for (int off = 1; off < 256; off <<= 1) {
    int t = (tid >= off) ? buf[tid - off] : 0;
    __syncthreads();
    buf[tid] += t;
    __syncthreads();
  }
  if (i < NN) offs[i] = bsum[blockIdx.x] + buf[tid] - v;
}

__global__ __launch_bounds__(256) void fill_kernel(const int* __restrict__ ei,
                                                   const int* __restrict__ offs,
                                                   int* __restrict__ cursor,
                                                   int2* __restrict__ csr_se) {
  int e = blockIdx.x * 256 + threadIdx.x;
  if (e >= EE) return;
  int c = ei[EE + e];
  c = min(max(c, 0), NN - 1);
  int pos = offs[c] + atomicAdd(&cursor[c], 1);
  pos = min(max(pos, 0), EE - 1);
  csr_se[pos] = make_int2(ei[e], e);
}

// ---------------- edge-gate MLP via MFMA: swapped operands, 128 e/blk -------
// Block = 128 edges, 4 waves; wave w owns layer w, walks 8 fragments.
// D_T = mfma(A = W1^T chunk T, B = eattr^T) -> D[h][e] with hidden in the
// REGISTER axis (h = T*16 + quad*4 + r) and edge in the lane axis (e = l15).
// Hidden reduction = per-lane fma into 4 independent chains + 2 cross-quad
// shuffle-adds. Gate + store on quad==0 lanes (16 consecutive edges).
__global__ __launch_bounds__(256) void edge_mlp_mfma(
    const void* __restrict__ eattr, const unsigned short* __restrict__ W1t,
    const void* __restrict__ mW2, const void* __restrict__ mb2,
    float* __restrict__ w_all4, const int* __restrict__ flag) {
  bool bf = *flag != 0;
  int tid = threadIdx.x;
  int wave = tid >> 6, lane = tid & 63;  // wave == layer index
  int l15 = lane & 15, quad = lane >> 4;

  // A-fragments: lane l15 = hidden row (T*16+l15) of this layer's W1^T,
  // k = quad*8..+7 (k=16 holds b1, k>16 zero).
  bf16x8 afrag[4];
#pragma unroll
  for (int t = 0; t < 4; t++)
    afrag[t] =
        *reinterpret_cast<const bf16x8*>(&W1t[((wave * 4 + t) * 16 + l15) * 32 + quad * 8]);

  // w2 per-lane: hidden h = T*16 + quad*4 + r within this layer's 64
  float w2v[16];
#pragma unroll
  for (int t = 0; t < 4; t++)
#pragma unroll
    for (int r = 0; r < 4; r++)
      w2v[t * 4 + r] = ldf(mW2, wave * 64 + t * 16 + quad * 4 + r, bf);
  float b2 = ldf(mb2, wave, bf);

  // constant part of the eattr^T B-fragment (bias lane / zero lanes)
  bf16x8 bconst = (bf16x8){0, 0, 0, 0, 0, 0, 0, 0};
  if (quad == 2) bconst[0] = (short)0x3F80;  // k=16 element = bf16(1.0)

  int ebase = blockIdx.x * EMB;
  int rowbytes = bf ? EDIM * 2 : EDIM * 4;
  const char* p = (const char*)eattr + (size_t)(ebase + l15) * rowbytes +
                  (size_t)quad * (rowbytes >> 1);
  int fragstep = 16 * rowbytes;

  auto loadb = [&](int fb, const char* pp) -> bf16x8 {
    bf16x8 v = bconst;
    if (quad < 2 && fb < EE) {
      if (bf) {
        v = *reinterpret_cast<const bf16x8*>(pp);
      } else {
        const float4* q = reinterpret_cast<const float4*>(pp);
        float4 v0 = q[0], v1 = q[1];
        v[0] = (short)f2bf_bits(v0.x); v[1] = (short)f2bf_bits(v0.y);
        v[2] = (short)f2bf_bits(v0.z); v[3] = (short)f2bf_bits(v0.w);
        v[4] = (short)f2bf_bits(v1.x); v[5] = (short)f2bf_bits(v1.y);
        v[6] = (short)f2bf_bits(v1.z); v[7] = (short)f2bf_bits(v1.w);
      }
    }
    return v;
  };

  bf16x8 bcur = loadb(ebase, p);
#pragma unroll 2
  for (int f = 0; f < EMB / 16; f++) {
    int fbase = ebase + f * 16;
    p += fragstep;
    bf16x8 bnxt = loadb(fbase + 16, p);  // prefetch next fragment
    if (fbase < EE) {
      float s0 = 0.f, s1 = 0.f, s2 = 0.f, s3 = 0.f;
#define DO_T(T, S)                                                            \
  {                                                                           \
    f32x4 acc = __builtin_amdgcn_mfma_f32_16x16x32_bf16(                      \
        afrag[T], bcur, (f32x4){0.f, 0.f, 0.f, 0.f}, 0, 0, 0);                \
    S = fmaf(fmaxf(acc.x, 0.f), w2v[T * 4 + 0], S);                           \
    S = fmaf(fmaxf(acc.y, 0.f), w2v[T * 4 + 1], S);                           \
    S = fmaf(fmaxf(acc.z, 0.f), w2v[T * 4 + 2], S);                           \
    S = fmaf(fmaxf(acc.w, 0.f), w2v[T * 4 + 3], S);                           \
  }
      DO_T(0, s0) DO_T(1, s1) DO_T(2, s2) DO_T(3, s3)
#undef DO_T
      float s = (s0 + s1) + (s2 + s3);
      s += __shfl_xor(s, 16);  // combine quads 0<->1, 2<->3
      s += __shfl_xor(s, 32);  // combine halves
      if (quad == 0) {
        float g = 1.f / (1.f + __expf(-(s + b2)));
        w_all4[(size_t)(fbase + l15) * 4 + wave] = g;
      }
    }
    bcur = bnxt;
  }
}

// ---------------- gather gates into CSR order -------------------------------
__global__ __launch_bounds__(256) void csr_gather(const int2* __restrict__ csr_se,
                                                  const float* __restrict__ w_all4,
                                                  float* __restrict__ csr_val) {
  int k = blockIdx.x * 256 + threadIdx.x;
  if (k >= EE) return;
  int eid = csr_se[k].y;
  eid = min(max(eid, 0), EE - 1);
  float4 w = reinterpret_cast<const float4*>(w_all4)[eid];
  csr_val[k] = w.x;
  csr_val[(size_t)EE + k] = w.y;
  csr_val[2 * (size_t)EE + k] = w.z;
  csr_val[3 * (size_t)EE + k] = w.w;
}

// ---------------- degree / dinv per layer (interleaved float4 out) ----------
__global__ __launch_bounds__(256) void deg_kernel(const int* __restrict__ offs,
                                                  const float* __restrict__ csr_val,
                                                  float* __restrict__ dinv4) {
  int n = blockIdx.x * 256 + threadIdx.x;
  if (n >= NN) return;
  int s = offs[n], e = offs[n + 1];
  float d0 = 1.f, d1 = 1.f, d2 = 1.f, d3 = 1.f;  // self-loop weight 1.0
  for (int k = s; k < e; k++) {
    d0 += csr_val[k];
    d1 += csr_val[EE + k];
    d2 += csr_val[2 * (size_t)EE + k];
    d3 += csr_val[3 * (size_t)EE + k];
  }
  float4 o;
  o.x = rsqrtf(d0); o.y = rsqrtf(d1); o.z = rsqrtf(d2); o.w = rsqrtf(d3);
  reinterpret_cast<float4*>(dinv4)[n] = o;
}

// csr_val[l][k] *= dinv_l[src_k]
__global__ __launch_bounds__(256) void csr_scale_kernel(const int2* __restrict__ csr_se,
                                                        const float* __restrict__ dinv4,
                                                        float* __restrict__ csr_val) {
  int k = blockIdx.x * 256 + threadIdx.x;
  if (k >= EE) return;
  int s = csr_se[k].x;
  s = min(max(s, 0), NN - 1);
  float4 d = reinterpret_cast<const float4*>(dinv4)[s];
  csr_val[k] *= d.x;
  csr_val[(size_t)EE + k] *= d.y;
  csr_val[2 * (size_t)EE + k] *= d.z;
  csr_val[3 * (size_t)EE + k] *= d.w;
}

// ---------------- node GEMM via MFMA: bf16 in/out, f32 bias -----------------
__global__ __launch_bounds__(256) void gemm_nodes_bf16(
    const unsigned short* __restrict__ A16, const unsigned short* __restrict__ Wt,
    const float* __restrict__ bias, unsigned short* __restrict__ out16,
    int relu) {
  __shared__ alignas(16) unsigned short sA[64 * 136];
  __shared__ alignas(16) unsigned short sW[128 * 136];
  int tid = threadIdx.x;
  int rbase = blockIdx.x * 64;

#pragma unroll
  for (int p = 0; p < 8; p++) {
    int idx8 = p * 256 + tid;
    int n = idx8 >> 4, kc = idx8 & 15;
    uint4 v = reinterpret_cast<const uint4*>(Wt)[idx8];
    *reinterpret_cast<uint4*>(&sW[n * 136 + kc * 8]) = v;
  }
#pragma unroll
  for (int p = 0; p < 4; p++) {
    int idx8 = p * 256 + tid;
    int m = idx8 >> 4, kc = idx8 & 15;
    int row = rbase + m;
    uint4 v = make_uint4(0u, 0u, 0u, 0u);
    if (row < NN)
      v = *reinterpret_cast<const uint4*>(&A16[(size_t)row * HID + kc * 8]);
    *reinterpret_cast<uint4*>(&sA[m * 136 + kc * 8]) = v;
  }
  __syncthreads();

  int wave = tid >> 6, lane = tid & 63;
  int l15 = lane & 15, quad = lane >> 4;
  int mstrip = wave * 16;

  f32x4 acc[8];
#pragma unroll
  for (int t = 0; t < 8; t++) acc[t] = (f32x4){0.f, 0.f, 0.f, 0.f};

#pragma unroll
  for (int ks = 0; ks < 4; ks++) {
    int k0 = ks * 32 + quad * 8;
    bf16x8 a = *reinterpret_cast<const bf16x8*>(&sA[(mstrip + l15) * 136 + k0]);
#pragma unroll
    for (int t = 0; t < 8; t++) {
      bf16x8 b = *reinterpret_cast<const bf16x8*>(&sW[(t * 16 + l15) * 136 + k0]);
      acc[t] = __builtin_amdgcn_mfma_f32_16x16x32_bf16(a, b, acc[t], 0, 0, 0);
    }
  }

#pragma unroll
  for (int t = 0; t < 8; t++) {
    int n = t * 16 + l15;
    float bv = bias ? bias[n] : 0.f;
#pragma unroll
    for (int r = 0; r < 4; r++) {
      int row = rbase + mstrip + quad * 4 + r;
      if (row < NN) {
        float o = acc[t][r] + bv;
        if (relu) o = fmaxf(o, 0.f);
        out16[(size_t)row * HID + n] = f2bf_bits(o);
      }
    }
  }
}

// ---------------- tail GEMM via MFMA ----------------------------------------
__global__ __launch_bounds__(256) void gemm_tail_mfma(
    const float* __restrict__ A, int lda, const unsigned short* __restrict__ Wt,
    int Kp, const void* __restrict__ bias, float* __restrict__ outp, int ldo,
    int relu, const int* __restrict__ flag) {
  __shared__ alignas(16) unsigned short sA[64 * 264];
  __shared__ alignas(16) unsigned short sW[64 * 264];
  int tid = threadIdx.x;
  int rbase = blockIdx.x * 64;
  int nbase = blockIdx.y * 64;
  int wave = tid >> 6, lane = tid & 63;
  int l15 = lane & 15, quad = lane >> 4;
  int mstrip = wave * 16;

  f32x4 acc[4];
#pragma unroll
  for (int t = 0; t < 4; t++) acc[t] = (f32x4){0.f, 0.f, 0.f, 0.f};

  for (int kc = 0; kc < Kp; kc += 256) {
#pragma unroll 4
    for (int p = 0; p < 16; p++) {
      int idx = p * 1024 + tid * 4;
      int m = idx >> 8, k = idx & 255;
      float4 v = *reinterpret_cast<const float4*>(&A[(size_t)(rbase + m) * lda + kc + k]);
      ushort4 b;
      b.x = f2bf_bits(v.x); b.y = f2bf_bits(v.y);
      b.z = f2bf_bits(v.z); b.w = f2bf_bits(v.w);
      *reinterpret_cast<ushort4*>(&sA[m * 264 + k]) = b;
    }
#pragma unroll 4
    for (int p = 0; p < 8; p++) {
      int idx8 = p * 256 + tid;
      int n = idx8 >> 5, kk = (idx8 & 31) * 8;
      uint4 v = *reinterpret_cast<const uint4*>(&Wt[(size_t)(nbase + n) * Kp + kc + kk]);
      *reinterpret_cast<uint4*>(&sW[n * 264 + kk]) = v;
    }
    __syncthreads();
#pragma unroll
    for (int ks = 0; ks < 8; ks++) {
      int k0 = ks * 32 + quad * 8;
      bf16x8 a = *reinterpret_cast<const bf16x8*>(&sA[(mstrip + l15) * 264 + k0]);
#pragma unroll
      for (int nt = 0; nt < 4; nt++) {
        bf16x8 b = *reinterpret_cast<const bf16x8*>(&sW[(nt * 16 + l15) * 264 + k0]);
        acc[nt] = __builtin_amdgcn_mfma_f32_16x16x32_bf16(a, b, acc[nt], 0, 0, 0);
      }
    }
    __syncthreads();
  }

  bool bf = *flag != 0;
#pragma unroll
  for (int nt = 0; nt < 4; nt++) {
    int col = nbase + nt * 16 + l15;
    float bv = ldf(bias, col, bf);
#pragma unroll
    for (int r = 0; r < 4; r++) {
      int row = rbase + mstrip + quad * 4 + r;
      float o = acc[nt][r] + bv;
      if (relu) o = fmaxf(o, 0.f);
      outp[(size_t)row * ldo + col] = o;
    }
  }
}

// ---------------- aggregation: 1 wave/node, 16B lane gathers, 4 j-slots -----
// lane = (grp = lane>>4 in 0..3, c16 = lane&15). Per j, grp's 16 lanes load
// the full 256B row (16B each). Group partials combined via shfl_xor 16/32.
// out16[n] = dn*(sum_k val_k*h16[src_k]) + dn^2*h16[n]
__global__ __launch_bounds__(64) void aggregate_kernel(
    const unsigned short* __restrict__ h16, const int* __restrict__ offs,
    const int2* __restrict__ csr_se, const float* __restrict__ csr_val,
    const float* __restrict__ dinv4, int layer,
    unsigned short* __restrict__ out16) {
  int n = blockIdx.x;
  int lane = threadIdx.x;      // 0..63
  int grp = lane >> 4;         // j-slot
  int c16 = lane & 15;         // 16B channel chunk (8 bf16)
  __shared__ int s_src[64];
  __shared__ float s_val[64];
  int start = offs[n], end = offs[n + 1];
  float a0 = 0.f, a1 = 0.f, a2 = 0.f, a3 = 0.f;
  float a4 = 0.f, a5 = 0.f, a6 = 0.f, a7 = 0.f;
  for (int base = start; base < end; base += 64) {
    int k = base + lane;
    if (k < end) {
      s_src[lane] = min(max(csr_se[k].x, 0), NN - 1);
      s_val[lane] = csr_val[k];
    }
    __syncthreads();
    int m = min(64, end - base);
    for (int j = grp; j < m; j += 4) {
      float v = s_val[j];
      uint4 u = *reinterpret_cast<const uint4*>(&h16[(size_t)s_src[j] * HID + c16 * 8]);
      a0 = fmaf(v, bfl(u.x), a0); a1 = fmaf(v, bfh(u.x), a1);
      a2 = fmaf(v, bfl(u.y), a2); a3 = fmaf(v, bfh(u.y), a3);
      a4 = fmaf(v, bfl(u.z), a4); a5 = fmaf(v, bfh(u.z), a5);
      a6 = fmaf(v, bfl(u.w), a6); a7 = fmaf(v, bfh(u.w), a7);
    }
    __syncthreads();
  }
  // combine the 4 j-slot groups (no barriers — in-wave shuffles)
  a0 += __shfl_xor(a0, 16); a1 += __shfl_xor(a1, 16);
  a2 += __shfl_xor(a2, 16); a3 += __shfl_xor(a3, 16);
  a4 += __shfl_xor(a4, 16); a5 += __shfl_xor(a5, 16);
  a6 += __shfl_xor(a6, 16); a7 += __shfl_xor(a7, 16);
  a0 += __shfl_xor(a0, 32); a1 += __shfl_xor(a1, 32);
  a2 += __shfl_xor(a2, 32); a3 += __shfl_xor(a3, 32);
  a4 += __shfl_xor(a4, 32); a5 += __shfl_xor(a5, 32);
  a6 += __shfl_xor(a6, 32); a7 += __shfl_xor(a7, 32);
  if (grp == 0) {
    float dn = dinv4[(size_t)n * 4 + layer];
    float dn2 = dn * dn;
    uint4 su = *reinterpret_cast<const uint4*>(&h16[(size_t)n * HID + c16 * 8]);
    ushort4 o0, o1v;
    o0.x  = f2bf_bits(dn * a0 + dn2 * bfl(su.x));
    o0.y  = f2bf_bits(dn * a1 + dn2 * bfh(su.x));
    o0.z  = f2bf_bits(dn * a2 + dn2 * bfl(su.y));
    o0.w  = f2bf_bits(dn * a3 + dn2 * bfh(su.y));
    o1v.x = f2bf_bits(dn * a4 + dn2 * bfl(su.z));
    o1v.y = f2bf_bits(dn * a5 + dn2 * bfh(su.z));
    o1v.z = f2bf_bits(dn * a6 + dn2 * bfl(su.w));
    o1v.w = f2bf_bits(dn * a7 + dn2 * bfh(su.w));
    *reinterpret_cast<ushort4*>(&out16[(size_t)n * HID + c16 * 8]) = o0;
    *reinterpret_cast<ushort4*>(&out16[(size_t)n * HID + c16 * 8 + 4]) = o1v;
  }
}

// ---------------- mean pool, 2-phase (bf16 input) ---------------------------
__global__ __launch_bounds__(128) void pool_partial(const unsigned short* __restrict__ h16,
                                                    const int* __restrict__ batch,
                                                    float* __restrict__ part) {
  int g = blockIdx.x, chunk = blockIdx.y, c = threadIdx.x;
  int lo = 0, hi = NN;
  while (lo < hi) { int mid = (lo + hi) >> 1; if (batch[mid] < g) lo = mid + 1; else hi = mid; }
  int start = lo;
  hi = NN;
  while (lo < hi) { int mid = (lo + hi) >> 1; if (batch[mid] < g + 1) lo = mid + 1; else hi = mid; }
  int end = lo;
  int len = end - start;
  int per = (len + PCH - 1) / PCH;
  int s = start + chunk * per;
  int e = min(s + per, end);
  float sum = 0.f;
  for (int n = s; n < e; n++) sum += bfl((unsigned)h16[(size_t)n * HID + c]);
  part[((size_t)g * PCH + chunk) * HID + c] = sum;
}

__global__ __launch_bounds__(128) void pool_combine(const float* __restrict__ part,
                                                    const int* __restrict__ batch,
                                                    float* __restrict__ cat) {
  int g = blockIdx.x, c = threadIdx.x;
  int lo = 0, hi = NN;
  while (lo < hi) { int mid = (lo + hi) >> 1; if (batch[mid] < g) lo = mid + 1; else hi = mid; }
  int start = lo;
  hi = NN;
  while (lo < hi) { int mid = (lo + hi) >> 1; if (batch[mid] < g + 1) lo = mid + 1; else hi = mid; }
  int end = lo;
  float s = 0.f;
#pragma unroll
  for (int k = 0; k < PCH; k++) s += part[((size_t)g * PCH + k) * HID + c];
  float cntf = (float)(end - start);
  cat[(size_t)g * PIN + c] = s / fmaxf(cntf, 1.f);
}

// ---------------- final [G,512] @ [512,1] + b -> out ------------------------
__global__ __launch_bounds__(64) void final_kernel(const float* __restrict__ A,
                                                   const void* __restrict__ W,
                                                   const void* __restrict__ b,
                                                   void* __restrict__ outp,
                                                   const int* __restrict__ flag) {
  bool bf = *flag != 0;
  int g = blockIdx.x, lane = threadIdx.x;
  float s = 0.f;
  for (int k = lane; k < PH; k += 64) s = fmaf(A[(size_t)g * PH + k], ldf(W, k, bf), s);
#pragma unroll
  for (int off = 32; off > 0; off >>= 1) s += __shfl_down(s, off);
  if (lane == 0) {
    float r = s + ldf(b, 0, bf);
    if (bf) ((bf16*)outp)[g] = __float2bfloat16(r);
    else    ((float*)outp)[g] = r;
  }
}

// ---------------------------------------------------------------------------
extern "C" void kernel_launch(void* const* d_in, const int* in_sizes, int n_in,
                              void* d_out, int out_size, void* d_ws, size_t ws_size,
                              hipStream_t stream) {
  const void* x      = d_in[0];
  const int*  ei     = (const int*)d_in[1];
  const void* eattr  = d_in[2];
  const int*  batch  = (const int*)d_in[3];
  const void* molf   = d_in[4];
  const void* lin_W  = d_in[5];
  const void* mW1    = d_in[6];
  const void* mb1    = d_in[7];
  const void* mW2    = d_in[8];
  const void* mb2    = d_in[9];
  const void* cbias  = d_in[10];
  const void* gW     = d_in[11];
  const void* gb     = d_in[12];
  const void* mlpW0  = d_in[13];
  const void* mlpb0  = d_in[14];
  const void* mlpW1  = d_in[15];
  const void* mlpb1  = d_in[16];
  const void* mlpW2  = d_in[17];
  const void* mlpb2  = d_in[18];
  const void* mlpW3  = d_in[19];
  const void* mlpb3  = d_in[20];
  const void* predW0 = d_in[21];
  const void* predb0 = d_in[22];
  const void* predW1 = d_in[23];
  const void* predb1 = d_in[24];
  const void* outW   = d_in[25];
  const void* outb   = d_in[26];

  char* base = (char*)d_ws;
  size_t off = 0;
  auto alloc = [&](size_t bytes) -> char* {
    char* p = base + off;
    off = (off + bytes + 255) & ~(size_t)255;
    return p;
  };
  unsigned short* h16  = (unsigned short*)alloc((size_t)NN * HID * 2);
  unsigned short* t16  = (unsigned short*)alloc((size_t)NN * HID * 2);
  float* dinv4    = (float*)alloc((size_t)NN * 4 * 4);
  int*   cnt      = (int*)alloc((size_t)NN * 4);
  int*   offs     = (int*)alloc((size_t)(NN + 1) * 4);
  int*   cursor   = (int*)alloc((size_t)NN * 4);
  int*   bsum     = (int*)alloc((size_t)256 * 4);
  int2*  csr_se   = (int2*)alloc((size_t)EE * 8);
  float* csr_val  = (float*)alloc((size_t)NL * EE * 4);
  float* w_all4   = (float*)alloc((size_t)EE * 4 * 4);
  unsigned short* Wt    = (unsigned short*)alloc((size_t)NL * HID * HID * 2);
  float* bprime   = (float*)alloc((size_t)NL * HID * 4);
  unsigned short* tailW = (unsigned short*)alloc((size_t)622592 * 2);
  unsigned short* edgeW = (unsigned short*)alloc((size_t)256 * 32 * 2);
  int*   flag     = (int*)alloc(256);
  float* part     = (float*)alloc((size_t)GG * PCH * HID * 4);
  float* molf32   = (float*)alloc((size_t)GG * 256 * 4);
  float* m0       = (float*)alloc((size_t)GG * MH * 4);
  float* m1       = (float*)alloc((size_t)GG * MH * 4);
  float* cat      = (float*)alloc((size_t)GG * PIN * 4);
  float* p0       = (float*)alloc((size_t)GG * PH * 4);
  float* p1       = (float*)alloc((size_t)GG * PH * 4);

  hipMemsetAsync(cnt, 0, (size_t)NN * 4, stream);
  hipMemsetAsync(cursor, 0, (size_t)NN * 4, stream);
  hipMemsetAsync(molf32, 0, (size_t)GG * 256 * 4, stream);

  // dtype probe first — everything downstream branches on it
  probe_kernel<<<1, 64, 0, stream>>>((const unsigned short*)x, flag);

  // weight prep (fused layer weights + tail + edge)
  prep_fused_w<<<256, 256, 0, stream>>>(lin_W, gW, Wt, flag);
  prep_fused_b<<<NL, 128, 0, stream>>>(cbias, gW, gb, bprime, flag);
  prep_tail<<<(622592 + 255) / 256, 256, 0, stream>>>(mlpW0, mlpW1, mlpW2, mlpW3,
                                                      predW0, predW1, tailW, flag);
  prep_edge_w<<<32, 256, 0, stream>>>(mW1, mb1, edgeW, flag);

  // x -> bf16 layer state
  {
    int n8 = NN * HID / 8;
    cvt_to_bf16<<<(n8 + 255) / 256, 256, 0, stream>>>(x, h16, n8, flag);
  }
  // edge gates (MFMA, swapped operands, 128 edges/block for occupancy)
  edge_mlp_mfma<<<(EE + EMB - 1) / EMB, 256, 0, stream>>>(eattr, edgeW, mW2, mb2,
                                                          w_all4, flag);
  // CSR build (3-phase parallel scan)
  count_kernel<<<(EE + 255) / 256, 256, 0, stream>>>(ei, cnt);
  scan_phase1<<<SCAN_B, 256, 0, stream>>>(cnt, bsum);
  scan_phase2<<<1, 256, 0, stream>>>(bsum, offs);
  scan_phase3<<<SCAN_B, 256, 0, stream>>>(cnt, bsum, offs);
  fill_kernel<<<(EE + 255) / 256, 256, 0, stream>>>(ei, offs, cursor, csr_se);
  // permute gates to CSR order, degrees, scaling
  csr_gather<<<(EE + 255) / 256, 256, 0, stream>>>(csr_se, w_all4, csr_val);
  deg_kernel<<<(NN + 255) / 256, 256, 0, stream>>>(offs, csr_val, dinv4);
  csr_scale_kernel<<<(EE + 255) / 256, 256, 0, stream>>>(csr_se, dinv4, csr_val);

  // GCN layers (fused): aggregate(h16)->t16; gemm(t16, W'_l, b'_l, relu)->h16
  const int gemm_blocks = (NN + 63) / 64;  // 782
  for (int l = 0; l < NL; l++) {
    aggregate_kernel<<<NN, 64, 0, stream>>>(h16, offs, csr_se,
                                            csr_val + (size_t)l * EE, dinv4, l, t16);
    gemm_nodes_bf16<<<gemm_blocks, 256, 0, stream>>>(
        t16, Wt + (size_t)l * HID * HID, bprime + (size_t)l * HID, h16, 1);
  }

  // pooling -> cat[:, 0:128]  (2-phase, bf16 input)
  pool_partial<<<dim3(GG, PCH), 128, 0, stream>>>(h16, batch, part);
  pool_combine<<<GG, 128, 0, stream>>>(part, batch, cat);

  // molecular MLP -> cat[:, 128:256]  (MFMA tail, K-padded weights)
  cvt_molf<<<(GG * 50 + 255) / 256, 256, 0, stream>>>(molf, molf32, flag);
  gemm_tail_mfma<<<dim3(4, 4), 256, 0, stream>>>(molf32, 256, tailW + 0,      256, mlpb0, m0, 256, 1, flag);
  gemm_tail_mfma<<<dim3(4, 4), 256, 0, stream>>>(m0,     256, tailW + 65536,  256, mlpb1, m1, 256, 1, flag);
  gemm_tail_mfma<<<dim3(4, 4), 256, 0, stream>>>(m1,     256, tailW + 131072, 256, mlpb2, m0, 256, 1, flag);
  gemm_tail_mfma<<<dim3(4, 2), 256, 0, stream>>>(m0,     256, tailW + 196608, 256, mlpb3, cat + MOUT, 256, 1, flag);

  // predictor
  gemm_tail_mfma<<<dim3(4, 8), 256, 0, stream>>>(cat, 256, tailW + 229376, 256, predb0, p0, 512, 1, flag);
  gemm_tail_mfma<<<dim3(4, 8), 256, 0, stream>>>(p0,  512, tailW + 360448, 512, predb1, p1, 512, 1, flag);
  final_kernel<<<GG, 64, 0, stream>>>(p1, outW, outb, d_out, flag);
}

// Round 9
// 567.248 us; speedup vs baseline: 1.0609x; 1.0147x over previous
//
#include <hip/hip_runtime.h>
#include <hip/hip_bf16.h>

// ---------------------------------------------------------------------------
// PDNConv GNN, MI355X round 26.
// Round-25 counters finally exposed fill_kernel: 42.6us, WRITE_SIZE 40MB for
// a 4.8MB payload (8x line-granular scatter amplification), VALUBusy 0.5%.
// Since the scatter dirties ~1 line/edge REGARDLESS of payload <=32B, widen
// the scattered record to 32B {src, g4} and carry the gates along (w_all4[e]
// read coalesced in fill). This DELETES csr_gather (a ~38MB random-gather
// pass) and improves deg locality (1 contiguous float4/edge vs 4 plane
// loads). csr_scale/aggregate read the same 32B record. Everything else =
// round-20/25 measured optimum (edge_mlp untouched as sanity anchor).
// ---------------------------------------------------------------------------

#define NN 50000
#define EE 600000
#define GG 256
#define HID 128
#define EDIM 16
#define EHID 64
#define NL 4
#define MIN_F 200
#define MH 256
#define MOUT 128
#define PH 512
#define PIN 256
#define SCAN_B 196  // ceil(NN/256)
#define PCH 8       // pooling chunks per graph
#define EMB 128     // edges per block (edge_mlp)

typedef __hip_bfloat16 bf16;
typedef __attribute__((ext_vector_type(8))) short bf16x8;
typedef __attribute__((ext_vector_type(4))) float f32x4;

__device__ __forceinline__ float bfl(unsigned u) { return __uint_as_float(u << 16); }
__device__ __forceinline__ float bfh(unsigned u) { return __uint_as_float(u & 0xffff0000u); }
__device__ __forceinline__ float b2f(bf16 x) { return __bfloat162float(x); }
__device__ __forceinline__ float ldf(const void* p, long i, bool bf) {
  return bf ? __bfloat162float(((const bf16*)p)[i]) : ((const float*)p)[i];
}
__device__ __forceinline__ unsigned short f2bf_bits(float v) {
  bf16 h = __float2bfloat16(v);
  return *reinterpret_cast<unsigned short*>(&h);
}

// ---------------- dtype probe ------------------------------------------------
__global__ void probe_kernel(const unsigned short* __restrict__ xs, int* flag) {
  if (threadIdx.x == 0 && blockIdx.x == 0) {
    int sane = 0;
    for (int i = 0; i < 128; i++) {
      unsigned e = (xs[i] >> 7) & 0xFF;
      if (e >= 96 && e <= 159) sane++;
    }
    *flag = (sane >= 112) ? 1 : 0;  // 1 = bf16 inputs
  }
}

// ---------------- input -> bf16 conversion (8 elems/thread) -----------------
__global__ __launch_bounds__(256) void cvt_to_bf16(const void* __restrict__ in,
                                                   unsigned short* __restrict__ outp,
                                                   int n8, const int* __restrict__ flag) {
  bool bf = *flag != 0;
  int i = blockIdx.x * 256 + threadIdx.x;
  if (i >= n8) return;
  if (bf) {
    reinterpret_cast<uint4*>(outp)[i] = reinterpret_cast<const uint4*>(in)[i];
  } else {
    const float4* p = reinterpret_cast<const float4*>(in) + (size_t)i * 2;
    float4 v0 = p[0], v1 = p[1];
    ushort4 a, b;
    a.x = f2bf_bits(v0.x); a.y = f2bf_bits(v0.y);
    a.z = f2bf_bits(v0.z); a.w = f2bf_bits(v0.w);
    b.x = f2bf_bits(v1.x); b.y = f2bf_bits(v1.y);
    b.z = f2bf_bits(v1.z); b.w = f2bf_bits(v1.w);
    reinterpret_cast<ushort4*>(outp)[i * 2] = a;
    reinterpret_cast<ushort4*>(outp)[i * 2 + 1] = b;
  }
}

// ---------------- mol_features [G,200] -> padded f32 [G,256] ----------------
__global__ __launch_bounds__(256) void cvt_molf(const void* __restrict__ in,
                                                float* __restrict__ outp,
                                                const int* __restrict__ flag) {
  bool bf = *flag != 0;
  int i = blockIdx.x * 256 + threadIdx.x;  // GG*50
  if (i >= GG * 50) return;
  int row = i / 50, c4 = (i % 50) * 4;
  float4 v;
  if (bf) {
    const unsigned short* p = (const unsigned short*)in + (size_t)row * MIN_F + c4;
    uint2 u = *reinterpret_cast<const uint2*>(p);
    v.x = bfl(u.x); v.y = bfh(u.x); v.z = bfl(u.y); v.w = bfh(u.y);
  } else {
    v = *reinterpret_cast<const float4*>((const float*)in + (size_t)row * MIN_F + c4);
  }
  *reinterpret_cast<float4*>(&outp[(size_t)row * 256 + c4]) = v;
}

// ---------------- weight prep: fused W'_l = linW_l @ gW_l -> bf16 [n][k] ----
__global__ __launch_bounds__(256) void prep_fused_w(const void* __restrict__ lin_W,
                                                    const void* __restrict__ gW,
                                                    unsigned short* __restrict__ Wt,
                                                    const int* __restrict__ flag) {
  bool bf = *flag != 0;
  int idx = blockIdx.x * 256 + threadIdx.x;  // 0 .. 4*16384-1
  if (idx >= 4 * 16384) return;
  int l = idx >> 14;
  int rem = idx & 16383;
  int n = rem >> 7, k = rem & 127;  // Wt[n][k] = W'[k][n]
  float s = 0.f;
  long lb = (long)l * 16384;
  for (int m = 0; m < 128; m++)
    s += ldf(lin_W, lb + (long)k * 128 + m, bf) * ldf(gW, lb + (long)m * 128 + n, bf);
  Wt[idx] = f2bf_bits(s);
}

// b'_l[n] = gb_l[n] + sum_k cbias_l[k] * gW_l[k][n]   (f32)
__global__ __launch_bounds__(128) void prep_fused_b(const void* __restrict__ cbias,
                                                    const void* __restrict__ gW,
                                                    const void* __restrict__ gb,
                                                    float* __restrict__ bprime,
                                                    const int* __restrict__ flag) {
  bool bf = *flag != 0;
  int idx = blockIdx.x * 128 + threadIdx.x;  // 0 .. 4*128-1
  if (idx >= NL * HID) return;
  int l = idx >> 7, n = idx & 127;
  float s = ldf(gb, idx, bf);
  long lb = (long)l * 16384;
  for (int k = 0; k < 128; k++)
    s += ldf(cbias, (long)l * 128 + k, bf) * ldf(gW, lb + (long)k * 128 + n, bf);
  bprime[idx] = s;
}

// ---------------- weight prep: edge MLP W1 -> bf16 W1t[256 cols][32 K] ------
// k<16: W1; k==16: b1 (MFMA bias-fold); k>16: 0.
__global__ __launch_bounds__(256) void prep_edge_w(const void* __restrict__ mW1,
                                                   const void* __restrict__ mb1,
                                                   unsigned short* __restrict__ W1t,
                                                   const int* __restrict__ flag) {
  bool bf = *flag != 0;
  int idx = blockIdx.x * 256 + threadIdx.x;  // 256*32
  if (idx >= 256 * 32) return;
  int col = idx >> 5, k = idx & 31;
  float v = 0.f;
  if (k < EDIM) v = ldf(mW1, (long)(col >> 6) * (EDIM * EHID) + (long)k * EHID + (col & 63), bf);
  else if (k == EDIM) v = ldf(mb1, col, bf);
  W1t[idx] = f2bf_bits(v);
}

// ---------------- weight prep: tail (MLP+predictor) -> bf16 [N][Kp], K-pad --
__global__ __launch_bounds__(256) void prep_tail(
    const void* __restrict__ mlpW0, const void* __restrict__ mlpW1,
    const void* __restrict__ mlpW2, const void* __restrict__ mlpW3,
    const void* __restrict__ predW0, const void* __restrict__ predW1,
    unsigned short* __restrict__ T, const int* __restrict__ flag) {
  bool bf = *flag != 0;
  int idx = blockIdx.x * 256 + threadIdx.x;
  const void* src; int N, Kp, Ksrc, off;
  if      (idx < 65536)  { src = mlpW0;  N = 256; Kp = 256; Ksrc = 200; off = 0; }
  else if (idx < 131072) { src = mlpW1;  N = 256; Kp = 256; Ksrc = 256; off = 65536; }
  else if (idx < 196608) { src = mlpW2;  N = 256; Kp = 256; Ksrc = 256; off = 131072; }
  else if (idx < 229376) { src = mlpW3;  N = 128; Kp = 256; Ksrc = 256; off = 196608; }
  else if (idx < 360448) { src = predW0; N = 512; Kp = 256; Ksrc = 256; off = 229376; }
  else if (idx < 622592) { src = predW1; N = 512; Kp = 512; Ksrc = 512; off = 360448; }
  else return;
  int rem = idx - off;
  int n = rem / Kp, k = rem % Kp;
  float v = (k < Ksrc) ? ldf(src, (long)k * N + n, bf) : 0.f;
  T[idx] = f2bf_bits(v);
}

// ---------------- CSR build: histogram / 3-phase scan / fill ----------------
__global__ __launch_bounds__(256) void count_kernel(const int* __restrict__ ei,
                                                    int* __restrict__ cnt) {
  int e = blockIdx.x * 256 + threadIdx.x;
  if (e >= EE) return;
  int c = ei[EE + e];
  c = min(max(c, 0), NN - 1);
  atomicAdd(&cnt[c], 1);
}

__global__ __launch_bounds__(256) void scan_phase1(const int* __restrict__ cnt,
                                                   int* __restrict__ bsum) {
  __shared__ int red[256];
  int tid = threadIdx.x;
  int i = blockIdx.x * 256 + tid;
  red[tid] = (i < NN) ? cnt[i] : 0;
  __syncthreads();
  for (int off = 128; off > 0; off >>= 1) {
    if (tid < off) red[tid] += red[tid + off];
    __syncthreads();
  }
  if (tid == 0) bsum[blockIdx.x] = red[0];
}

__global__ __launch_bounds__(256) void scan_phase2(int* __restrict__ bsum,
                                                   int* __restrict__ offs) {
  __shared__ int buf[256];
  int tid = threadIdx.x;
  int v = (tid < SCAN_B) ? bsum[tid] : 0;
  buf[tid] = v;
  __syncthreads();
  for (int off = 1; off < 256; off <<= 1) {
    int t = (tid >= off) ? buf[tid - off] : 0;
    __syncthreads();
    buf[tid] += t;
    __syncthreads();
  }
  if (tid < SCAN_B) bsum[tid] = buf[tid] - v;  // exclusive block offsets
  if (tid == 255) offs[NN] = buf[255];
}

__global__ __launch_bounds__(256) void scan_phase3(const int* __restrict__ cnt,
                                                   const int* __restrict__ bsum,
                                                   int* __restrict__ offs) {
  __shared__ int buf[256];
  int tid = threadIdx.x;
  int i = blockIdx.x * 256 + tid;
  int v = (i < NN) ? cnt[i] : 0;
  buf[tid] = v;
  __syncthreads();
  for (int off = 1; off < 256; off <<= 1) {
    int t = (tid >= off) ? buf[tid - off] : 0;
    __syncthreads();
    buf[tid] += t;
    __syncthreads();
  }
  if (i < NN) offs[i] = bsum[blockIdx.x] + buf[tid] - v;
}

// fill: scatter 32B record {src, g4} per CSR slot. Same dirty-line count as
// the old 8B int2 scatter (<=1 line/edge); gates carried along for free.
__global__ __launch_bounds__(256) void fill_kernel(const int* __restrict__ ei,
                                                   const int* __restrict__ offs,
                                                   int* __restrict__ cursor,
                                                   const float4* __restrict__ w_all4,
                                                   char* __restrict__ csr_rec) {
  int e = blockIdx.x * 256 + threadIdx.x;
  if (e >= EE) return;
  int c = ei[EE + e];
  c = min(max(c, 0), NN - 1);
  int src = min(max(ei[e], 0), NN - 1);
  float4 g = w_all4[e];  // coalesced
  int pos = offs[c] + atomicAdd(&cursor[c], 1);
  pos = min(max(pos, 0), EE - 1);
  char* r = csr_rec + (size_t)pos * 32;
  *reinterpret_cast<int*>(r) = src;
  *reinterpret_cast<float4*>(r + 16) = g;
}

// ---------------- edge-gate MLP via MFMA: swapped operands, 128 e/blk -------
// (exact round-20 form — best measured: ~42us, occ ~60%)
__global__ __launch_bounds__(256) void edge_mlp_mfma(
    const void* __restrict__ eattr, const unsigned short* __restrict__ W1t,
    const void* __restrict__ mW2, const void* __restrict__ mb2,
    float* __restrict__ w_all4, const int* __restrict__ flag) {
  bool bf = *flag != 0;
  int tid = threadIdx.x;
  int wave = tid >> 6, lane = tid & 63;  // wave == layer index
  int l15 = lane & 15, quad = lane >> 4;

  bf16x8 afrag[4];
#pragma unroll
  for (int t = 0; t < 4; t++)
    afrag[t] =
        *reinterpret_cast<const bf16x8*>(&W1t[((wave * 4 + t) * 16 + l15) * 32 + quad * 8]);

  float w2v[16];
#pragma unroll
  for (int t = 0; t < 4; t++)
#pragma unroll
    for (int r = 0; r < 4; r++)
      w2v[t * 4 + r] = ldf(mW2, wave * 64 + t * 16 + quad * 4 + r, bf);
  float b2 = ldf(mb2, wave, bf);

  bf16x8 bconst = (bf16x8){0, 0, 0, 0, 0, 0, 0, 0};
  if (quad == 2) bconst[0] = (short)0x3F80;  // k=16 element = bf16(1.0)

  int ebase = blockIdx.x * EMB;
  int rowbytes = bf ? EDIM * 2 : EDIM * 4;
  const char* p = (const char*)eattr + (size_t)(ebase + l15) * rowbytes +
                  (size_t)quad * (rowbytes >> 1);
  int fragstep = 16 * rowbytes;

  auto loadb = [&](int fb, const char* pp) -> bf16x8 {
    bf16x8 v = bconst;
    if (quad < 2 && fb < EE) {
      if (bf) {
        v = *reinterpret_cast<const bf16x8*>(pp);
      } else {
        const float4* q = reinterpret_cast<const float4*>(pp);
        float4 v0 = q[0], v1 = q[1];
        v[0] = (short)f2bf_bits(v0.x); v[1] = (short)f2bf_bits(v0.y);
        v[2] = (short)f2bf_bits(v0.z); v[3] = (short)f2bf_bits(v0.w);
        v[4] = (short)f2bf_bits(v1.x); v[5] = (short)f2bf_bits(v1.y);
        v[6] = (short)f2bf_bits(v1.z); v[7] = (short)f2bf_bits(v1.w);
      }
    }
    return v;
  };

  bf16x8 bcur = loadb(ebase, p);
#pragma unroll 2
  for (int f = 0; f < EMB / 16; f++) {
    int fbase = ebase + f * 16;
    p += fragstep;
    bf16x8 bnxt = loadb(fbase + 16, p);  // prefetch next fragment
    if (fbase < EE) {
      float s0 = 0.f, s1 = 0.f, s2 = 0.f, s3 = 0.f;
#define DO_T(T, S)                                                            \
  {                                                                           \
    f32x4 acc = __builtin_amdgcn_mfma_f32_16x16x32_bf16(                      \
        afrag[T], bcur, (f32x4){0.f, 0.f, 0.f, 0.f}, 0, 0, 0);                \
    S = fmaf(fmaxf(acc.x, 0.f), w2v[T * 4 + 0], S);                           \
    S = fmaf(fmaxf(acc.y, 0.f), w2v[T * 4 + 1], S);                           \
    S = fmaf(fmaxf(acc.z, 0.f), w2v[T * 4 + 2], S);                           \
    S = fmaf(fmaxf(acc.w, 0.f), w2v[T * 4 + 3], S);                           \
  }
      DO_T(0, s0) DO_T(1, s1) DO_T(2, s2) DO_T(3, s3)
#undef DO_T
      float s = (s0 + s1) + (s2 + s3);
      s += __shfl_xor(s, 16);  // combine quads 0<->1, 2<->3
      s += __shfl_xor(s, 32);  // combine halves
      if (quad == 0) {
        float g = 1.f / (1.f + __expf(-(s + b2)));
        w_all4[(size_t)(fbase + l15) * 4 + wave] = g;
      }
    }
    bcur = bnxt;
  }
}

// ---------------- degree / dinv per layer (reads 32B records) ---------------
__global__ __launch_bounds__(256) void deg_kernel(const int* __restrict__ offs,
                                                  const char* __restrict__ csr_rec,
                                                  float* __restrict__ dinv4) {
  int n = blockIdx.x * 256 + threadIdx.x;
  if (n >= NN) return;
  int s = offs[n], e = offs[n + 1];
  float d0 = 1.f, d1 = 1.f, d2 = 1.f, d3 = 1.f;  // self-loop weight 1.0
  for (int k = s; k < e; k++) {
    float4 g = *reinterpret_cast<const float4*>(csr_rec + (size_t)k * 32 + 16);
    d0 += g.x; d1 += g.y; d2 += g.z; d3 += g.w;
  }
  float4 o;
  o.x = rsqrtf(d0); o.y = rsqrtf(d1); o.z = rsqrtf(d2); o.w = rsqrtf(d3);
  reinterpret_cast<float4*>(dinv4)[n] = o;
}

// rec.g *= dinv4[rec.src]  (elementwise over the 4 layers)
__global__ __launch_bounds__(256) void csr_scale_kernel(char* __restrict__ csr_rec,
                                                        const float* __restrict__ dinv4) {
  int k = blockIdx.x * 256 + threadIdx.x;
  if (k >= EE) return;
  char* r = csr_rec + (size_t)k * 32;
  int s = *reinterpret_cast<const int*>(r);
  s = min(max(s, 0), NN - 1);
  float4 d = reinterpret_cast<const float4*>(dinv4)[s];
  float4* gp = reinterpret_cast<float4*>(r + 16);
  float4 g = *gp;
  g.x *= d.x; g.y *= d.y; g.z *= d.z; g.w *= d.w;
  *gp = g;
}

// ---------------- node GEMM via MFMA: bf16 in/out, f32 bias -----------------
__global__ __launch_bounds__(256) void gemm_nodes_bf16(
    const unsigned short* __restrict__ A16, const unsigned short* __restrict__ Wt,
    const float* __restrict__ bias, unsigned short* __restrict__ out16,
    int relu) {
  __shared__ alignas(16) unsigned short sA[64 * 136];
  __shared__ alignas(16) unsigned short sW[128 * 136];
  int tid = threadIdx.x;
  int rbase = blockIdx.x * 64;

#pragma unroll
  for (int p = 0; p < 8; p++) {
    int idx8 = p * 256 + tid;
    int n = idx8 >> 4, kc = idx8 & 15;
    uint4 v = reinterpret_cast<const uint4*>(Wt)[idx8];
    *reinterpret_cast<uint4*>(&sW[n * 136 + kc * 8]) = v;
  }
#pragma unroll
  for (int p = 0; p < 4; p++) {
    int idx8 = p * 256 + tid;
    int m = idx8 >> 4, kc = idx8 & 15;
    int row = rbase + m;
    uint4 v = make_uint4(0u, 0u, 0u, 0u);
    if (row < NN)
      v = *reinterpret_cast<const uint4*>(&A16[(size_t)row * HID + kc * 8]);
    *reinterpret_cast<uint4*>(&sA[m * 136 + kc * 8]) = v;
  }
  __syncthreads();

  int wave = tid >> 6, lane = tid & 63;
  int l15 = lane & 15, quad = lane >> 4;
  int mstrip = wave * 16;

  f32x4 acc[8];
#pragma unroll
  for (int t = 0; t < 8; t++) acc[t] = (f32x4){0.f, 0.f, 0.f, 0.f};

#pragma unroll
  for (int ks = 0; ks < 4; ks++) {
    int k0 = ks * 32 + quad * 8;
    bf16x8 a = *reinterpret_cast<const bf16x8*>(&sA[(mstrip + l15) * 136 + k0]);
#pragma unroll
    for (int t = 0; t < 8; t++) {
      bf16x8 b = *reinterpret_cast<const bf16x8*>(&sW[(t * 16 + l15) * 136 + k0]);
      acc[t] = __builtin_amdgcn_mfma_f32_16x16x32_bf16(a, b, acc[t], 0, 0, 0);
    }
  }

#pragma unroll
  for (int t = 0; t < 8; t++) {
    int n = t * 16 + l15;
    float bv = bias ? bias[n] : 0.f;
#pragma unroll
    for (int r = 0; r < 4; r++) {
      int row = rbase + mstrip + quad * 4 + r;
      if (row < NN) {
        float o = acc[t][r] + bv;
        if (relu) o = fmaxf(o, 0.f);
        out16[(size_t)row * HID + n] = f2bf_bits(o);
      }
    }
  }
}

// ---------------- tail GEMM via MFMA ----------------------------------------
__global__ __launch_bounds__(256) void gemm_tail_mfma(
    const float* __restrict__ A, int lda, const unsigned short* __restrict__ Wt,
    int Kp, const void* __restrict__ bias, float* __restrict__ outp, int ldo,
    int relu, const int* __restrict__ flag) {
  __shared__ alignas(16) unsigned short sA[64 * 264];
  __shared__ alignas(16) unsigned short sW[64 * 264];
  int tid = threadIdx.x;
  int rbase = blockIdx.x * 64;
  int nbase = blockIdx.y * 64;
  int wave = tid >> 6, lane = tid & 63;
  int l15 = lane & 15, quad = lane >> 4;
  int mstrip = wave * 16;

  f32x4 acc[4];
#pragma unroll
  for (int t = 0; t < 4; t++) acc[t] = (f32x4){0.f, 0.f, 0.f, 0.f};

  for (int kc = 0; kc < Kp; kc += 256) {
#pragma unroll 4
    for (int p = 0; p < 16; p++) {
      int idx = p * 1024 + tid * 4;
      int m = idx >> 8, k = idx & 255;
      float4 v = *reinterpret_cast<const float4*>(&A[(size_t)(rbase + m) * lda + kc + k]);
      ushort4 b;
      b.x = f2bf_bits(v.x); b.y = f2bf_bits(v.y);
      b.z = f2bf_bits(v.z); b.w = f2bf_bits(v.w);
      *reinterpret_cast<ushort4*>(&sA[m * 264 + k]) = b;
    }
#pragma unroll 4
    for (int p = 0; p < 8; p++) {
      int idx8 = p * 256 + tid;
      int n = idx8 >> 5, kk = (idx8 & 31) * 8;
      uint4 v = *reinterpret_cast<const uint4*>(&Wt[(size_t)(nbase + n) * Kp + kc + kk]);
      *reinterpret_cast<uint4*>(&sW[n * 264 + kk]) = v;
    }
    __syncthreads();
#pragma unroll
    for (int ks = 0; ks < 8; ks++) {
      int k0 = ks * 32 + quad * 8;
      bf16x8 a = *reinterpret_cast<const bf16x8*>(&sA[(mstrip + l15) * 264 + k0]);
#pragma unroll
      for (int nt = 0; nt < 4; nt++) {
        bf16x8 b = *reinterpret_cast<const bf16x8*>(&sW[(nt * 16 + l15) * 264 + k0]);
        acc[nt] = __builtin_amdgcn_mfma_f32_16x16x32_bf16(a, b, acc[nt], 0, 0, 0);
      }
    }
    __syncthreads();
  }

  bool bf = *flag != 0;
#pragma unroll
  for (int nt = 0; nt < 4; nt++) {
    int col = nbase + nt * 16 + l15;
    float bv = ldf(bias, col, bf);
#pragma unroll
    for (int r = 0; r < 4; r++) {
      int row = rbase + mstrip + quad * 4 + r;
      float o = acc[nt][r] + bv;
      if (relu) o = fmaxf(o, 0.f);
      outp[(size_t)row * ldo + col] = o;
    }
  }
}

// ---------------- aggregation: 1 wave/node, 16B lane gathers, 4 j-slots -----
// lane = (grp = lane>>4 in 0..3, c16 = lane&15). Per j, grp's 16 lanes load
// the full 256B row (16B each). Group partials combined via shfl_xor 16/32.
// Staging reads the 32B record {src, g4}; val = g4[layer] (pre-scaled).
// out16[n] = dn*(sum_k val_k*h16[src_k]) + dn^2*h16[n]
__global__ __launch_bounds__(64) void aggregate_kernel(
    const unsigned short* __restrict__ h16, const int* __restrict__ offs,
    const char* __restrict__ csr_rec, const float* __restrict__ dinv4,
    int layer, unsigned short* __restrict__ out16) {
  int n = blockIdx.x;
  int lane = threadIdx.x;      // 0..63
  int grp = lane >> 4;         // j-slot
  int c16 = lane & 15;         // 16B channel chunk (8 bf16)
  __shared__ int s_src[64];
  __shared__ float s_val[64];
  int start = offs[n], end = offs[n + 1];
  float a0 = 0.f, a1 = 0.f, a2 = 0.f, a3 = 0.f;
  float a4 = 0.f, a5 = 0.f, a6 = 0.f, a7 = 0.f;
  for (int base = start; base < end; base += 64) {
    int k = base + lane;
    if (k < end) {
      const char* r = csr_rec + (size_t)k * 32;
      int sv = *reinterpret_cast<const int*>(r);
      float4 g = *reinterpret_cast<const float4*>(r + 16);
      float v = (layer == 0) ? g.x : (layer == 1) ? g.y : (layer == 2) ? g.z : g.w;
      s_src[lane] = min(max(sv, 0), NN - 1);
      s_val[lane] = v;
    }
    __syncthreads();
    int m = min(64, end - base);
    for (int j = grp; j < m; j += 4) {
      float v = s_val[j];
      uint4 u = *reinterpret_cast<const uint4*>(&h16[(size_t)s_src[j] * HID + c16 * 8]);
      a0 = fmaf(v, bfl(u.x), a0); a1 = fmaf(v, bfh(u.x), a1);
      a2 = fmaf(v, bfl(u.y), a2); a3 = fmaf(v, bfh(u.y), a3);
      a4 = fmaf(v, bfl(u.z), a4); a5 = fmaf(v, bfh(u.z), a5);
      a6 = fmaf(v, bfl(u.w), a6); a7 = fmaf(v, bfh(u.w), a7);
    }
    __syncthreads();
  }
  // combine the 4 j-slot groups (no barriers — in-wave shuffles)
  a0 += __shfl_xor(a0, 16); a1 += __shfl_xor(a1, 16);
  a2 += __shfl_xor(a2, 16); a3 += __shfl_xor(a3, 16);
  a4 += __shfl_xor(a4, 16); a5 += __shfl_xor(a5, 16);
  a6 += __shfl_xor(a6, 16); a7 += __shfl_xor(a7, 16);
  a0 += __shfl_xor(a0, 32); a1 += __shfl_xor(a1, 32);
  a2 += __shfl_xor(a2, 32); a3 += __shfl_xor(a3, 32);
  a4 += __shfl_xor(a4, 32); a5 += __shfl_xor(a5, 32);
  a6 += __shfl_xor(a6, 32); a7 += __shfl_xor(a7, 32);
  if (grp == 0) {
    float dn = dinv4[(size_t)n * 4 + layer];
    float dn2 = dn * dn;
    uint4 su = *reinterpret_cast<const uint4*>(&h16[(size_t)n * HID + c16 * 8]);
    ushort4 o0, o1v;
    o0.x  = f2bf_bits(dn * a0 + dn2 * bfl(su.x));
    o0.y  = f2bf_bits(dn * a1 + dn2 * bfh(su.x));
    o0.z  = f2bf_bits(dn * a2 + dn2 * bfl(su.y));
    o0.w  = f2bf_bits(dn * a3 + dn2 * bfh(su.y));
    o1v.x = f2bf_bits(dn * a4 + dn2 * bfl(su.z));
    o1v.y = f2bf_bits(dn * a5 + dn2 * bfh(su.z));
    o1v.z = f2bf_bits(dn * a6 + dn2 * bfl(su.w));
    o1v.w = f2bf_bits(dn * a7 + dn2 * bfh(su.w));
    *reinterpret_cast<ushort4*>(&out16[(size_t)n * HID + c16 * 8]) = o0;
    *reinterpret_cast<ushort4*>(&out16[(size_t)n * HID + c16 * 8 + 4]) = o1v;
  }
}

// ---------------- mean pool, 2-phase (bf16 input) ---------------------------
__global__ __launch_bounds__(128) void pool_partial(const unsigned short* __restrict__ h16,
                                                    const int* __restrict__ batch,
                                                    float* __restrict__ part) {
  int g = blockIdx.x, chunk = blockIdx.y, c = threadIdx.x;
  int lo = 0, hi = NN;
  while (lo < hi) { int mid = (lo + hi) >> 1; if (batch[mid] < g) lo = mid + 1; else hi = mid; }
  int start = lo;
  hi = NN;
  while (lo < hi) { int mid = (lo + hi) >> 1; if (batch[mid] < g + 1) lo = mid + 1; else hi = mid; }
  int end = lo;
  int len = end - start;
  int per = (len + PCH - 1) / PCH;
  int s = start + chunk * per;
  int e = min(s + per, end);
  float sum = 0.f;
  for (int n = s; n < e; n++) sum += bfl((unsigned)h16[(size_t)n * HID + c]);
  part[((size_t)g * PCH + chunk) * HID + c] = sum;
}

__global__ __launch_bounds__(128) void pool_combine(const float* __restrict__ part,
                                                    const int* __restrict__ batch,
                                                    float* __restrict__ cat) {
  int g = blockIdx.x, c = threadIdx.x;
  int lo = 0, hi = NN;
  while (lo < hi) { int mid = (lo + hi) >> 1; if (batch[mid] < g) lo = mid + 1; else hi = mid; }
  int start = lo;
  hi = NN;
  while (lo < hi) { int mid = (lo + hi) >> 1; if (batch[mid] < g + 1) lo = mid + 1; else hi = mid; }
  int end = lo;
  float s = 0.f;
#pragma unroll
  for (int k = 0; k < PCH; k++) s += part[((size_t)g * PCH + k) * HID + c];
  float cntf = (float)(end - start);
  cat[(size_t)g * PIN + c] = s / fmaxf(cntf, 1.f);
}

// ---------------- final [G,512] @ [512,1] + b -> out ------------------------
__global__ __launch_bounds__(64) void final_kernel(const float* __restrict__ A,
                                                   const void* __restrict__ W,
                                                   const void* __restrict__ b,
                                                   void* __restrict__ outp,
                                                   const int* __restrict__ flag) {
  bool bf = *flag != 0;
  int g = blockIdx.x, lane = threadIdx.x;
  float s = 0.f;
  for (int k = lane; k < PH; k += 64) s = fmaf(A[(size_t)g * PH + k], ldf(W, k, bf), s);
#pragma unroll
  for (int off = 32; off > 0; off >>= 1) s += __shfl_down(s, off);
  if (lane == 0) {
    float r = s + ldf(b, 0, bf);
    if (bf) ((bf16*)outp)[g] = __float2bfloat16(r);
    else    ((float*)outp)[g] = r;
  }
}

// ---------------------------------------------------------------------------
extern "C" void kernel_launch(void* const* d_in, const int* in_sizes, int n_in,
                              void* d_out, int out_size, void* d_ws, size_t ws_size,
                              hipStream_t stream) {
  const void* x      = d_in[0];
  const int*  ei     = (const int*)d_in[1];
  const void* eattr  = d_in[2];
  const int*  batch  = (const int*)d_in[3];
  const void* molf   = d_in[4];
  const void* lin_W  = d_in[5];
  const void* mW1    = d_in[6];
  const void* mb1    = d_in[7];
  const void* mW2    = d_in[8];
  const void* mb2    = d_in[9];
  const void* cbias  = d_in[10];
  const void* gW     = d_in[11];
  const void* gb     = d_in[12];
  const void* mlpW0  = d_in[13];
  const void* mlpb0  = d_in[14];
  const void* mlpW1  = d_in[15];
  const void* mlpb1  = d_in[16];
  const void* mlpW2  = d_in[17];
  const void* mlpb2  = d_in[18];
  const void* mlpW3  = d_in[19];
  const void* mlpb3  = d_in[20];
  const void* predW0 = d_in[21];
  const void* predb0 = d_in[22];
  const void* predW1 = d_in[23];
  const void* predb1 = d_in[24];
  const void* outW   = d_in[25];
  const void* outb   = d_in[26];

  char* base = (char*)d_ws;
  size_t off = 0;
  auto alloc = [&](size_t bytes) -> char* {
    char* p = base + off;
    off = (off + bytes + 255) & ~(size_t)255;
    return p;
  };
  unsigned short* h16  = (unsigned short*)alloc((size_t)NN * HID * 2);
  unsigned short* t16  = (unsigned short*)alloc((size_t)NN * HID * 2);
  float* dinv4    = (float*)alloc((size_t)NN * 4 * 4);
  int*   cnt      = (int*)alloc((size_t)NN * 4);
  int*   offs     = (int*)alloc((size_t)(NN + 1) * 4);
  int*   cursor   = (int*)alloc((size_t)NN * 4);
  int*   bsum     = (int*)alloc((size_t)256 * 4);
  char*  csr_rec  = alloc((size_t)EE * 32);
  float* w_all4   = (float*)alloc((size_t)EE * 4 * 4);
  unsigned short* Wt    = (unsigned short*)alloc((size_t)NL * HID * HID * 2);
  float* bprime   = (float*)alloc((size_t)NL * HID * 4);
  unsigned short* tailW = (unsigned short*)alloc((size_t)622592 * 2);
  unsigned short* edgeW = (unsigned short*)alloc((size_t)256 * 32 * 2);
  int*   flag     = (int*)alloc(256);
  float* part     = (float*)alloc((size_t)GG * PCH * HID * 4);
  float* molf32   = (float*)alloc((size_t)GG * 256 * 4);
  float* m0       = (float*)alloc((size_t)GG * MH * 4);
  float* m1       = (float*)alloc((size_t)GG * MH * 4);
  float* cat      = (float*)alloc((size_t)GG * PIN * 4);
  float* p0       = (float*)alloc((size_t)GG * PH * 4);
  float* p1       = (float*)alloc((size_t)GG * PH * 4);

  hipMemsetAsync(cnt, 0, (size_t)NN * 4, stream);
  hipMemsetAsync(cursor, 0, (size_t)NN * 4, stream);
  hipMemsetAsync(molf32, 0, (size_t)GG * 256 * 4, stream);

  // dtype probe first — everything downstream branches on it
  probe_kernel<<<1, 64, 0, stream>>>((const unsigned short*)x, flag);

  // weight prep (fused layer weights + tail + edge)
  prep_fused_w<<<256, 256, 0, stream>>>(lin_W, gW, Wt, flag);
  prep_fused_b<<<NL, 128, 0, stream>>>(cbias, gW, gb, bprime, flag);
  prep_tail<<<(622592 + 255) / 256, 256, 0, stream>>>(mlpW0, mlpW1, mlpW2, mlpW3,
                                                      predW0, predW1, tailW, flag);
  prep_edge_w<<<32, 256, 0, stream>>>(mW1, mb1, edgeW, flag);

  // x -> bf16 layer state
  {
    int n8 = NN * HID / 8;
    cvt_to_bf16<<<(n8 + 255) / 256, 256, 0, stream>>>(x, h16, n8, flag);
  }
  // edge gates (MFMA, round-20 form)
  edge_mlp_mfma<<<(EE + EMB - 1) / EMB, 256, 0, stream>>>(eattr, edgeW, mW2, mb2,
                                                          w_all4, flag);
  // CSR build (3-phase parallel scan); fill scatters {src, gates} 32B records
  count_kernel<<<(EE + 255) / 256, 256, 0, stream>>>(ei, cnt);
  scan_phase1<<<SCAN_B, 256, 0, stream>>>(cnt, bsum);
  scan_phase2<<<1, 256, 0, stream>>>(bsum, offs);
  scan_phase3<<<SCAN_B, 256, 0, stream>>>(cnt, bsum, offs);
  fill_kernel<<<(EE + 255) / 256, 256, 0, stream>>>(ei, offs, cursor,
                                                    (const float4*)w_all4, csr_rec);
  // degrees + in-place gate scaling (csr_gather deleted)
  deg_kernel<<<(NN + 255) / 256, 256, 0, stream>>>(offs, csr_rec, dinv4);
  csr_scale_kernel<<<(EE + 255) / 256, 256, 0, stream>>>(csr_rec, dinv4);

  // GCN layers (fused): aggregate(h16)->t16; gemm(t16, W'_l, b'_l, relu)->h16
  const int gemm_blocks = (NN + 63) / 64;  // 782
  for (int l = 0; l < NL; l++) {
    aggregate_kernel<<<NN, 64, 0, stream>>>(h16, offs, csr_rec, dinv4, l, t16);
    gemm_nodes_bf16<<<gemm_blocks, 256, 0, stream>>>(
        t16, Wt + (size_t)l * HID * HID, bprime + (size_t)l * HID, h16, 1);
  }

  // pooling -> cat[:, 0:128]  (2-phase, bf16 input)
  pool_partial<<<dim3(GG, PCH), 128, 0, stream>>>(h16, batch, part);
  pool_combine<<<GG, 128, 0, stream>>>(part, batch, cat);

  // molecular MLP -> cat[:, 128:256]  (MFMA tail, K-padded weights)
  cvt_molf<<<(GG * 50 + 255) / 256, 256, 0, stream>>>(molf, molf32, flag);
  gemm_tail_mfma<<<dim3(4, 4), 256, 0, stream>>>(molf32, 256, tailW + 0,      256, mlpb0, m0, 256, 1, flag);
  gemm_tail_mfma<<<dim3(4, 4), 256, 0, stream>>>(m0,     256, tailW + 65536,  256, mlpb1, m1, 256, 1, flag);
  gemm_tail_mfma<<<dim3(4, 4), 256, 0, stream>>>(m1,     256, tailW + 131072, 256, mlpb2, m0, 256, 1, flag);
  gemm_tail_mfma<<<dim3(4, 2), 256, 0, stream>>>(m0,     256, tailW + 196608, 256, mlpb3, cat + MOUT, 256, 1, flag);

  // predictor
  gemm_tail_mfma<<<dim3(4, 8), 256, 0, stream>>>(cat, 256, tailW + 229376, 256, predb0, p0, 512, 1, flag);
  gemm_tail_mfma<<<dim3(4, 8), 256, 0, stream>>>(p0,  512, tailW + 360448, 512, predb1, p1, 512, 1, flag);
  final_kernel<<<GG, 64, 0, stream>>>(p1, outW, outb, d_out, flag);
}

// Round 11
// 548.751 us; speedup vs baseline: 1.0966x; 1.0337x over previous
//
#include <hip/hip_runtime.h>
#include <hip/hip_bf16.h>

// ---------------------------------------------------------------------------
// PDNConv GNN, MI355X round 28 — RESUBMIT of round 27 (infra failure, no data).
// Round-26 WIN (567us, best): 32B {src,g4} records deleted csr_gather.
// fill_kernel now #1 (45us, VALUBusy 0.5%, 13% HBM): bound by TCC atomic
// serialization — cursor is 200KB so 16 nodes/64B-line -> ~192 serialized
// atomics per line, and we pay the identical atomic pass twice (count+fill).
// This round: (1) count's atomicAdd RETURNS the rank -> store rank[e]; fill
// becomes atomic-free pure scatter; cursor buffer deleted. Total atomics
// halve. (2) pad counters to one per 64B line (cntp[c*16]) -> per-line
// contention 192 -> ~12 (avg degree). Scan reads the padded array.
// Everything else = round-26.
// ---------------------------------------------------------------------------

#define NN 50000
#define EE 600000
#define GG 256
#define HID 128
#define EDIM 16
#define EHID 64
#define NL 4
#define MIN_F 200
#define MH 256
#define MOUT 128
#define PH 512
#define PIN 256
#define SCAN_B 196  // ceil(NN/256)
#define PCH 8       // pooling chunks per graph
#define EMB 128     // edges per block (edge_mlp)
#define CPAD 16     // ints per counter line (64B)

typedef __hip_bfloat16 bf16;
typedef __attribute__((ext_vector_type(8))) short bf16x8;
typedef __attribute__((ext_vector_type(4))) float f32x4;

__device__ __forceinline__ float bfl(unsigned u) { return __uint_as_float(u << 16); }
__device__ __forceinline__ float bfh(unsigned u) { return __uint_as_float(u & 0xffff0000u); }
__device__ __forceinline__ float b2f(bf16 x) { return __bfloat162float(x); }
__device__ __forceinline__ float ldf(const void* p, long i, bool bf) {
  return bf ? __bfloat162float(((const bf16*)p)[i]) : ((const float*)p)[i];
}
__device__ __forceinline__ unsigned short f2bf_bits(float v) {
  bf16 h = __float2bfloat16(v);
  return *reinterpret_cast<unsigned short*>(&h);
}

// ---------------- dtype probe ------------------------------------------------
__global__ void probe_kernel(const unsigned short* __restrict__ xs, int* flag) {
  if (threadIdx.x == 0 && blockIdx.x == 0) {
    int sane = 0;
    for (int i = 0; i < 128; i++) {
      unsigned e = (xs[i] >> 7) & 0xFF;
      if (e >= 96 && e <= 159) sane++;
    }
    *flag = (sane >= 112) ? 1 : 0;  // 1 = bf16 inputs
  }
}

// ---------------- input -> bf16 conversion (8 elems/thread) -----------------
__global__ __launch_bounds__(256) void cvt_to_bf16(const void* __restrict__ in,
                                                   unsigned short* __restrict__ outp,
                                                   int n8, const int* __restrict__ flag) {
  bool bf = *flag != 0;
  int i = blockIdx.x * 256 + threadIdx.x;
  if (i >= n8) return;
  if (bf) {
    reinterpret_cast<uint4*>(outp)[i] = reinterpret_cast<const uint4*>(in)[i];
  } else {
    const float4* p = reinterpret_cast<const float4*>(in) + (size_t)i * 2;
    float4 v0 = p[0], v1 = p[1];
    ushort4 a, b;
    a.x = f2bf_bits(v0.x); a.y = f2bf_bits(v0.y);
    a.z = f2bf_bits(v0.z); a.w = f2bf_bits(v0.w);
    b.x = f2bf_bits(v1.x); b.y = f2bf_bits(v1.y);
    b.z = f2bf_bits(v1.z); b.w = f2bf_bits(v1.w);
    reinterpret_cast<ushort4*>(outp)[i * 2] = a;
    reinterpret_cast<ushort4*>(outp)[i * 2 + 1] = b;
  }
}

// ---------------- mol_features [G,200] -> padded f32 [G,256] ----------------
__global__ __launch_bounds__(256) void cvt_molf(const void* __restrict__ in,
                                                float* __restrict__ outp,
                                                const int* __restrict__ flag) {
  bool bf = *flag != 0;
  int i = blockIdx.x * 256 + threadIdx.x;  // GG*50
  if (i >= GG * 50) return;
  int row = i / 50, c4 = (i % 50) * 4;
  float4 v;
  if (bf) {
    const unsigned short* p = (const unsigned short*)in + (size_t)row * MIN_F + c4;
    uint2 u = *reinterpret_cast<const uint2*>(p);
    v.x = bfl(u.x); v.y = bfh(u.x); v.z = bfl(u.y); v.w = bfh(u.y);
  } else {
    v = *reinterpret_cast<const float4*>((const float*)in + (size_t)row * MIN_F + c4);
  }
  *reinterpret_cast<float4*>(&outp[(size_t)row * 256 + c4]) = v;
}

// ---------------- weight prep: fused W'_l = linW_l @ gW_l -> bf16 [n][k] ----
__global__ __launch_bounds__(256) void prep_fused_w(const void* __restrict__ lin_W,
                                                    const void* __restrict__ gW,
                                                    unsigned short* __restrict__ Wt,
                                                    const int* __restrict__ flag) {
  bool bf = *flag != 0;
  int idx = blockIdx.x * 256 + threadIdx.x;  // 0 .. 4*16384-1
  if (idx >= 4 * 16384) return;
  int l = idx >> 14;
  int rem = idx & 16383;
  int n = rem >> 7, k = rem & 127;  // Wt[n][k] = W'[k][n]
  float s = 0.f;
  long lb = (long)l * 16384;
  for (int m = 0; m < 128; m++)
    s += ldf(lin_W, lb + (long)k * 128 + m, bf) * ldf(gW, lb + (long)m * 128 + n, bf);
  Wt[idx] = f2bf_bits(s);
}

// b'_l[n] = gb_l[n] + sum_k cbias_l[k] * gW_l[k][n]   (f32)
__global__ __launch_bounds__(128) void prep_fused_b(const void* __restrict__ cbias,
                                                    const void* __restrict__ gW,
                                                    const void* __restrict__ gb,
                                                    float* __restrict__ bprime,
                                                    const int* __restrict__ flag) {
  bool bf = *flag != 0;
  int idx = blockIdx.x * 128 + threadIdx.x;  // 0 .. 4*128-1
  if (idx >= NL * HID) return;
  int l = idx >> 7, n = idx & 127;
  float s = ldf(gb, idx, bf);
  long lb = (long)l * 16384;
  for (int k = 0; k < 128; k++)
    s += ldf(cbias, (long)l * 128 + k, bf) * ldf(gW, lb + (long)k * 128 + n, bf);
  bprime[idx] = s;
}

// ---------------- weight prep: edge MLP W1 -> bf16 W1t[256 cols][32 K] ------
// k<16: W1; k==16: b1 (MFMA bias-fold); k>16: 0.
__global__ __launch_bounds__(256) void prep_edge_w(const void* __restrict__ mW1,
                                                   const void* __restrict__ mb1,
                                                   unsigned short* __restrict__ W1t,
                                                   const int* __restrict__ flag) {
  bool bf = *flag != 0;
  int idx = blockIdx.x * 256 + threadIdx.x;  // 256*32
  if (idx >= 256 * 32) return;
  int col = idx >> 5, k = idx & 31;
  float v = 0.f;
  if (k < EDIM) v = ldf(mW1, (long)(col >> 6) * (EDIM * EHID) + (long)k * EHID + (col & 63), bf);
  else if (k == EDIM) v = ldf(mb1, col, bf);
  W1t[idx] = f2bf_bits(v);
}

// ---------------- weight prep: tail (MLP+predictor) -> bf16 [N][Kp], K-pad --
__global__ __launch_bounds__(256) void prep_tail(
    const void* __restrict__ mlpW0, const void* __restrict__ mlpW1,
    const void* __restrict__ mlpW2, const void* __restrict__ mlpW3,
    const void* __restrict__ predW0, const void* __restrict__ predW1,
    unsigned short* __restrict__ T, const int* __restrict__ flag) {
  bool bf = *flag != 0;
  int idx = blockIdx.x * 256 + threadIdx.x;
  const void* src; int N, Kp, Ksrc, off;
  if      (idx < 65536)  { src = mlpW0;  N = 256; Kp = 256; Ksrc = 200; off = 0; }
  else if (idx < 131072) { src = mlpW1;  N = 256; Kp = 256; Ksrc = 256; off = 65536; }
  else if (idx < 196608) { src = mlpW2;  N = 256; Kp = 256; Ksrc = 256; off = 131072; }
  else if (idx < 229376) { src = mlpW3;  N = 128; Kp = 256; Ksrc = 256; off = 196608; }
  else if (idx < 360448) { src = predW0; N = 512; Kp = 256; Ksrc = 256; off = 229376; }
  else if (idx < 622592) { src = predW1; N = 512; Kp = 512; Ksrc = 512; off = 360448; }
  else return;
  int rem = idx - off;
  int n = rem / Kp, k = rem % Kp;
  float v = (k < Ksrc) ? ldf(src, (long)k * N + n, bf) : 0.f;
  T[idx] = f2bf_bits(v);
}

// ---------------- CSR build: padded-count(+rank) / 3-phase scan / fill ------
// count: the atomicAdd's return value IS edge e's rank within its node.
// Counters padded to one per 64B line -> per-line contention ~= avg degree.
__global__ __launch_bounds__(256) void count_kernel(const int* __restrict__ ei,
                                                    int* __restrict__ cntp,
                                                    int* __restrict__ rank) {
  int e = blockIdx.x * 256 + threadIdx.x;
  if (e >= EE) return;
  int c = ei[EE + e];
  c = min(max(c, 0), NN - 1);
  rank[e] = atomicAdd(&cntp[(size_t)c * CPAD], 1);
}

__global__ __launch_bounds__(256) void scan_phase1(const int* __restrict__ cntp,
                                                   int* __restrict__ bsum) {
  __shared__ int red[256];
  int tid = threadIdx.x;
  int i = blockIdx.x * 256 + tid;
  red[tid] = (i < NN) ? cntp[(size_t)i * CPAD] : 0;
  __syncthreads();
  for (int off = 128; off > 0; off >>= 1) {
    if (tid < off) red[tid] += red[tid + off];
    __syncthreads();
  }
  if (tid == 0) bsum[blockIdx.x] = red[0];
}

__global__ __launch_bounds__(256) void scan_phase2(int* __restrict__ bsum,
                                                   int* __restrict__ offs) {
  __shared__ int buf[256];
  int tid = threadIdx.x;
  int v = (tid < SCAN_B) ? bsum[tid] : 0;
  buf[tid] = v;
  __syncthreads();
  for (int off = 1; off < 256; off <<= 1) {
    int t = (tid >= off) ? buf[tid - off] : 0;
    __syncthreads();
    buf[tid] += t;
    __syncthreads();
  }
  if (tid < SCAN_B) bsum[tid] = buf[tid] - v;  // exclusive block offsets
  if (tid == 255) offs[NN] = buf[255];
}

__global__ __launch_bounds__(256) void scan_phase3(const int* __restrict__ cntp,
                                                   const int* __restrict__ bsum,
                                                   int* __restrict__ offs) {
  __shared__ int buf[256];
  int tid = threadIdx.x;
  int i = blockIdx.x * 256 + tid;
  int v = (i < NN) ? cntp[(size_t)i * CPAD] : 0;
  buf[tid] = v;
  __syncthreads();
  for (int off = 1; off < 256; off <<= 1) {
    int t = (tid >= off) ? buf[tid - off] : 0;
    __syncthreads();
    buf[tid] += t;
    __syncthreads();
  }
  if (i < NN) offs[i] = bsum[blockIdx.x] + buf[tid] - v;
}

// fill: ATOMIC-FREE. pos = offs[c] + rank[e]; scatter 32B record {src, g4}.
__global__ __launch_bounds__(256) void fill_kernel(const int* __restrict__ ei,
                                                   const int* __restrict__ offs,
                                                   const int* __restrict__ rank,
                                                   const float4* __restrict__ w_all4,
                                                   char* __restrict__ csr_rec) {
  int e = blockIdx.x * 256 + threadIdx.x;
  if (e >= EE) return;
  int c = ei[EE + e];
  c = min(max(c, 0), NN - 1);
  int src = min(max(ei[e], 0), NN - 1);
  float4 g = w_all4[e];  // coalesced
  int pos = offs[c] + rank[e];
  pos = min(max(pos, 0), EE - 1);
  char* r = csr_rec + (size_t)pos * 32;
  *reinterpret_cast<int*>(r) = src;
  *reinterpret_cast<float4*>(r + 16) = g;
}

// ---------------- edge-gate MLP via MFMA: swapped operands, 128 e/blk -------
// (exact round-20 form — best measured: ~42us, occ ~60%)
__global__ __launch_bounds__(256) void edge_mlp_mfma(
    const void* __restrict__ eattr, const unsigned short* __restrict__ W1t,
    const void* __restrict__ mW2, const void* __restrict__ mb2,
    float* __restrict__ w_all4, const int* __restrict__ flag) {
  bool bf = *flag != 0;
  int tid = threadIdx.x;
  int wave = tid >> 6, lane = tid & 63;  // wave == layer index
  int l15 = lane & 15, quad = lane >> 4;

  bf16x8 afrag[4];
#pragma unroll
  for (int t = 0; t < 4; t++)
    afrag[t] =
        *reinterpret_cast<const bf16x8*>(&W1t[((wave * 4 + t) * 16 + l15) * 32 + quad * 8]);

  float w2v[16];
#pragma unroll
  for (int t = 0; t < 4; t++)
#pragma unroll
    for (int r = 0; r < 4; r++)
      w2v[t * 4 + r] = ldf(mW2, wave * 64 + t * 16 + quad * 4 + r, bf);
  float b2 = ldf(mb2, wave, bf);

  bf16x8 bconst = (bf16x8){0, 0, 0, 0, 0, 0, 0, 0};
  if (quad == 2) bconst[0] = (short)0x3F80;  // k=16 element = bf16(1.0)

  int ebase = blockIdx.x * EMB;
  int rowbytes = bf ? EDIM * 2 : EDIM * 4;
  const char* p = (const char*)eattr + (size_t)(ebase + l15) * rowbytes +
                  (size_t)quad * (rowbytes >> 1);
  int fragstep = 16 * rowbytes;

  auto loadb = [&](int fb, const char* pp) -> bf16x8 {
    bf16x8 v = bconst;
    if (quad < 2 && fb < EE) {
      if (bf) {
        v = *reinterpret_cast<const bf16x8*>(pp);
      } else {
        const float4* q = reinterpret_cast<const float4*>(pp);
        float4 v0 = q[0], v1 = q[1];
        v[0] = (short)f2bf_bits(v0.x); v[1] = (short)f2bf_bits(v0.y);
        v[2] = (short)f2bf_bits(v0.z); v[3] = (short)f2bf_bits(v0.w);
        v[4] = (short)f2bf_bits(v1.x); v[5] = (short)f2bf_bits(v1.y);
        v[6] = (short)f2bf_bits(v1.z); v[7] = (short)f2bf_bits(v1.w);
      }
    }
    return v;
  };

  bf16x8 bcur = loadb(ebase, p);
#pragma unroll 2
  for (int f = 0; f < EMB / 16; f++) {
    int fbase = ebase + f * 16;
    p += fragstep;
    bf16x8 bnxt = loadb(fbase + 16, p);  // prefetch next fragment
    if (fbase < EE) {
      float s0 = 0.f, s1 = 0.f, s2 = 0.f, s3 = 0.f;
#define DO_T(T, S)                                                            \
  {                                                                           \
    f32x4 acc = __builtin_amdgcn_mfma_f32_16x16x32_bf16(                      \
        afrag[T], bcur, (f32x4){0.f, 0.f, 0.f, 0.f}, 0, 0, 0);                \
    S = fmaf(fmaxf(acc.x, 0.f), w2v[T * 4 + 0], S);                           \
    S = fmaf(fmaxf(acc.y, 0.f), w2v[T * 4 + 1], S);                           \
    S = fmaf(fmaxf(acc.z, 0.f), w2v[T * 4 + 2], S);                           \
    S = fmaf(fmaxf(acc.w, 0.f), w2v[T * 4 + 3], S);                           \
  }
      DO_T(0, s0) DO_T(1, s1) DO_T(2, s2) DO_T(3, s3)
#undef DO_T
      float s = (s0 + s1) + (s2 + s3);
      s += __shfl_xor(s, 16);  // combine quads 0<->1, 2<->3
      s += __shfl_xor(s, 32);  // combine halves
      if (quad == 0) {
        float g = 1.f / (1.f + __expf(-(s + b2)));
        w_all4[(size_t)(fbase + l15) * 4 + wave] = g;
      }
    }
    bcur = bnxt;
  }
}

// ---------------- degree / dinv per layer (reads 32B records) ---------------
__global__ __launch_bounds__(256) void deg_kernel(const int* __restrict__ offs,
                                                  const char* __restrict__ csr_rec,
                                                  float* __restrict__ dinv4) {
  int n = blockIdx.x * 256 + threadIdx.x;
  if (n >= NN) return;
  int s = offs[n], e = offs[n + 1];
  float d0 = 1.f, d1 = 1.f, d2 = 1.f, d3 = 1.f;  // self-loop weight 1.0
  for (int k = s; k < e; k++) {
    float4 g = *reinterpret_cast<const float4*>(csr_rec + (size_t)k * 32 + 16);
    d0 += g.x; d1 += g.y; d2 += g.z; d3 += g.w;
  }
  float4 o;
  o.x = rsqrtf(d0); o.y = rsqrtf(d1); o.z = rsqrtf(d2); o.w = rsqrtf(d3);
  reinterpret_cast<float4*>(dinv4)[n] = o;
}

// rec.g *= dinv4[rec.src]  (elementwise over the 4 layers)
__global__ __launch_bounds__(256) void csr_scale_kernel(char* __restrict__ csr_rec,
                                                        const float* __restrict__ dinv4) {
  int k = blockIdx.x * 256 + threadIdx.x;
  if (k >= EE) return;
  char* r = csr_rec + (size_t)k * 32;
  int s = *reinterpret_cast<const int*>(r);
  s = min(max(s, 0), NN - 1);
  float4 d = reinterpret_cast<const float4*>(dinv4)[s];
  float4* gp = reinterpret_cast<float4*>(r + 16);
  float4 g = *gp;
  g.x *= d.x; g.y *= d.y; g.z *= d.z; g.w *= d.w;
  *gp = g;
}

// ---------------- node GEMM via MFMA: bf16 in/out, f32 bias -----------------
__global__ __launch_bounds__(256) void gemm_nodes_bf16(
    const unsigned short* __restrict__ A16, const unsigned short* __restrict__ Wt,
    const float* __restrict__ bias, unsigned short* __restrict__ out16,
    int relu) {
  __shared__ alignas(16) unsigned short sA[64 * 136];
  __shared__ alignas(16) unsigned short sW[128 * 136];
  int tid = threadIdx.x;
  int rbase = blockIdx.x * 64;

#pragma unroll
  for (int p = 0; p < 8; p++) {
    int idx8 = p * 256 + tid;
    int n = idx8 >> 4, kc = idx8 & 15;
    uint4 v = reinterpret_cast<const uint4*>(Wt)[idx8];
    *reinterpret_cast<uint4*>(&sW[n * 136 + kc * 8]) = v;
  }
#pragma unroll
  for (int p = 0; p < 4; p++) {
    int idx8 = p * 256 + tid;
    int m = idx8 >> 4, kc = idx8 & 15;
    int row = rbase + m;
    uint4 v = make_uint4(0u, 0u, 0u, 0u);
    if (row < NN)
      v = *reinterpret_cast<const uint4*>(&A16[(size_t)row * HID + kc * 8]);
    *reinterpret_cast<uint4*>(&sA[m * 136 + kc * 8]) = v;
  }
  __syncthreads();

  int wave = tid >> 6, lane = tid & 63;
  int l15 = lane & 15, quad = lane >> 4;
  int mstrip = wave * 16;

  f32x4 acc[8];
#pragma unroll
  for (int t = 0; t < 8; t++) acc[t] = (f32x4){0.f, 0.f, 0.f, 0.f};

#pragma unroll
  for (int ks = 0; ks < 4; ks++) {
    int k0 = ks * 32 + quad * 8;
    bf16x8 a = *reinterpret_cast<const bf16x8*>(&sA[(mstrip + l15) * 136 + k0]);
#pragma unroll
    for (int t = 0; t < 8; t++) {
      bf16x8 b = *reinterpret_cast<const bf16x8*>(&sW[(t * 16 + l15) * 136 + k0]);
      acc[t] = __builtin_amdgcn_mfma_f32_16x16x32_bf16(a, b, acc[t], 0, 0, 0);
    }
  }

#pragma unroll
  for (int t = 0; t < 8; t++) {
    int n = t * 16 + l15;
    float bv = bias ? bias[n] : 0.f;
#pragma unroll
    for (int r = 0; r < 4; r++) {
      int row = rbase + mstrip + quad * 4 + r;
      if (row < NN) {
        float o = acc[t][r] + bv;
        if (relu) o = fmaxf(o, 0.f);
        out16[(size_t)row * HID + n] = f2bf_bits(o);
      }
    }
  }
}

// ---------------- tail GEMM via MFMA ----------------------------------------
__global__ __launch_bounds__(256) void gemm_tail_mfma(
    const float* __restrict__ A, int lda, const unsigned short* __restrict__ Wt,
    int Kp, const void* __restrict__ bias, float* __restrict__ outp, int ldo,
    int relu, const int* __restrict__ flag) {
  __shared__ alignas(16) unsigned short sA[64 * 264];
  __shared__ alignas(16) unsigned short sW[64 * 264];
  int tid = threadIdx.x;
  int rbase = blockIdx.x * 64;
  int nbase = blockIdx.y * 64;
  int wave = tid >> 6, lane = tid & 63;
  int l15 = lane & 15, quad = lane >> 4;
  int mstrip = wave * 16;

  f32x4 acc[4];
#pragma unroll
  for (int t = 0; t < 4; t++) acc[t] = (f32x4){0.f, 0.f, 0.f, 0.f};

  for (int kc = 0; kc < Kp; kc += 256) {
#pragma unroll 4
    for (int p = 0; p < 16; p++) {
      int idx = p * 1024 + tid * 4;
      int m = idx >> 8, k = idx & 255;
      float4 v = *reinterpret_cast<const float4*>(&A[(size_t)(rbase + m) * lda + kc + k]);
      ushort4 b;
      b.x = f2bf_bits(v.x); b.y = f2bf_bits(v.y);
      b.z = f2bf_bits(v.z); b.w = f2bf_bits(v.w);
      *reinterpret_cast<ushort4*>(&sA[m * 264 + k]) = b;
    }
#pragma unroll 4
    for (int p = 0; p < 8; p++) {
      int idx8 = p * 256 + tid;
      int n = idx8 >> 5, kk = (idx8 & 31) * 8;
      uint4 v = *reinterpret_cast<const uint4*>(&Wt[(size_t)(nbase + n) * Kp + kc + kk]);
      *reinterpret_cast<uint4*>(&sW[n * 264 + kk]) = v;
    }
    __syncthreads();
#pragma unroll
    for (int ks = 0; ks < 8; ks++) {
      int k0 = ks * 32 + quad * 8;
      bf16x8 a = *reinterpret_cast<const bf16x8*>(&sA[(mstrip + l15) * 264 + k0]);
#pragma unroll
      for (int nt = 0; nt < 4; nt++) {
        bf16x8 b = *reinterpret_cast<const bf16x8*>(&sW[(nt * 16 + l15) * 264 + k0]);
        acc[nt] = __builtin_amdgcn_mfma_f32_16x16x32_bf16(a, b, acc[nt], 0, 0, 0);
      }
    }
    __syncthreads();
  }

  bool bf = *flag != 0;
#pragma unroll
  for (int nt = 0; nt < 4; nt++) {
    int col = nbase + nt * 16 + l15;
    float bv = ldf(bias, col, bf);
#pragma unroll
    for (int r = 0; r < 4; r++) {
      int row = rbase + mstrip + quad * 4 + r;
      float o = acc[nt][r] + bv;
      if (relu) o = fmaxf(o, 0.f);
      outp[(size_t)row * ldo + col] = o;
    }
  }
}

// ---------------- aggregation: 1 wave/node, 16B lane gathers, 4 j-slots -----
// lane = (grp = lane>>4 in 0..3, c16 = lane&15). Per j, grp's 16 lanes load
// the full 256B row (16B each). Group partials combined via shfl_xor 16/32.
// Staging reads the 32B record {src, g4}; val = g4[layer] (pre-scaled).
// out16[n] = dn*(sum_k val_k*h16[src_k]) + dn^2*h16[n]
__global__ __launch_bounds__(64) void aggregate_kernel(
    const unsigned short* __restrict__ h16, const int* __restrict__ offs,
    const char* __restrict__ csr_rec, const float* __restrict__ dinv4,
    int layer, unsigned short* __restrict__ out16) {
  int n = blockIdx.x;
  int lane = threadIdx.x;      // 0..63
  int grp = lane >> 4;         // j-slot
  int c16 = lane & 15;         // 16B channel chunk (8 bf16)
  __shared__ int s_src[64];
  __shared__ float s_val[64];
  int start = offs[n], end = offs[n + 1];
  float a0 = 0.f, a1 = 0.f, a2 = 0.f, a3 = 0.f;
  float a4 = 0.f, a5 = 0.f, a6 = 0.f, a7 = 0.f;
  for (int base = start; base < end; base += 64) {
    int k = base + lane;
    if (k < end) {
      const char* r = csr_rec + (size_t)k * 32;
      int sv = *reinterpret_cast<const int*>(r);
      float4 g = *reinterpret_cast<const float4*>(r + 16);
      float v = (layer == 0) ? g.x : (layer == 1) ? g.y : (layer == 2) ? g.z : g.w;
      s_src[lane] = min(max(sv, 0), NN - 1);
      s_val[lane] = v;
    }
    __syncthreads();
    int m = min(64, end - base);
    for (int j = grp; j < m; j += 4) {
      float v = s_val[j];
      uint4 u = *reinterpret_cast<const uint4*>(&h16[(size_t)s_src[j] * HID + c16 * 8]);
      a0 = fmaf(v, bfl(u.x), a0); a1 = fmaf(v, bfh(u.x), a1);
      a2 = fmaf(v, bfl(u.y), a2); a3 = fmaf(v, bfh(u.y), a3);
      a4 = fmaf(v, bfl(u.z), a4); a5 = fmaf(v, bfh(u.z), a5);
      a6 = fmaf(v, bfl(u.w), a6); a7 = fmaf(v, bfh(u.w), a7);
    }
    __syncthreads();
  }
  // combine the 4 j-slot groups (no barriers — in-wave shuffles)
  a0 += __shfl_xor(a0, 16); a1 += __shfl_xor(a1, 16);
  a2 += __shfl_xor(a2, 16); a3 += __shfl_xor(a3, 16);
  a4 += __shfl_xor(a4, 16); a5 += __shfl_xor(a5, 16);
  a6 += __shfl_xor(a6, 16); a7 += __shfl_xor(a7, 16);
  a0 += __shfl_xor(a0, 32); a1 += __shfl_xor(a1, 32);
  a2 += __shfl_xor(a2, 32); a3 += __shfl_xor(a3, 32);
  a4 += __shfl_xor(a4, 32); a5 += __shfl_xor(a5, 32);
  a6 += __shfl_xor(a6, 32); a7 += __shfl_xor(a7, 32);
  if (grp == 0) {
    float dn = dinv4[(size_t)n * 4 + layer];
    float dn2 = dn * dn;
    uint4 su = *reinterpret_cast<const uint4*>(&h16[(size_t)n * HID + c16 * 8]);
    ushort4 o0, o1v;
    o0.x  = f2bf_bits(dn * a0 + dn2 * bfl(su.x));
    o0.y  = f2bf_bits(dn * a1 + dn2 * bfh(su.x));
    o0.z  = f2bf_bits(dn * a2 + dn2 * bfl(su.y));
    o0.w  = f2bf_bits(dn * a3 + dn2 * bfh(su.y));
    o1v.x = f2bf_bits(dn * a4 + dn2 * bfl(su.z));
    o1v.y = f2bf_bits(dn * a5 + dn2 * bfh(su.z));
    o1v.z = f2bf_bits(dn * a6 + dn2 * bfl(su.w));
    o1v.w = f2bf_bits(dn * a7 + dn2 * bfh(su.w));
    *reinterpret_cast<ushort4*>(&out16[(size_t)n * HID + c16 * 8]) = o0;
    *reinterpret_cast<ushort4*>(&out16[(size_t)n * HID + c16 * 8 + 4]) = o1v;
  }
}

// ---------------- mean pool, 2-phase (bf16 input) ---------------------------
__global__ __launch_bounds__(128) void pool_partial(const unsigned short* __restrict__ h16,
                                                    const int* __restrict__ batch,
                                                    float* __restrict__ part) {
  int g = blockIdx.x, chunk = blockIdx.y, c = threadIdx.x;
  int lo = 0, hi = NN;
  while (lo < hi) { int mid = (lo + hi) >> 1; if (batch[mid] < g) lo = mid + 1; else hi = mid; }
  int start = lo;
  hi = NN;
  while (lo < hi) { int mid = (lo + hi) >> 1; if (batch[mid] < g + 1) lo = mid + 1; else hi = mid; }
  int end = lo;
  int len = end - start;
  int per = (len + PCH - 1) / PCH;
  int s = start + chunk * per;
  int e = min(s + per, end);
  float sum = 0.f;
  for (int n = s; n < e; n++) sum += bfl((unsigned)h16[(size_t)n * HID + c]);
  part[((size_t)g * PCH + chunk) * HID + c] = sum;
}

__global__ __launch_bounds__(128) void pool_combine(const float* __restrict__ part,
                                                    const int* __restrict__ batch,
                                                    float* __restrict__ cat) {
  int g = blockIdx.x, c = threadIdx.x;
  int lo = 0, hi = NN;
  while (lo < hi) { int mid = (lo + hi) >> 1; if (batch[mid] < g) lo = mid + 1; else hi = mid; }
  int start = lo;
  hi = NN;
  while (lo < hi) { int mid = (lo + hi) >> 1; if (batch[mid] < g + 1) lo = mid + 1; else hi = mid; }
  int end = lo;
  float s = 0.f;
#pragma unroll
  for (int k = 0; k < PCH; k++) s += part[((size_t)g * PCH + k) * HID + c];
  float cntf = (float)(end - start);
  cat[(size_t)g * PIN + c] = s / fmaxf(cntf, 1.f);
}

// ---------------- final [G,512] @ [512,1] + b -> out ------------------------
__global__ __launch_bounds__(64) void final_kernel(const float* __restrict__ A,
                                                   const void* __restrict__ W,
                                                   const void* __restrict__ b,
                                                   void* __restrict__ outp,
                                                   const int* __restrict__ flag) {
  bool bf = *flag != 0;
  int g = blockIdx.x, lane = threadIdx.x;
  float s = 0.f;
  for (int k = lane; k < PH; k += 64) s = fmaf(A[(size_t)g * PH + k], ldf(W, k, bf), s);
#pragma unroll
  for (int off = 32; off > 0; off >>= 1) s += __shfl_down(s, off);
  if (lane == 0) {
    float r = s + ldf(b, 0, bf);
    if (bf) ((bf16*)outp)[g] = __float2bfloat16(r);
    else    ((float*)outp)[g] = r;
  }
}

// ---------------------------------------------------------------------------
extern "C" void kernel_launch(void* const* d_in, const int* in_sizes, int n_in,
                              void* d_out, int out_size, void* d_ws, size_t ws_size,
                              hipStream_t stream) {
  const void* x      = d_in[0];
  const int*  ei     = (const int*)d_in[1];
  const void* eattr  = d_in[2];
  const int*  batch  = (const int*)d_in[3];
  const void* molf   = d_in[4];
  const void* lin_W  = d_in[5];
  const void* mW1    = d_in[6];
  const void* mb1    = d_in[7];
  const void* mW2    = d_in[8];
  const void* mb2    = d_in[9];
  const void* cbias  = d_in[10];
  const void* gW     = d_in[11];
  const void* gb     = d_in[12];
  const void* mlpW0  = d_in[13];
  const void* mlpb0  = d_in[14];
  const void* mlpW1  = d_in[15];
  const void* mlpb1  = d_in[16];
  const void* mlpW2  = d_in[17];
  const void* mlpb2  = d_in[18];
  const void* mlpW3  = d_in[19];
  const void* mlpb3  = d_in[20];
  const void* predW0 = d_in[21];
  const void* predb0 = d_in[22];
  const void* predW1 = d_in[23];
  const void* predb1 = d_in[24];
  const void* outW   = d_in[25];
  const void* outb   = d_in[26];

  char* base = (char*)d_ws;
  size_t off = 0;
  auto alloc = [&](size_t bytes) -> char* {
    char* p = base + off;
    off = (off + bytes + 255) & ~(size_t)255;
    return p;
  };
  unsigned short* h16  = (unsigned short*)alloc((size_t)NN * HID * 2);
  unsigned short* t16  = (unsigned short*)alloc((size_t)NN * HID * 2);
  float* dinv4    = (float*)alloc((size_t)NN * 4 * 4);
  int*   cntp     = (int*)alloc((size_t)NN * CPAD * 4);
  int*   offs     = (int*)alloc((size_t)(NN + 1) * 4);
  int*   rank     = (int*)alloc((size_t)EE * 4);
  int*   bsum     = (int*)alloc((size_t)256 * 4);
  char*  csr_rec  = alloc((size_t)EE * 32);
  float* w_all4   = (float*)alloc((size_t)EE * 4 * 4);
  unsigned short* Wt    = (unsigned short*)alloc((size_t)NL * HID * HID * 2);
  float* bprime   = (float*)alloc((size_t)NL * HID * 4);
  unsigned short* tailW = (unsigned short*)alloc((size_t)622592 * 2);
  unsigned short* edgeW = (unsigned short*)alloc((size_t)256 * 32 * 2);
  int*   flag     = (int*)alloc(256);
  float* part     = (float*)alloc((size_t)GG * PCH * HID * 4);
  float* molf32   = (float*)alloc((size_t)GG * 256 * 4);
  float* m0       = (float*)alloc((size_t)GG * MH * 4);
  float* m1       = (float*)alloc((size_t)GG * MH * 4);
  float* cat      = (float*)alloc((size_t)GG * PIN * 4);
  float* p0       = (float*)alloc((size_t)GG * PH * 4);
  float* p1       = (float*)alloc((size_t)GG * PH * 4);

  hipMemsetAsync(cntp, 0, (size_t)NN * CPAD * 4, stream);
  hipMemsetAsync(molf32, 0, (size_t)GG * 256 * 4, stream);

  // dtype probe first — everything downstream branches on it
  probe_kernel<<<1, 64, 0, stream>>>((const unsigned short*)x, flag);

  // weight prep (fused layer weights + tail + edge)
  prep_fused_w<<<256, 256, 0, stream>>>(lin_W, gW, Wt, flag);
  prep_fused_b<<<NL, 128, 0, stream>>>(cbias, gW, gb, bprime, flag);
  prep_tail<<<(622592 + 255) / 256, 256, 0, stream>>>(mlpW0, mlpW1, mlpW2, mlpW3,
                                                      predW0, predW1, tailW, flag);
  prep_edge_w<<<32, 256, 0, stream>>>(mW1, mb1, edgeW, flag);

  // x -> bf16 layer state
  {
    int n8 = NN * HID / 8;
    cvt_to_bf16<<<(n8 + 255) / 256, 256, 0, stream>>>(x, h16, n8, flag);
  }
  // edge gates (MFMA, round-20 form)
  edge_mlp_mfma<<<(EE + EMB - 1) / EMB, 256, 0, stream>>>(eattr, edgeW, mW2, mb2,
                                                          w_all4, flag);
  // CSR build: padded count (returns rank), 3-phase scan, atomic-free fill
  count_kernel<<<(EE + 255) / 256, 256, 0, stream>>>(ei, cntp, rank);
  scan_phase1<<<SCAN_B, 256, 0, stream>>>(cntp, bsum);
  scan_phase2<<<1, 256, 0, stream>>>(bsum, offs);
  scan_phase3<<<SCAN_B, 256, 0, stream>>>(cntp, bsum, offs);
  fill_kernel<<<(EE + 255) / 256, 256, 0, stream>>>(ei, offs, rank,
                                                    (const float4*)w_all4, csr_rec);
  // degrees + in-place gate scaling
  deg_kernel<<<(NN + 255) / 256, 256, 0, stream>>>(offs, csr_rec, dinv4);
  csr_scale_kernel<<<(EE + 255) / 256, 256, 0, stream>>>(csr_rec, dinv4);

  // GCN layers (fused): aggregate(h16)->t16; gemm(t16, W'_l, b'_l, relu)->h16
  const int gemm_blocks = (NN + 63) / 64;  // 782
  for (int l = 0; l < NL; l++) {
    aggregate_kernel<<<NN, 64, 0, stream>>>(h16, offs, csr_rec, dinv4, l, t16);
    gemm_nodes_bf16<<<gemm_blocks, 256, 0, stream>>>(
        t16, Wt + (size_t)l * HID * HID, bprime + (size_t)l * HID, h16, 1);
  }

  // pooling -> cat[:, 0:128]  (2-phase, bf16 input)
  pool_partial<<<dim3(GG, PCH), 128, 0, stream>>>(h16, batch, part);
  pool_combine<<<GG, 128, 0, stream>>>(part, batch, cat);

  // molecular MLP -> cat[:, 128:256]  (MFMA tail, K-padded weights)
  cvt_molf<<<(GG * 50 + 255) / 256, 256, 0, stream>>>(molf, molf32, flag);
  gemm_tail_mfma<<<dim3(4, 4), 256, 0, stream>>>(molf32, 256, tailW + 0,      256, mlpb0, m0, 256, 1, flag);
  gemm_tail_mfma<<<dim3(4, 4), 256, 0, stream>>>(m0,     256, tailW + 65536,  256, mlpb1, m1, 256, 1, flag);
  gemm_tail_mfma<<<dim3(4, 4), 256, 0, stream>>>(m1,     256, tailW + 131072, 256, mlpb2, m0, 256, 1, flag);
  gemm_tail_mfma<<<dim3(4, 2), 256, 0, stream>>>(m0,     256, tailW + 196608, 256, mlpb3, cat + MOUT, 256, 1, flag);

  // predictor
  gemm_tail_mfma<<<dim3(4, 8), 256, 0, stream>>>(cat, 256, tailW + 229376, 256, predb0, p0, 512, 1, flag);
  gemm_tail_mfma<<<dim3(4, 8), 256, 0, stream>>>(p0,  512, tailW + 360448, 512, predb1, p1, 512, 1, flag);
  final_kernel<<<GG, 64, 0, stream>>>(p1, outW, outb, d_out, flag);
}

// Round 12
// 542.544 us; speedup vs baseline: 1.1092x; 1.0114x over previous
//
#include <hip/hip_runtime.h>
#include <hip/hip_bf16.h>

// ---------------------------------------------------------------------------
// PDNConv GNN, MI355X round 29.
// Round-28 WIN (548.8us): atomic-free fill (rank from count's atomicAdd,
// 64B-padded counters) dropped fill below the visibility cutoff. Remaining
// concentrated cost: aggregate x4 streams the full 32B record per edge per
// layer (76.8MB total) but needs only {src, g[layer]} (19.2MB). Round-29:
// csr_scale -> csr_split: same record read + dinv[src] gather, but writes
// SoA: csr_src[EE] + 4 pre-scaled gate planes csr_g[4][EE] (12MB contiguous,
// LESS than the old in-place rewrite). Each aggregate reads 4.8MB/layer
// instead of 19.2 (-57.6MB streamed). fill keeps its optimal 1-line/edge
// 32B-record scatter; deg reads records; edge_mlp untouched (anchor).
// ---------------------------------------------------------------------------

#define NN 50000
#define EE 600000
#define GG 256
#define HID 128
#define EDIM 16
#define EHID 64
#define NL 4
#define MIN_F 200
#define MH 256
#define MOUT 128
#define PH 512
#define PIN 256
#define SCAN_B 196  // ceil(NN/256)
#define PCH 8       // pooling chunks per graph
#define EMB 128     // edges per block (edge_mlp)
#define CPAD 16     // ints per counter line (64B)

typedef __hip_bfloat16 bf16;
typedef __attribute__((ext_vector_type(8))) short bf16x8;
typedef __attribute__((ext_vector_type(4))) float f32x4;

__device__ __forceinline__ float bfl(unsigned u) { return __uint_as_float(u << 16); }
__device__ __forceinline__ float bfh(unsigned u) { return __uint_as_float(u & 0xffff0000u); }
__device__ __forceinline__ float b2f(bf16 x) { return __bfloat162float(x); }
__device__ __forceinline__ float ldf(const void* p, long i, bool bf) {
  return bf ? __bfloat162float(((const bf16*)p)[i]) : ((const float*)p)[i];
}
__device__ __forceinline__ unsigned short f2bf_bits(float v) {
  bf16 h = __float2bfloat16(v);
  return *reinterpret_cast<unsigned short*>(&h);
}

// ---------------- dtype probe ------------------------------------------------
__global__ void probe_kernel(const unsigned short* __restrict__ xs, int* flag) {
  if (threadIdx.x == 0 && blockIdx.x == 0) {
    int sane = 0;
    for (int i = 0; i < 128; i++) {
      unsigned e = (xs[i] >> 7) & 0xFF;
      if (e >= 96 && e <= 159) sane++;
    }
    *flag = (sane >= 112) ? 1 : 0;  // 1 = bf16 inputs
  }
}

// ---------------- input -> bf16 conversion (8 elems/thread) -----------------
__global__ __launch_bounds__(256) void cvt_to_bf16(const void* __restrict__ in,
                                                   unsigned short* __restrict__ outp,
                                                   int n8, const int* __restrict__ flag) {
  bool bf = *flag != 0;
  int i = blockIdx.x * 256 + threadIdx.x;
  if (i >= n8) return;
  if (bf) {
    reinterpret_cast<uint4*>(outp)[i] = reinterpret_cast<const uint4*>(in)[i];
  } else {
    const float4* p = reinterpret_cast<const float4*>(in) + (size_t)i * 2;
    float4 v0 = p[0], v1 = p[1];
    ushort4 a, b;
    a.x = f2bf_bits(v0.x); a.y = f2bf_bits(v0.y);
    a.z = f2bf_bits(v0.z); a.w = f2bf_bits(v0.w);
    b.x = f2bf_bits(v1.x); b.y = f2bf_bits(v1.y);
    b.z = f2bf_bits(v1.z); b.w = f2bf_bits(v1.w);
    reinterpret_cast<ushort4*>(outp)[i * 2] = a;
    reinterpret_cast<ushort4*>(outp)[i * 2 + 1] = b;
  }
}

// ---------------- mol_features [G,200] -> padded f32 [G,256] ----------------
__global__ __launch_bounds__(256) void cvt_molf(const void* __restrict__ in,
                                                float* __restrict__ outp,
                                                const int* __restrict__ flag) {
  bool bf = *flag != 0;
  int i = blockIdx.x * 256 + threadIdx.x;  // GG*50
  if (i >= GG * 50) return;
  int row = i / 50, c4 = (i % 50) * 4;
  float4 v;
  if (bf) {
    const unsigned short* p = (const unsigned short*)in + (size_t)row * MIN_F + c4;
    uint2 u = *reinterpret_cast<const uint2*>(p);
    v.x = bfl(u.x); v.y = bfh(u.x); v.z = bfl(u.y); v.w = bfh(u.y);
  } else {
    v = *reinterpret_cast<const float4*>((const float*)in + (size_t)row * MIN_F + c4);
  }
  *reinterpret_cast<float4*>(&outp[(size_t)row * 256 + c4]) = v;
}

// ---------------- weight prep: fused W'_l = linW_l @ gW_l -> bf16 [n][k] ----
__global__ __launch_bounds__(256) void prep_fused_w(const void* __restrict__ lin_W,
                                                    const void* __restrict__ gW,
                                                    unsigned short* __restrict__ Wt,
                                                    const int* __restrict__ flag) {
  bool bf = *flag != 0;
  int idx = blockIdx.x * 256 + threadIdx.x;  // 0 .. 4*16384-1
  if (idx >= 4 * 16384) return;
  int l = idx >> 14;
  int rem = idx & 16383;
  int n = rem >> 7, k = rem & 127;  // Wt[n][k] = W'[k][n]
  float s = 0.f;
  long lb = (long)l * 16384;
  for (int m = 0; m < 128; m++)
    s += ldf(lin_W, lb + (long)k * 128 + m, bf) * ldf(gW, lb + (long)m * 128 + n, bf);
  Wt[idx] = f2bf_bits(s);
}

// b'_l[n] = gb_l[n] + sum_k cbias_l[k] * gW_l[k][n]   (f32)
__global__ __launch_bounds__(128) void prep_fused_b(const void* __restrict__ cbias,
                                                    const void* __restrict__ gW,
                                                    const void* __restrict__ gb,
                                                    float* __restrict__ bprime,
                                                    const int* __restrict__ flag) {
  bool bf = *flag != 0;
  int idx = blockIdx.x * 128 + threadIdx.x;  // 0 .. 4*128-1
  if (idx >= NL * HID) return;
  int l = idx >> 7, n = idx & 127;
  float s = ldf(gb, idx, bf);
  long lb = (long)l * 16384;
  for (int k = 0; k < 128; k++)
    s += ldf(cbias, (long)l * 128 + k, bf) * ldf(gW, lb + (long)k * 128 + n, bf);
  bprime[idx] = s;
}

// ---------------- weight prep: edge MLP W1 -> bf16 W1t[256 cols][32 K] ------
// k<16: W1; k==16: b1 (MFMA bias-fold); k>16: 0.
__global__ __launch_bounds__(256) void prep_edge_w(const void* __restrict__ mW1,
                                                   const void* __restrict__ mb1,
                                                   unsigned short* __restrict__ W1t,
                                                   const int* __restrict__ flag) {
  bool bf = *flag != 0;
  int idx = blockIdx.x * 256 + threadIdx.x;  // 256*32
  if (idx >= 256 * 32) return;
  int col = idx >> 5, k = idx & 31;
  float v = 0.f;
  if (k < EDIM) v = ldf(mW1, (long)(col >> 6) * (EDIM * EHID) + (long)k * EHID + (col & 63), bf);
  else if (k == EDIM) v = ldf(mb1, col, bf);
  W1t[idx] = f2bf_bits(v);
}

// ---------------- weight prep: tail (MLP+predictor) -> bf16 [N][Kp], K-pad --
__global__ __launch_bounds__(256) void prep_tail(
    const void* __restrict__ mlpW0, const void* __restrict__ mlpW1,
    const void* __restrict__ mlpW2, const void* __restrict__ mlpW3,
    const void* __restrict__ predW0, const void* __restrict__ predW1,
    unsigned short* __restrict__ T, const int* __restrict__ flag) {
  bool bf = *flag != 0;
  int idx = blockIdx.x * 256 + threadIdx.x;
  const void* src; int N, Kp, Ksrc, off;
  if      (idx < 65536)  { src = mlpW0;  N = 256; Kp = 256; Ksrc = 200; off = 0; }
  else if (idx < 131072) { src = mlpW1;  N = 256; Kp = 256; Ksrc = 256; off = 65536; }
  else if (idx < 196608) { src = mlpW2;  N = 256; Kp = 256; Ksrc = 256; off = 131072; }
  else if (idx < 229376) { src = mlpW3;  N = 128; Kp = 256; Ksrc = 256; off = 196608; }
  else if (idx < 360448) { src = predW0; N = 512; Kp = 256; Ksrc = 256; off = 229376; }
  else if (idx < 622592) { src = predW1; N = 512; Kp = 512; Ksrc = 512; off = 360448; }
  else return;
  int rem = idx - off;
  int n = rem / Kp, k = rem % Kp;
  float v = (k < Ksrc) ? ldf(src, (long)k * N + n, bf) : 0.f;
  T[idx] = f2bf_bits(v);
}

// ---------------- CSR build: padded-count(+rank) / 3-phase scan / fill ------
__global__ __launch_bounds__(256) void count_kernel(const int* __restrict__ ei,
                                                    int* __restrict__ cntp,
                                                    int* __restrict__ rank) {
  int e = blockIdx.x * 256 + threadIdx.x;
  if (e >= EE) return;
  int c = ei[EE + e];
  c = min(max(c, 0), NN - 1);
  rank[e] = atomicAdd(&cntp[(size_t)c * CPAD], 1);
}

__global__ __launch_bounds__(256) void scan_phase1(const int* __restrict__ cntp,
                                                   int* __restrict__ bsum) {
  __shared__ int red[256];
  int tid = threadIdx.x;
  int i = blockIdx.x * 256 + tid;
  red[tid] = (i < NN) ? cntp[(size_t)i * CPAD] : 0;
  __syncthreads();
  for (int off = 128; off > 0; off >>= 1) {
    if (tid < off) red[tid] += red[tid + off];
    __syncthreads();
  }
  if (tid == 0) bsum[blockIdx.x] = red[0];
}

__global__ __launch_bounds__(256) void scan_phase2(int* __restrict__ bsum,
                                                   int* __restrict__ offs) {
  __shared__ int buf[256];
  int tid = threadIdx.x;
  int v = (tid < SCAN_B) ? bsum[tid] : 0;
  buf[tid] = v;
  __syncthreads();
  for (int off = 1; off < 256; off <<= 1) {
    int t = (tid >= off) ? buf[tid - off] : 0;
    __syncthreads();
    buf[tid] += t;
    __syncthreads();
  }
  if (tid < SCAN_B) bsum[tid] = buf[tid] - v;  // exclusive block offsets
  if (tid == 255) offs[NN] = buf[255];
}

__global__ __launch_bounds__(256) void scan_phase3(const int* __restrict__ cntp,
                                                   const int* __restrict__ bsum,
                                                   int* __restrict__ offs) {
  __shared__ int buf[256];
  int tid = threadIdx.x;
  int i = blockIdx.x * 256 + tid;
  int v = (i < NN) ? cntp[(size_t)i * CPAD] : 0;
  buf[tid] = v;
  __syncthreads();
  for (int off = 1; off < 256; off <<= 1) {
    int t = (tid >= off) ? buf[tid - off] : 0;
    __syncthreads();
    buf[tid] += t;
    __syncthreads();
  }
  if (i < NN) offs[i] = bsum[blockIdx.x] + buf[tid] - v;
}

// fill: ATOMIC-FREE. pos = offs[c] + rank[e]; scatter 32B record {src, g4}.
__global__ __launch_bounds__(256) void fill_kernel(const int* __restrict__ ei,
                                                   const int* __restrict__ offs,
                                                   const int* __restrict__ rank,
                                                   const float4* __restrict__ w_all4,
                                                   char* __restrict__ csr_rec) {
  int e = blockIdx.x * 256 + threadIdx.x;
  if (e >= EE) return;
  int c = ei[EE + e];
  c = min(max(c, 0), NN - 1);
  int src = min(max(ei[e], 0), NN - 1);
  float4 g = w_all4[e];  // coalesced
  int pos = offs[c] + rank[e];
  pos = min(max(pos, 0), EE - 1);
  char* r = csr_rec + (size_t)pos * 32;
  *reinterpret_cast<int*>(r) = src;
  *reinterpret_cast<float4*>(r + 16) = g;
}

// ---------------- edge-gate MLP via MFMA: swapped operands, 128 e/blk -------
// (exact round-20 form — best measured: ~42us, occ ~60%)
__global__ __launch_bounds__(256) void edge_mlp_mfma(
    const void* __restrict__ eattr, const unsigned short* __restrict__ W1t,
    const void* __restrict__ mW2, const void* __restrict__ mb2,
    float* __restrict__ w_all4, const int* __restrict__ flag) {
  bool bf = *flag != 0;
  int tid = threadIdx.x;
  int wave = tid >> 6, lane = tid & 63;  // wave == layer index
  int l15 = lane & 15, quad = lane >> 4;

  bf16x8 afrag[4];
#pragma unroll
  for (int t = 0; t < 4; t++)
    afrag[t] =
        *reinterpret_cast<const bf16x8*>(&W1t[((wave * 4 + t) * 16 + l15) * 32 + quad * 8]);

  float w2v[16];
#pragma unroll
  for (int t = 0; t < 4; t++)
#pragma unroll
    for (int r = 0; r < 4; r++)
      w2v[t * 4 + r] = ldf(mW2, wave * 64 + t * 16 + quad * 4 + r, bf);
  float b2 = ldf(mb2, wave, bf);

  bf16x8 bconst = (bf16x8){0, 0, 0, 0, 0, 0, 0, 0};
  if (quad == 2) bconst[0] = (short)0x3F80;  // k=16 element = bf16(1.0)

  int ebase = blockIdx.x * EMB;
  int rowbytes = bf ? EDIM * 2 : EDIM * 4;
  const char* p = (const char*)eattr + (size_t)(ebase + l15) * rowbytes +
                  (size_t)quad * (rowbytes >> 1);
  int fragstep = 16 * rowbytes;

  auto loadb = [&](int fb, const char* pp) -> bf16x8 {
    bf16x8 v = bconst;
    if (quad < 2 && fb < EE) {
      if (bf) {
        v = *reinterpret_cast<const bf16x8*>(pp);
      } else {
        const float4* q = reinterpret_cast<const float4*>(pp);
        float4 v0 = q[0], v1 = q[1];
        v[0] = (short)f2bf_bits(v0.x); v[1] = (short)f2bf_bits(v0.y);
        v[2] = (short)f2bf_bits(v0.z); v[3] = (short)f2bf_bits(v0.w);
        v[4] = (short)f2bf_bits(v1.x); v[5] = (short)f2bf_bits(v1.y);
        v[6] = (short)f2bf_bits(v1.z); v[7] = (short)f2bf_bits(v1.w);
      }
    }
    return v;
  };

  bf16x8 bcur = loadb(ebase, p);
#pragma unroll 2
  for (int f = 0; f < EMB / 16; f++) {
    int fbase = ebase + f * 16;
    p += fragstep;
    bf16x8 bnxt = loadb(fbase + 16, p);  // prefetch next fragment
    if (fbase < EE) {
      float s0 = 0.f, s1 = 0.f, s2 = 0.f, s3 = 0.f;
#define DO_T(T, S)                                                            \
  {                                                                           \
    f32x4 acc = __builtin_amdgcn_mfma_f32_16x16x32_bf16(                      \
        afrag[T], bcur, (f32x4){0.f, 0.f, 0.f, 0.f}, 0, 0, 0);                \
    S = fmaf(fmaxf(acc.x, 0.f), w2v[T * 4 + 0], S);                           \
    S = fmaf(fmaxf(acc.y, 0.f), w2v[T * 4 + 1], S);                           \
    S = fmaf(fmaxf(acc.z, 0.f), w2v[T * 4 + 2], S);                           \
    S = fmaf(fmaxf(acc.w, 0.f), w2v[T * 4 + 3], S);                           \
  }
      DO_T(0, s0) DO_T(1, s1) DO_T(2, s2) DO_T(3, s3)
#undef DO_T
      float s = (s0 + s1) + (s2 + s3);
      s += __shfl_xor(s, 16);  // combine quads 0<->1, 2<->3
      s += __shfl_xor(s, 32);  // combine halves
      if (quad == 0) {
        float g = 1.f / (1.f + __expf(-(s + b2)));
        w_all4[(size_t)(fbase + l15) * 4 + wave] = g;
      }
    }
    bcur = bnxt;
  }
}

// ---------------- degree / dinv per layer (reads 32B records) ---------------
__global__ __launch_bounds__(256) void deg_kernel(const int* __restrict__ offs,
                                                  const char* __restrict__ csr_rec,
                                                  float* __restrict__ dinv4) {
  int n = blockIdx.x * 256 + threadIdx.x;
  if (n >= NN) return;
  int s = offs[n], e = offs[n + 1];
  float d0 = 1.f, d1 = 1.f, d2 = 1.f, d3 = 1.f;  // self-loop weight 1.0
  for (int k = s; k < e; k++) {
    float4 g = *reinterpret_cast<const float4*>(csr_rec + (size_t)k * 32 + 16);
    d0 += g.x; d1 += g.y; d2 += g.z; d3 += g.w;
  }
  float4 o;
  o.x = rsqrtf(d0); o.y = rsqrtf(d1); o.z = rsqrtf(d2); o.w = rsqrtf(d3);
  reinterpret_cast<float4*>(dinv4)[n] = o;
}

// split: record -> SoA {csr_src[k], csr_g[l][k] = g_l * dinv_l[src]}
// reads 19.2MB contiguous + dinv gather; writes 12MB contiguous.
__global__ __launch_bounds__(256) void csr_split_kernel(const char* __restrict__ csr_rec,
                                                        const float* __restrict__ dinv4,
                                                        int* __restrict__ csr_src,
                                                        float* __restrict__ csr_g) {
  int k = blockIdx.x * 256 + threadIdx.x;
  if (k >= EE) return;
  const char* r = csr_rec + (size_t)k * 32;
  int s = *reinterpret_cast<const int*>(r);
  s = min(max(s, 0), NN - 1);
  float4 d = reinterpret_cast<const float4*>(dinv4)[s];
  float4 g = *reinterpret_cast<const float4*>(r + 16);
  csr_src[k] = s;
  csr_g[k] = g.x * d.x;
  csr_g[(size_t)EE + k] = g.y * d.y;
  csr_g[2 * (size_t)EE + k] = g.z * d.z;
  csr_g[3 * (size_t)EE + k] = g.w * d.w;
}

// ---------------- node GEMM via MFMA: bf16 in/out, f32 bias -----------------
__global__ __launch_bounds__(256) void gemm_nodes_bf16(
    const unsigned short* __restrict__ A16, const unsigned short* __restrict__ Wt,
    const float* __restrict__ bias, unsigned short* __restrict__ out16,
    int relu) {
  __shared__ alignas(16) unsigned short sA[64 * 136];
  __shared__ alignas(16) unsigned short sW[128 * 136];
  int tid = threadIdx.x;
  int rbase = blockIdx.x * 64;

#pragma unroll
  for (int p = 0; p < 8; p++) {
    int idx8 = p * 256 + tid;
    int n = idx8 >> 4, kc = idx8 & 15;
    uint4 v = reinterpret_cast<const uint4*>(Wt)[idx8];
    *reinterpret_cast<uint4*>(&sW[n * 136 + kc * 8]) = v;
  }
#pragma unroll
  for (int p = 0; p < 4; p++) {
    int idx8 = p * 256 + tid;
    int m = idx8 >> 4, kc = idx8 & 15;
    int row = rbase + m;
    uint4 v = make_uint4(0u, 0u, 0u, 0u);
    if (row < NN)
      v = *reinterpret_cast<const uint4*>(&A16[(size_t)row * HID + kc * 8]);
    *reinterpret_cast<uint4*>(&sA[m * 136 + kc * 8]) = v;
  }
  __syncthreads();

  int wave = tid >> 6, lane = tid & 63;
  int l15 = lane & 15, quad = lane >> 4;
  int mstrip = wave * 16;

  f32x4 acc[8];
#pragma unroll
  for (int t = 0; t < 8; t++) acc[t] = (f32x4){0.f, 0.f, 0.f, 0.f};

#pragma unroll
  for (int ks = 0; ks < 4; ks++) {
    int k0 = ks * 32 + quad * 8;
    bf16x8 a = *reinterpret_cast<const bf16x8*>(&sA[(mstrip + l15) * 136 + k0]);
#pragma unroll
    for (int t = 0; t < 8; t++) {
      bf16x8 b = *reinterpret_cast<const bf16x8*>(&sW[(t * 16 + l15) * 136 + k0]);
      acc[t] = __builtin_amdgcn_mfma_f32_16x16x32_bf16(a, b, acc[t], 0, 0, 0);
    }
  }

#pragma unroll
  for (int t = 0; t < 8; t++) {
    int n = t * 16 + l15;
    float bv = bias ? bias[n] : 0.f;
#pragma unroll
    for (int r = 0; r < 4; r++) {
      int row = rbase + mstrip + quad * 4 + r;
      if (row < NN) {
        float o = acc[t][r] + bv;
        if (relu) o = fmaxf(o, 0.f);
        out16[(size_t)row * HID + n] = f2bf_bits(o);
      }
    }
  }
}

// ---------------- tail GEMM via MFMA ----------------------------------------
__global__ __launch_bounds__(256) void gemm_tail_mfma(
    const float* __restrict__ A, int lda, const unsigned short* __restrict__ Wt,
    int Kp, const void* __restrict__ bias, float* __restrict__ outp, int ldo,
    int relu, const int* __restrict__ flag) {
  __shared__ alignas(16) unsigned short sA[64 * 264];
  __shared__ alignas(16) unsigned short sW[64 * 264];
  int tid = threadIdx.x;
  int rbase = blockIdx.x * 64;
  int nbase = blockIdx.y * 64;
  int wave = tid >> 6, lane = tid & 63;
  int l15 = lane & 15, quad = lane >> 4;
  int mstrip = wave * 16;

  f32x4 acc[4];
#pragma unroll
  for (int t = 0; t < 4; t++) acc[t] = (f32x4){0.f, 0.f, 0.f, 0.f};

  for (int kc = 0; kc < Kp; kc += 256) {
#pragma unroll 4
    for (int p = 0; p < 16; p++) {
      int idx = p * 1024 + tid * 4;
      int m = idx >> 8, k = idx & 255;
      float4 v = *reinterpret_cast<const float4*>(&A[(size_t)(rbase + m) * lda + kc + k]);
      ushort4 b;
      b.x = f2bf_bits(v.x); b.y = f2bf_bits(v.y);
      b.z = f2bf_bits(v.z); b.w = f2bf_bits(v.w);
      *reinterpret_cast<ushort4*>(&sA[m * 264 + k]) = b;
    }
#pragma unroll 4
    for (int p = 0; p < 8; p++) {
      int idx8 = p * 256 + tid;
      int n = idx8 >> 5, kk = (idx8 & 31) * 8;
      uint4 v = *reinterpret_cast<const uint4*>(&Wt[(size_t)(nbase + n) * Kp + kc + kk]);
      *reinterpret_cast<uint4*>(&sW[n * 264 + kk]) = v;
    }
    __syncthreads();
#pragma unroll
    for (int ks = 0; ks < 8; ks++) {
      int k0 = ks * 32 + quad * 8;
      bf16x8 a = *reinterpret_cast<const bf16x8*>(&sA[(mstrip + l15) * 264 + k0]);
#pragma unroll
      for (int nt = 0; nt < 4; nt++) {
        bf16x8 b = *reinterpret_cast<const bf16x8*>(&sW[(nt * 16 + l15) * 264 + k0]);
        acc[nt] = __builtin_amdgcn_mfma_f32_16x16x32_bf16(a, b, acc[nt], 0, 0, 0);
      }
    }
    __syncthreads();
  }

  bool bf = *flag != 0;
#pragma unroll
  for (int nt = 0; nt < 4; nt++) {
    int col = nbase + nt * 16 + l15;
    float bv = ldf(bias, col, bf);
#pragma unroll
    for (int r = 0; r < 4; r++) {
      int row = rbase + mstrip + quad * 4 + r;
      float o = acc[nt][r] + bv;
      if (relu) o = fmaxf(o, 0.f);
      outp[(size_t)row * ldo + col] = o;
    }
  }
}

// ---------------- aggregation: 1 wave/node, SoA staging ---------------------
// lane = (grp = lane>>4 in 0..3, c16 = lane&15). Staging reads csr_src[k]
// (4B) + its layer's gate plane csr_gl[k] (4B, pre-scaled) — 4.8MB/layer vs
// 19.2 for the 32B records. Per j, grp's 16 lanes load the full 256B h16 row.
// out16[n] = dn*(sum_k val_k*h16[src_k]) + dn^2*h16[n]
__global__ __launch_bounds__(64) void aggregate_kernel(
    const unsigned short* __restrict__ h16, const int* __restrict__ offs,
    const int* __restrict__ csr_src, const float* __restrict__ csr_gl,
    const float* __restrict__ dinv4, int layer,
    unsigned short* __restrict__ out16) {
  int n = blockIdx.x;
  int lane = threadIdx.x;      // 0..63
  int grp = lane >> 4;         // j-slot
  int c16 = lane & 15;         // 16B channel chunk (8 bf16)
  __shared__ int s_src[64];
  __shared__ float s_val[64];
  int start = offs[n], end = offs[n + 1];
  float a0 = 0.f, a1 = 0.f, a2 = 0.f, a3 = 0.f;
  float a4 = 0.f, a5 = 0.f, a6 = 0.f, a7 = 0.f;
  for (int base = start; base < end; base += 64) {
    int k = base + lane;
    if (k < end) {
      s_src[lane] = min(max(csr_src[k], 0), NN - 1);
      s_val[lane] = csr_gl[k];
    }
    __syncthreads();
    int m = min(64, end - base);
    for (int j = grp; j < m; j += 4) {
      float v = s_val[j];
      uint4 u = *reinterpret_cast<const uint4*>(&h16[(size_t)s_src[j] * HID + c16 * 8]);
      a0 = fmaf(v, bfl(u.x), a0); a1 = fmaf(v, bfh(u.x), a1);
      a2 = fmaf(v, bfl(u.y), a2); a3 = fmaf(v, bfh(u.y), a3);
      a4 = fmaf(v, bfl(u.z), a4); a5 = fmaf(v, bfh(u.z), a5);
      a6 = fmaf(v, bfl(u.w), a6); a7 = fmaf(v, bfh(u.w), a7);
    }
    __syncthreads();
  }
  // combine the 4 j-slot groups (no barriers — in-wave shuffles)
  a0 += __shfl_xor(a0, 16); a1 += __shfl_xor(a1, 16);
  a2 += __shfl_xor(a2, 16); a3 += __shfl_xor(a3, 16);
  a4 += __shfl_xor(a4, 16); a5 += __shfl_xor(a5, 16);
  a6 += __shfl_xor(a6, 16); a7 += __shfl_xor(a7, 16);
  a0 += __shfl_xor(a0, 32); a1 += __shfl_xor(a1, 32);
  a2 += __shfl_xor(a2, 32); a3 += __shfl_xor(a3, 32);
  a4 += __shfl_xor(a4, 32); a5 += __shfl_xor(a5, 32);
  a6 += __shfl_xor(a6, 32); a7 += __shfl_xor(a7, 32);
  if (grp == 0) {
    float dn = dinv4[(size_t)n * 4 + layer];
    float dn2 = dn * dn;
    uint4 su = *reinterpret_cast<const uint4*>(&h16[(size_t)n * HID + c16 * 8]);
    ushort4 o0, o1v;
    o0.x  = f2bf_bits(dn * a0 + dn2 * bfl(su.x));
    o0.y  = f2bf_bits(dn * a1 + dn2 * bfh(su.x));
    o0.z  = f2bf_bits(dn * a2 + dn2 * bfl(su.y));
    o0.w  = f2bf_bits(dn * a3 + dn2 * bfh(su.y));
    o1v.x = f2bf_bits(dn * a4 + dn2 * bfl(su.z));
    o1v.y = f2bf_bits(dn * a5 + dn2 * bfh(su.z));
    o1v.z = f2bf_bits(dn * a6 + dn2 * bfl(su.w));
    o1v.w = f2bf_bits(dn * a7 + dn2 * bfh(su.w));
    *reinterpret_cast<ushort4*>(&out16[(size_t)n * HID + c16 * 8]) = o0;
    *reinterpret_cast<ushort4*>(&out16[(size_t)n * HID + c16 * 8 + 4]) = o1v;
  }
}

// ---------------- mean pool, 2-phase (bf16 input) ---------------------------
__global__ __launch_bounds__(128) void pool_partial(const unsigned short* __restrict__ h16,
                                                    const int* __restrict__ batch,
                                                    float* __restrict__ part) {
  int g = blockIdx.x, chunk = blockIdx.y, c = threadIdx.x;
  int lo = 0, hi = NN;
  while (lo < hi) { int mid = (lo + hi) >> 1; if (batch[mid] < g) lo = mid + 1; else hi = mid; }
  int start = lo;
  hi = NN;
  while (lo < hi) { int mid = (lo + hi) >> 1; if (batch[mid] < g + 1) lo = mid + 1; else hi = mid; }
  int end = lo;
  int len = end - start;
  int per = (len + PCH - 1) / PCH;
  int s = start + chunk * per;
  int e = min(s + per, end);
  float sum = 0.f;
  for (int n = s; n < e; n++) sum += bfl((unsigned)h16[(size_t)n * HID + c]);
  part[((size_t)g * PCH + chunk) * HID + c] = sum;
}

__global__ __launch_bounds__(128) void pool_combine(const float* __restrict__ part,
                                                    const int* __restrict__ batch,
                                                    float* __restrict__ cat) {
  int g = blockIdx.x, c = threadIdx.x;
  int lo = 0, hi = NN;
  while (lo < hi) { int mid = (lo + hi) >> 1; if (batch[mid] < g) lo = mid + 1; else hi = mid; }
  int start = lo;
  hi = NN;
  while (lo < hi) { int mid = (lo + hi) >> 1; if (batch[mid] < g + 1) lo = mid + 1; else hi = mid; }
  int end = lo;
  float s = 0.f;
#pragma unroll
  for (int k = 0; k < PCH; k++) s += part[((size_t)g * PCH + k) * HID + c];
  float cntf = (float)(end - start);
  cat[(size_t)g * PIN + c] = s / fmaxf(cntf, 1.f);
}

// ---------------- final [G,512] @ [512,1] + b -> out ------------------------
__global__ __launch_bounds__(64) void final_kernel(const float* __restrict__ A,
                                                   const void* __restrict__ W,
                                                   const void* __restrict__ b,
                                                   void* __restrict__ outp,
                                                   const int* __restrict__ flag) {
  bool bf = *flag != 0;
  int g = blockIdx.x, lane = threadIdx.x;
  float s = 0.f;
  for (int k = lane; k < PH; k += 64) s = fmaf(A[(size_t)g * PH + k], ldf(W, k, bf), s);
#pragma unroll
  for (int off = 32; off > 0; off >>= 1) s += __shfl_down(s, off);
  if (lane == 0) {
    float r = s + ldf(b, 0, bf);
    if (bf) ((bf16*)outp)[g] = __float2bfloat16(r);
    else    ((float*)outp)[g] = r;
  }
}

// ---------------------------------------------------------------------------
extern "C" void kernel_launch(void* const* d_in, const int* in_sizes, int n_in,
                              void* d_out, int out_size, void* d_ws, size_t ws_size,
                              hipStream_t stream) {
  const void* x      = d_in[0];
  const int*  ei     = (const int*)d_in[1];
  const void* eattr  = d_in[2];
  const int*  batch  = (const int*)d_in[3];
  const void* molf   = d_in[4];
  const void* lin_W  = d_in[5];
  const void* mW1    = d_in[6];
  const void* mb1    = d_in[7];
  const void* mW2    = d_in[8];
  const void* mb2    = d_in[9];
  const void* cbias  = d_in[10];
  const void* gW     = d_in[11];
  const void* gb     = d_in[12];
  const void* mlpW0  = d_in[13];
  const void* mlpb0  = d_in[14];
  const void* mlpW1  = d_in[15];
  const void* mlpb1  = d_in[16];
  const void* mlpW2  = d_in[17];
  const void* mlpb2  = d_in[18];
  const void* mlpW3  = d_in[19];
  const void* mlpb3  = d_in[20];
  const void* predW0 = d_in[21];
  const void* predb0 = d_in[22];
  const void* predW1 = d_in[23];
  const void* predb1 = d_in[24];
  const void* outW   = d_in[25];
  const void* outb   = d_in[26];

  char* base = (char*)d_ws;
  size_t off = 0;
  auto alloc = [&](size_t bytes) -> char* {
    char* p = base + off;
    off = (off + bytes + 255) & ~(size_t)255;
    return p;
  };
  unsigned short* h16  = (unsigned short*)alloc((size_t)NN * HID * 2);
  unsigned short* t16  = (unsigned short*)alloc((size_t)NN * HID * 2);
  float* dinv4    = (float*)alloc((size_t)NN * 4 * 4);
  int*   cntp     = (int*)alloc((size_t)NN * CPAD * 4);
  int*   offs     = (int*)alloc((size_t)(NN + 1) * 4);
  int*   rank     = (int*)alloc((size_t)EE * 4);
  int*   bsum     = (int*)alloc((size_t)256 * 4);
  char*  csr_rec  = alloc((size_t)EE * 32);
  int*   csr_src  = (int*)alloc((size_t)EE * 4);
  float* csr_g    = (float*)alloc((size_t)NL * EE * 4);
  float* w_all4   = (float*)alloc((size_t)EE * 4 * 4);
  unsigned short* Wt    = (unsigned short*)alloc((size_t)NL * HID * HID * 2);
  float* bprime   = (float*)alloc((size_t)NL * HID * 4);
  unsigned short* tailW = (unsigned short*)alloc((size_t)622592 * 2);
  unsigned short* edgeW = (unsigned short*)alloc((size_t)256 * 32 * 2);
  int*   flag     = (int*)alloc(256);
  float* part     = (float*)alloc((size_t)GG * PCH * HID * 4);
  float* molf32   = (float*)alloc((size_t)GG * 256 * 4);
  float* m0       = (float*)alloc((size_t)GG * MH * 4);
  float* m1       = (float*)alloc((size_t)GG * MH * 4);
  float* cat      = (float*)alloc((size_t)GG * PIN * 4);
  float* p0       = (float*)alloc((size_t)GG * PH * 4);
  float* p1       = (float*)alloc((size_t)GG * PH * 4);

  hipMemsetAsync(cntp, 0, (size_t)NN * CPAD * 4, stream);
  hipMemsetAsync(molf32, 0, (size_t)GG * 256 * 4, stream);

  // dtype probe first — everything downstream branches on it
  probe_kernel<<<1, 64, 0, stream>>>((const unsigned short*)x, flag);

  // weight prep (fused layer weights + tail + edge)
  prep_fused_w<<<256, 256, 0, stream>>>(lin_W, gW, Wt, flag);
  prep_fused_b<<<NL, 128, 0, stream>>>(cbias, gW, gb, bprime, flag);
  prep_tail<<<(622592 + 255) / 256, 256, 0, stream>>>(mlpW0, mlpW1, mlpW2, mlpW3,
                                                      predW0, predW1, tailW, flag);
  prep_edge_w<<<32, 256, 0, stream>>>(mW1, mb1, edgeW, flag);

  // x -> bf16 layer state
  {
    int n8 = NN * HID / 8;
    cvt_to_bf16<<<(n8 + 255) / 256, 256, 0, stream>>>(x, h16, n8, flag);
  }
  // edge gates (MFMA, round-20 form)
  edge_mlp_mfma<<<(EE + EMB - 1) / EMB, 256, 0, stream>>>(eattr, edgeW, mW2, mb2,
                                                          w_all4, flag);
  // CSR build: padded count (returns rank), 3-phase scan, atomic-free fill
  count_kernel<<<(EE + 255) / 256, 256, 0, stream>>>(ei, cntp, rank);
  scan_phase1<<<SCAN_B, 256, 0, stream>>>(cntp, bsum);
  scan_phase2<<<1, 256, 0, stream>>>(bsum, offs);
  scan_phase3<<<SCAN_B, 256, 0, stream>>>(cntp, bsum, offs);
  fill_kernel<<<(EE + 255) / 256, 256, 0, stream>>>(ei, offs, rank,
                                                    (const float4*)w_all4, csr_rec);
  // degrees, then split records into SoA {src, per-layer scaled gates}
  deg_kernel<<<(NN + 255) / 256, 256, 0, stream>>>(offs, csr_rec, dinv4);
  csr_split_kernel<<<(EE + 255) / 256, 256, 0, stream>>>(csr_rec, dinv4,
                                                         csr_src, csr_g);

  // GCN layers (fused): aggregate(h16)->t16; gemm(t16, W'_l, b'_l, relu)->h16
  const int gemm_blocks = (NN + 63) / 64;  // 782
  for (int l = 0; l < NL; l++) {
    aggregate_kernel<<<NN, 64, 0, stream>>>(h16, offs, csr_src,
                                            csr_g + (size_t)l * EE, dinv4, l, t16);
    gemm_nodes_bf16<<<gemm_blocks, 256, 0, stream>>>(
        t16, Wt + (size_t)l * HID * HID, bprime + (size_t)l * HID, h16, 1);
  }

  // pooling -> cat[:, 0:128]  (2-phase, bf16 input)
  pool_partial<<<dim3(GG, PCH), 128, 0, stream>>>(h16, batch, part);
  pool_combine<<<GG, 128, 0, stream>>>(part, batch, cat);

  // molecular MLP -> cat[:, 128:256]  (MFMA tail, K-padded weights)
  cvt_molf<<<(GG * 50 + 255) / 256, 256, 0, stream>>>(molf, molf32, flag);
  gemm_tail_mfma<<<dim3(4, 4), 256, 0, stream>>>(molf32, 256, tailW + 0,      256, mlpb0, m0, 256, 1, flag);
  gemm_tail_mfma<<<dim3(4, 4), 256, 0, stream>>>(m0,     256, tailW + 65536,  256, mlpb1, m1, 256, 1, flag);
  gemm_tail_mfma<<<dim3(4, 4), 256, 0, stream>>>(m1,     256, tailW + 131072, 256, mlpb2, m0, 256, 1, flag);
  gemm_tail_mfma<<<dim3(4, 2), 256, 0, stream>>>(m0,     256, tailW + 196608, 256, mlpb3, cat + MOUT, 256, 1, flag);

  // predictor
  gemm_tail_mfma<<<dim3(4, 8), 256, 0, stream>>>(cat, 256, tailW + 229376, 256, predb0, p0, 512, 1, flag);
  gemm_tail_mfma<<<dim3(4, 8), 256, 0, stream>>>(p0,  512, tailW + 360448, 512, predb1, p1, 512, 1, flag);
  final_kernel<<<GG, 64, 0, stream>>>(p1, outW, outb, d_out, flag);
}

// Round 13
// 532.049 us; speedup vs baseline: 1.1311x; 1.0197x over previous
//
#include <hip/hip_runtime.h>
#include <hip/hip_bf16.h>

// ---------------------------------------------------------------------------
// PDNConv GNN, MI355X round 30.
// r28 WIN (548.8): atomic-free fill. r29 WIN (542.5): SoA gate planes for
// aggregate (-57.6MB streamed). Top-5 = edge_mlp only (~42us, latency-bound,
// VALU ~25%/SIMD, HBM 9% -> idle memory slots). Round-30: FUSE count_kernel
// into edge_mlp — threads 0..127 of each 128-edge block also do the CSR
// count (read col, rank[e]=atomicAdd(cntp[c*16],1)). Deletes one full
// dispatch (~12-18us incl. its 2.4MB ei re-read); atomics hide under the
// MFMA/gather latency. Stream order: scan launches after edge_mlp. All else
// = round-29.
// ---------------------------------------------------------------------------

#define NN 50000
#define EE 600000
#define GG 256
#define HID 128
#define EDIM 16
#define EHID 64
#define NL 4
#define MIN_F 200
#define MH 256
#define MOUT 128
#define PH 512
#define PIN 256
#define SCAN_B 196  // ceil(NN/256)
#define PCH 8       // pooling chunks per graph
#define EMB 128     // edges per block (edge_mlp)
#define CPAD 16     // ints per counter line (64B)

typedef __hip_bfloat16 bf16;
typedef __attribute__((ext_vector_type(8))) short bf16x8;
typedef __attribute__((ext_vector_type(4))) float f32x4;

__device__ __forceinline__ float bfl(unsigned u) { return __uint_as_float(u << 16); }
__device__ __forceinline__ float bfh(unsigned u) { return __uint_as_float(u & 0xffff0000u); }
__device__ __forceinline__ float b2f(bf16 x) { return __bfloat162float(x); }
__device__ __forceinline__ float ldf(const void* p, long i, bool bf) {
  return bf ? __bfloat162float(((const bf16*)p)[i]) : ((const float*)p)[i];
}
__device__ __forceinline__ unsigned short f2bf_bits(float v) {
  bf16 h = __float2bfloat16(v);
  return *reinterpret_cast<unsigned short*>(&h);
}

// ---------------- dtype probe ------------------------------------------------
__global__ void probe_kernel(const unsigned short* __restrict__ xs, int* flag) {
  if (threadIdx.x == 0 && blockIdx.x == 0) {
    int sane = 0;
    for (int i = 0; i < 128; i++) {
      unsigned e = (xs[i] >> 7) & 0xFF;
      if (e >= 96 && e <= 159) sane++;
    }
    *flag = (sane >= 112) ? 1 : 0;  // 1 = bf16 inputs
  }
}

// ---------------- input -> bf16 conversion (8 elems/thread) -----------------
__global__ __launch_bounds__(256) void cvt_to_bf16(const void* __restrict__ in,
                                                   unsigned short* __restrict__ outp,
                                                   int n8, const int* __restrict__ flag) {
  bool bf = *flag != 0;
  int i = blockIdx.x * 256 + threadIdx.x;
  if (i >= n8) return;
  if (bf) {
    reinterpret_cast<uint4*>(outp)[i] = reinterpret_cast<const uint4*>(in)[i];
  } else {
    const float4* p = reinterpret_cast<const float4*>(in) + (size_t)i * 2;
    float4 v0 = p[0], v1 = p[1];
    ushort4 a, b;
    a.x = f2bf_bits(v0.x); a.y = f2bf_bits(v0.y);
    a.z = f2bf_bits(v0.z); a.w = f2bf_bits(v0.w);
    b.x = f2bf_bits(v1.x); b.y = f2bf_bits(v1.y);
    b.z = f2bf_bits(v1.z); b.w = f2bf_bits(v1.w);
    reinterpret_cast<ushort4*>(outp)[i * 2] = a;
    reinterpret_cast<ushort4*>(outp)[i * 2 + 1] = b;
  }
}

// ---------------- mol_features [G,200] -> padded f32 [G,256] ----------------
__global__ __launch_bounds__(256) void cvt_molf(const void* __restrict__ in,
                                                float* __restrict__ outp,
                                                const int* __restrict__ flag) {
  bool bf = *flag != 0;
  int i = blockIdx.x * 256 + threadIdx.x;  // GG*50
  if (i >= GG * 50) return;
  int row = i / 50, c4 = (i % 50) * 4;
  float4 v;
  if (bf) {
    const unsigned short* p = (const unsigned short*)in + (size_t)row * MIN_F + c4;
    uint2 u = *reinterpret_cast<const uint2*>(p);
    v.x = bfl(u.x); v.y = bfh(u.x); v.z = bfl(u.y); v.w = bfh(u.y);
  } else {
    v = *reinterpret_cast<const float4*>((const float*)in + (size_t)row * MIN_F + c4);
  }
  *reinterpret_cast<float4*>(&outp[(size_t)row * 256 + c4]) = v;
}

// ---------------- weight prep: fused W'_l = linW_l @ gW_l -> bf16 [n][k] ----
__global__ __launch_bounds__(256) void prep_fused_w(const void* __restrict__ lin_W,
                                                    const void* __restrict__ gW,
                                                    unsigned short* __restrict__ Wt,
                                                    const int* __restrict__ flag) {
  bool bf = *flag != 0;
  int idx = blockIdx.x * 256 + threadIdx.x;  // 0 .. 4*16384-1
  if (idx >= 4 * 16384) return;
  int l = idx >> 14;
  int rem = idx & 16383;
  int n = rem >> 7, k = rem & 127;  // Wt[n][k] = W'[k][n]
  float s = 0.f;
  long lb = (long)l * 16384;
  for (int m = 0; m < 128; m++)
    s += ldf(lin_W, lb + (long)k * 128 + m, bf) * ldf(gW, lb + (long)m * 128 + n, bf);
  Wt[idx] = f2bf_bits(s);
}

// b'_l[n] = gb_l[n] + sum_k cbias_l[k] * gW_l[k][n]   (f32)
__global__ __launch_bounds__(128) void prep_fused_b(const void* __restrict__ cbias,
                                                    const void* __restrict__ gW,
                                                    const void* __restrict__ gb,
                                                    float* __restrict__ bprime,
                                                    const int* __restrict__ flag) {
  bool bf = *flag != 0;
  int idx = blockIdx.x * 128 + threadIdx.x;  // 0 .. 4*128-1
  if (idx >= NL * HID) return;
  int l = idx >> 7, n = idx & 127;
  float s = ldf(gb, idx, bf);
  long lb = (long)l * 16384;
  for (int k = 0; k < 128; k++)
    s += ldf(cbias, (long)l * 128 + k, bf) * ldf(gW, lb + (long)k * 128 + n, bf);
  bprime[idx] = s;
}

// ---------------- weight prep: edge MLP W1 -> bf16 W1t[256 cols][32 K] ------
// k<16: W1; k==16: b1 (MFMA bias-fold); k>16: 0.
__global__ __launch_bounds__(256) void prep_edge_w(const void* __restrict__ mW1,
                                                   const void* __restrict__ mb1,
                                                   unsigned short* __restrict__ W1t,
                                                   const int* __restrict__ flag) {
  bool bf = *flag != 0;
  int idx = blockIdx.x * 256 + threadIdx.x;  // 256*32
  if (idx >= 256 * 32) return;
  int col = idx >> 5, k = idx & 31;
  float v = 0.f;
  if (k < EDIM) v = ldf(mW1, (long)(col >> 6) * (EDIM * EHID) + (long)k * EHID + (col & 63), bf);
  else if (k == EDIM) v = ldf(mb1, col, bf);
  W1t[idx] = f2bf_bits(v);
}

// ---------------- weight prep: tail (MLP+predictor) -> bf16 [N][Kp], K-pad --
__global__ __launch_bounds__(256) void prep_tail(
    const void* __restrict__ mlpW0, const void* __restrict__ mlpW1,
    const void* __restrict__ mlpW2, const void* __restrict__ mlpW3,
    const void* __restrict__ predW0, const void* __restrict__ predW1,
    unsigned short* __restrict__ T, const int* __restrict__ flag) {
  bool bf = *flag != 0;
  int idx = blockIdx.x * 256 + threadIdx.x;
  const void* src; int N, Kp, Ksrc, off;
  if      (idx < 65536)  { src = mlpW0;  N = 256; Kp = 256; Ksrc = 200; off = 0; }
  else if (idx < 131072) { src = mlpW1;  N = 256; Kp = 256; Ksrc = 256; off = 65536; }
  else if (idx < 196608) { src = mlpW2;  N = 256; Kp = 256; Ksrc = 256; off = 131072; }
  else if (idx < 229376) { src = mlpW3;  N = 128; Kp = 256; Ksrc = 256; off = 196608; }
  else if (idx < 360448) { src = predW0; N = 512; Kp = 256; Ksrc = 256; off = 229376; }
  else if (idx < 622592) { src = predW1; N = 512; Kp = 512; Ksrc = 512; off = 360448; }
  else return;
  int rem = idx - off;
  int n = rem / Kp, k = rem % Kp;
  float v = (k < Ksrc) ? ldf(src, (long)k * N + n, bf) : 0.f;
  T[idx] = f2bf_bits(v);
}

// ---------------- CSR scan (count fused into edge_mlp) ----------------------
__global__ __launch_bounds__(256) void scan_phase1(const int* __restrict__ cntp,
                                                   int* __restrict__ bsum) {
  __shared__ int red[256];
  int tid = threadIdx.x;
  int i = blockIdx.x * 256 + tid;
  red[tid] = (i < NN) ? cntp[(size_t)i * CPAD] : 0;
  __syncthreads();
  for (int off = 128; off > 0; off >>= 1) {
    if (tid < off) red[tid] += red[tid + off];
    __syncthreads();
  }
  if (tid == 0) bsum[blockIdx.x] = red[0];
}

__global__ __launch_bounds__(256) void scan_phase2(int* __restrict__ bsum,
                                                   int* __restrict__ offs) {
  __shared__ int buf[256];
  int tid = threadIdx.x;
  int v = (tid < SCAN_B) ? bsum[tid] : 0;
  buf[tid] = v;
  __syncthreads();
  for (int off = 1; off < 256; off <<= 1) {
    int t = (tid >= off) ? buf[tid - off] : 0;
    __syncthreads();
    buf[tid] += t;
    __syncthreads();
  }
  if (tid < SCAN_B) bsum[tid] = buf[tid] - v;  // exclusive block offsets
  if (tid == 255) offs[NN] = buf[255];
}

__global__ __launch_bounds__(256) void scan_phase3(const int* __restrict__ cntp,
                                                   const int* __restrict__ bsum,
                                                   int* __restrict__ offs) {
  __shared__ int buf[256];
  int tid = threadIdx.x;
  int i = blockIdx.x * 256 + tid;
  int v = (i < NN) ? cntp[(size_t)i * CPAD] : 0;
  buf[tid] = v;
  __syncthreads();
  for (int off = 1; off < 256; off <<= 1) {
    int t = (tid >= off) ? buf[tid - off] : 0;
    __syncthreads();
    buf[tid] += t;
    __syncthreads();
  }
  if (i < NN) offs[i] = bsum[blockIdx.x] + buf[tid] - v;
}

// fill: ATOMIC-FREE. pos = offs[c] + rank[e]; scatter 32B record {src, g4}.
__global__ __launch_bounds__(256) void fill_kernel(const int* __restrict__ ei,
                                                   const int* __restrict__ offs,
                                                   const int* __restrict__ rank,
                                                   const float4* __restrict__ w_all4,
                                                   char* __restrict__ csr_rec) {
  int e = blockIdx.x * 256 + threadIdx.x;
  if (e >= EE) return;
  int c = ei[EE + e];
  c = min(max(c, 0), NN - 1);
  int src = min(max(ei[e], 0), NN - 1);
  float4 g = w_all4[e];  // coalesced
  int pos = offs[c] + rank[e];
  pos = min(max(pos, 0), EE - 1);
  char* r = csr_rec + (size_t)pos * 32;
  *reinterpret_cast<int*>(r) = src;
  *reinterpret_cast<float4*>(r + 16) = g;
}

// ---------------- edge-gate MLP via MFMA + fused CSR count ------------------
// r20 form (swapped operands, 128 e/blk) + threads 0..127 also perform the
// CSR count for this block's edges (rank from atomicAdd on padded counters).
// Atomic latency hides under the MFMA/gather pipeline.
__global__ __launch_bounds__(256) void edge_mlp_mfma(
    const void* __restrict__ eattr, const unsigned short* __restrict__ W1t,
    const void* __restrict__ mW2, const void* __restrict__ mb2,
    float* __restrict__ w_all4, const int* __restrict__ ei,
    int* __restrict__ cntp, int* __restrict__ rank,
    const int* __restrict__ flag) {
  bool bf = *flag != 0;
  int tid = threadIdx.x;
  int wave = tid >> 6, lane = tid & 63;  // wave == layer index
  int l15 = lane & 15, quad = lane >> 4;
  int ebase = blockIdx.x * EMB;

  // ---- fused CSR count (threads 0..127 -> this block's 128 edges) ----
  {
    int ecnt = min(EMB, EE - ebase);
    if (tid < ecnt) {
      int e = ebase + tid;
      int c = ei[EE + e];
      c = min(max(c, 0), NN - 1);
      rank[e] = atomicAdd(&cntp[(size_t)c * CPAD], 1);
    }
  }

  bf16x8 afrag[4];
#pragma unroll
  for (int t = 0; t < 4; t++)
    afrag[t] =
        *reinterpret_cast<const bf16x8*>(&W1t[((wave * 4 + t) * 16 + l15) * 32 + quad * 8]);

  float w2v[16];
#pragma unroll
  for (int t = 0; t < 4; t++)
#pragma unroll
    for (int r = 0; r < 4; r++)
      w2v[t * 4 + r] = ldf(mW2, wave * 64 + t * 16 + quad * 4 + r, bf);
  float b2 = ldf(mb2, wave, bf);

  bf16x8 bconst = (bf16x8){0, 0, 0, 0, 0, 0, 0, 0};
  if (quad == 2) bconst[0] = (short)0x3F80;  // k=16 element = bf16(1.0)

  int rowbytes = bf ? EDIM * 2 : EDIM * 4;
  const char* p = (const char*)eattr + (size_t)(ebase + l15) * rowbytes +
                  (size_t)quad * (rowbytes >> 1);
  int fragstep = 16 * rowbytes;

  auto loadb = [&](int fb, const char* pp) -> bf16x8 {
    bf16x8 v = bconst;
    if (quad < 2 && fb < EE) {
      if (bf) {
        v = *reinterpret_cast<const bf16x8*>(pp);
      } else {
        const float4* q = reinterpret_cast<const float4*>(pp);
        float4 v0 = q[0], v1 = q[1];
        v[0] = (short)f2bf_bits(v0.x); v[1] = (short)f2bf_bits(v0.y);
        v[2] = (short)f2bf_bits(v0.z); v[3] = (short)f2bf_bits(v0.w);
        v[4] = (short)f2bf_bits(v1.x); v[5] = (short)f2bf_bits(v1.y);
        v[6] = (short)f2bf_bits(v1.z); v[7] = (short)f2bf_bits(v1.w);
      }
    }
    return v;
  };

  bf16x8 bcur = loadb(ebase, p);
#pragma unroll 2
  for (int f = 0; f < EMB / 16; f++) {
    int fbase = ebase + f * 16;
    p += fragstep;
    bf16x8 bnxt = loadb(fbase + 16, p);  // prefetch next fragment
    if (fbase < EE) {
      float s0 = 0.f, s1 = 0.f, s2 = 0.f, s3 = 0.f;
#define DO_T(T, S)                                                            \
  {                                                                           \
    f32x4 acc = __builtin_amdgcn_mfma_f32_16x16x32_bf16(                      \
        afrag[T], bcur, (f32x4){0.f, 0.f, 0.f, 0.f}, 0, 0, 0);                \
    S = fmaf(fmaxf(acc.x, 0.f), w2v[T * 4 + 0], S);                           \
    S = fmaf(fmaxf(acc.y, 0.f), w2v[T * 4 + 1], S);                           \
    S = fmaf(fmaxf(acc.z, 0.f), w2v[T * 4 + 2], S);                           \
    S = fmaf(fmaxf(acc.w, 0.f), w2v[T * 4 + 3], S);                           \
  }
      DO_T(0, s0) DO_T(1, s1) DO_T(2, s2) DO_T(3, s3)
#undef DO_T
      float s = (s0 + s1) + (s2 + s3);
      s += __shfl_xor(s, 16);  // combine quads 0<->1, 2<->3
      s += __shfl_xor(s, 32);  // combine halves
      if (quad == 0) {
        float g = 1.f / (1.f + __expf(-(s + b2)));
        w_all4[(size_t)(fbase + l15) * 4 + wave] = g;
      }
    }
    bcur = bnxt;
  }
}

// ---------------- degree / dinv per layer (reads 32B records) ---------------
__global__ __launch_bounds__(256) void deg_kernel(const int* __restrict__ offs,
                                                  const char* __restrict__ csr_rec,
                                                  float* __restrict__ dinv4) {
  int n = blockIdx.x * 256 + threadIdx.x;
  if (n >= NN) return;
  int s = offs[n], e = offs[n + 1];
  float d0 = 1.f, d1 = 1.f, d2 = 1.f, d3 = 1.f;  // self-loop weight 1.0
  for (int k = s; k < e; k++) {
    float4 g = *reinterpret_cast<const float4*>(csr_rec + (size_t)k * 32 + 16);
    d0 += g.x; d1 += g.y; d2 += g.z; d3 += g.w;
  }
  float4 o;
  o.x = rsqrtf(d0); o.y = rsqrtf(d1); o.z = rsqrtf(d2); o.w = rsqrtf(d3);
  reinterpret_cast<float4*>(dinv4)[n] = o;
}

// split: record -> SoA {csr_src[k], csr_g[l][k] = g_l * dinv_l[src]}
__global__ __launch_bounds__(256) void csr_split_kernel(const char* __restrict__ csr_rec,
                                                        const float* __restrict__ dinv4,
                                                        int* __restrict__ csr_src,
                                                        float* __restrict__ csr_g) {
  int k = blockIdx.x * 256 + threadIdx.x;
  if (k >= EE) return;
  const char* r = csr_rec + (size_t)k * 32;
  int s = *reinterpret_cast<const int*>(r);
  s = min(max(s, 0), NN - 1);
  float4 d = reinterpret_cast<const float4*>(dinv4)[s];
  float4 g = *reinterpret_cast<const float4*>(r + 16);
  csr_src[k] = s;
  csr_g[k] = g.x * d.x;
  csr_g[(size_t)EE + k] = g.y * d.y;
  csr_g[2 * (size_t)EE + k] = g.z * d.z;
  csr_g[3 * (size_t)EE + k] = g.w * d.w;
}

// ---------------- node GEMM via MFMA: bf16 in/out, f32 bias -----------------
__global__ __launch_bounds__(256) void gemm_nodes_bf16(
    const unsigned short* __restrict__ A16, const unsigned short* __restrict__ Wt,
    const float* __restrict__ bias, unsigned short* __restrict__ out16,
    int relu) {
  __shared__ alignas(16) unsigned short sA[64 * 136];
  __shared__ alignas(16) unsigned short sW[128 * 136];
  int tid = threadIdx.x;
  int rbase = blockIdx.x * 64;

#pragma unroll
  for (int p = 0; p < 8; p++) {
    int idx8 = p * 256 + tid;
    int n = idx8 >> 4, kc = idx8 & 15;
    uint4 v = reinterpret_cast<const uint4*>(Wt)[idx8];
    *reinterpret_cast<uint4*>(&sW[n * 136 + kc * 8]) = v;
  }
#pragma unroll
  for (int p = 0; p < 4; p++) {
    int idx8 = p * 256 + tid;
    int m = idx8 >> 4, kc = idx8 & 15;
    int row = rbase + m;
    uint4 v = make_uint4(0u, 0u, 0u, 0u);
    if (row < NN)
      v = *reinterpret_cast<const uint4*>(&A16[(size_t)row * HID + kc * 8]);
    *reinterpret_cast<uint4*>(&sA[m * 136 + kc * 8]) = v;
  }
  __syncthreads();

  int wave = tid >> 6, lane = tid & 63;
  int l15 = lane & 15, quad = lane >> 4;
  int mstrip = wave * 16;

  f32x4 acc[8];
#pragma unroll
  for (int t = 0; t < 8; t++) acc[t] = (f32x4){0.f, 0.f, 0.f, 0.f};

#pragma unroll
  for (int ks = 0; ks < 4; ks++) {
    int k0 = ks * 32 + quad * 8;
    bf16x8 a = *reinterpret_cast<const bf16x8*>(&sA[(mstrip + l15) * 136 + k0]);
#pragma unroll
    for (int t = 0; t < 8; t++) {
      bf16x8 b = *reinterpret_cast<const bf16x8*>(&sW[(t * 16 + l15) * 136 + k0]);
      acc[t] = __builtin_amdgcn_mfma_f32_16x16x32_bf16(a, b, acc[t], 0, 0, 0);
    }
  }

#pragma unroll
  for (int t = 0; t < 8; t++) {
    int n = t * 16 + l15;
    float bv = bias ? bias[n] : 0.f;
#pragma unroll
    for (int r = 0; r < 4; r++) {
      int row = rbase + mstrip + quad * 4 + r;
      if (row < NN) {
        float o = acc[t][r] + bv;
        if (relu) o = fmaxf(o, 0.f);
        out16[(size_t)row * HID + n] = f2bf_bits(o);
      }
    }
  }
}

// ---------------- tail GEMM via MFMA ----------------------------------------
__global__ __launch_bounds__(256) void gemm_tail_mfma(
    const float* __restrict__ A, int lda, const unsigned short* __restrict__ Wt,
    int Kp, const void* __restrict__ bias, float* __restrict__ outp, int ldo,
    int relu, const int* __restrict__ flag) {
  __shared__ alignas(16) unsigned short sA[64 * 264];
  __shared__ alignas(16) unsigned short sW[64 * 264];
  int tid = threadIdx.x;
  int rbase = blockIdx.x * 64;
  int nbase = blockIdx.y * 64;
  int wave = tid >> 6, lane = tid & 63;
  int l15 = lane & 15, quad = lane >> 4;
  int mstrip = wave * 16;

  f32x4 acc[4];
#pragma unroll
  for (int t = 0; t < 4; t++) acc[t] = (f32x4){0.f, 0.f, 0.f, 0.f};

  for (int kc = 0; kc < Kp; kc += 256) {
#pragma unroll 4
    for (int p = 0; p < 16; p++) {
      int idx = p * 1024 + tid * 4;
      int m = idx >> 8, k = idx & 255;
      float4 v = *reinterpret_cast<const float4*>(&A[(size_t)(rbase + m) * lda + kc + k]);
      ushort4 b;
      b.x = f2bf_bits(v.x); b.y = f2bf_bits(v.y);
      b.z = f2bf_bits(v.z); b.w = f2bf_bits(v.w);
      *reinterpret_cast<ushort4*>(&sA[m * 264 + k]) = b;
    }
#pragma unroll 4
    for (int p = 0; p < 8; p++) {
      int idx8 = p * 256 + tid;
      int n = idx8 >> 5, kk = (idx8 & 31) * 8;
      uint4 v = *reinterpret_cast<const uint4*>(&Wt[(size_t)(nbase + n) * Kp + kc + kk]);
      *reinterpret_cast<uint4*>(&sW[n * 264 + kk]) = v;
    }
    __syncthreads();
#pragma unroll
    for (int ks = 0; ks < 8; ks++) {
      int k0 = ks * 32 + quad * 8;
      bf16x8 a = *reinterpret_cast<const bf16x8*>(&sA[(mstrip + l15) * 264 + k0]);
#pragma unroll
      for (int nt = 0; nt < 4; nt++) {
        bf16x8 b = *reinterpret_cast<const bf16x8*>(&sW[(nt * 16 + l15) * 264 + k0]);
        acc[nt] = __builtin_amdgcn_mfma_f32_16x16x32_bf16(a, b, acc[nt], 0, 0, 0);
      }
    }
    __syncthreads();
  }

  bool bf = *flag != 0;
#pragma unroll
  for (int nt = 0; nt < 4; nt++) {
    int col = nbase + nt * 16 + l15;
    float bv = ldf(bias, col, bf);
#pragma unroll
    for (int r = 0; r < 4; r++) {
      int row = rbase + mstrip + quad * 4 + r;
      float o = acc[nt][r] + bv;
      if (relu) o = fmaxf(o, 0.f);
      outp[(size_t)row * ldo + col] = o;
    }
  }
}

// ---------------- aggregation: 1 wave/node, SoA staging ---------------------
__global__ __launch_bounds__(64) void aggregate_kernel(
    const unsigned short* __restrict__ h16, const int* __restrict__ offs,
    const int* __restrict__ csr_src, const float* __restrict__ csr_gl,
    const float* __restrict__ dinv4, int layer,
    unsigned short* __restrict__ out16) {
  int n = blockIdx.x;
  int lane = threadIdx.x;      // 0..63
  int grp = lane >> 4;         // j-slot
  int c16 = lane & 15;         // 16B channel chunk (8 bf16)
  __shared__ int s_src[64];
  __shared__ float s_val[64];
  int start = offs[n], end = offs[n + 1];
  float a0 = 0.f, a1 = 0.f, a2 = 0.f, a3 = 0.f;
  float a4 = 0.f, a5 = 0.f, a6 = 0.f, a7 = 0.f;
  for (int base = start; base < end; base += 64) {
    int k = base + lane;
    if (k < end) {
      s_src[lane] = min(max(csr_src[k], 0), NN - 1);
      s_val[lane] = csr_gl[k];
    }
    __syncthreads();
    int m = min(64, end - base);
    for (int j = grp; j < m; j += 4) {
      float v = s_val[j];
      uint4 u = *reinterpret_cast<const uint4*>(&h16[(size_t)s_src[j] * HID + c16 * 8]);
      a0 = fmaf(v, bfl(u.x), a0); a1 = fmaf(v, bfh(u.x), a1);
      a2 = fmaf(v, bfl(u.y), a2); a3 = fmaf(v, bfh(u.y), a3);
      a4 = fmaf(v, bfl(u.z), a4); a5 = fmaf(v, bfh(u.z), a5);
      a6 = fmaf(v, bfl(u.w), a6); a7 = fmaf(v, bfh(u.w), a7);
    }
    __syncthreads();
  }
  // combine the 4 j-slot groups (no barriers — in-wave shuffles)
  a0 += __shfl_xor(a0, 16); a1 += __shfl_xor(a1, 16);
  a2 += __shfl_xor(a2, 16); a3 += __shfl_xor(a3, 16);
  a4 += __shfl_xor(a4, 16); a5 += __shfl_xor(a5, 16);
  a6 += __shfl_xor(a6, 16); a7 += __shfl_xor(a7, 16);
  a0 += __shfl_xor(a0, 32); a1 += __shfl_xor(a1, 32);
  a2 += __shfl_xor(a2, 32); a3 += __shfl_xor(a3, 32);
  a4 += __shfl_xor(a4, 32); a5 += __shfl_xor(a5, 32);
  a6 += __shfl_xor(a6, 32); a7 += __shfl_xor(a7, 32);
  if (grp == 0) {
    float dn = dinv4[(size_t)n * 4 + layer];
    float dn2 = dn * dn;
    uint4 su = *reinterpret_cast<const uint4*>(&h16[(size_t)n * HID + c16 * 8]);
    ushort4 o0, o1v;
    o0.x  = f2bf_bits(dn * a0 + dn2 * bfl(su.x));
    o0.y  = f2bf_bits(dn * a1 + dn2 * bfh(su.x));
    o0.z  = f2bf_bits(dn * a2 + dn2 * bfl(su.y));
    o0.w  = f2bf_bits(dn * a3 + dn2 * bfh(su.y));
    o1v.x = f2bf_bits(dn * a4 + dn2 * bfl(su.z));
    o1v.y = f2bf_bits(dn * a5 + dn2 * bfh(su.z));
    o1v.z = f2bf_bits(dn * a6 + dn2 * bfl(su.w));
    o1v.w = f2bf_bits(dn * a7 + dn2 * bfh(su.w));
    *reinterpret_cast<ushort4*>(&out16[(size_t)n * HID + c16 * 8]) = o0;
    *reinterpret_cast<ushort4*>(&out16[(size_t)n * HID + c16 * 8 + 4]) = o1v;
  }
}

// ---------------- mean pool, 2-phase (bf16 input) ---------------------------
__global__ __launch_bounds__(128) void pool_partial(const unsigned short* __restrict__ h16,
                                                    const int* __restrict__ batch,
                                                    float* __restrict__ part) {
  int g = blockIdx.x, chunk = blockIdx.y, c = threadIdx.x;
  int lo = 0, hi = NN;
  while (lo < hi) { int mid = (lo + hi) >> 1; if (batch[mid] < g) lo = mid + 1; else hi = mid; }
  int start = lo;
  hi = NN;
  while (lo < hi) { int mid = (lo + hi) >> 1; if (batch[mid] < g + 1) lo = mid + 1; else hi = mid; }
  int end = lo;
  int len = end - start;
  int per = (len + PCH - 1) / PCH;
  int s = start + chunk * per;
  int e = min(s + per, end);
  float sum = 0.f;
  for (int n = s; n < e; n++) sum += bfl((unsigned)h16[(size_t)n * HID + c]);
  part[((size_t)g * PCH + chunk) * HID + c] = sum;
}

__global__ __launch_bounds__(128) void pool_combine(const float* __restrict__ part,
                                                    const int* __restrict__ batch,
                                                    float* __restrict__ cat) {
  int g = blockIdx.x, c = threadIdx.x;
  int lo = 0, hi = NN;
  while (lo < hi) { int mid = (lo + hi) >> 1; if (batch[mid] < g) lo = mid + 1; else hi = mid; }
  int start = lo;
  hi = NN;
  while (lo < hi) { int mid = (lo + hi) >> 1; if (batch[mid] < g + 1) lo = mid + 1; else hi = mid; }
  int end = lo;
  float s = 0.f;
#pragma unroll
  for (int k = 0; k < PCH; k++) s += part[((size_t)g * PCH + k) * HID + c];
  float cntf = (float)(end - start);
  cat[(size_t)g * PIN + c] = s / fmaxf(cntf, 1.f);
}

// ---------------- final [G,512] @ [512,1] + b -> out ------------------------
__global__ __launch_bounds__(64) void final_kernel(const float* __restrict__ A,
                                                   const void* __restrict__ W,
                                                   const void* __restrict__ b,
                                                   void* __restrict__ outp,
                                                   const int* __restrict__ flag) {
  bool bf = *flag != 0;
  int g = blockIdx.x, lane = threadIdx.x;
  float s = 0.f;
  for (int k = lane; k < PH; k += 64) s = fmaf(A[(size_t)g * PH + k], ldf(W, k, bf), s);
#pragma unroll
  for (int off = 32; off > 0; off >>= 1) s += __shfl_down(s, off);
  if (lane == 0) {
    float r = s + ldf(b, 0, bf);
    if (bf) ((bf16*)outp)[g] = __float2bfloat16(r);
    else    ((float*)outp)[g] = r;
  }
}

// ---------------------------------------------------------------------------
extern "C" void kernel_launch(void* const* d_in, const int* in_sizes, int n_in,
                              void* d_out, int out_size, void* d_ws, size_t ws_size,
                              hipStream_t stream) {
  const void* x      = d_in[0];
  const int*  ei     = (const int*)d_in[1];
  const void* eattr  = d_in[2];
  const int*  batch  = (const int*)d_in[3];
  const void* molf   = d_in[4];
  const void* lin_W  = d_in[5];
  const void* mW1    = d_in[6];
  const void* mb1    = d_in[7];
  const void* mW2    = d_in[8];
  const void* mb2    = d_in[9];
  const void* cbias  = d_in[10];
  const void* gW     = d_in[11];
  const void* gb     = d_in[12];
  const void* mlpW0  = d_in[13];
  const void* mlpb0  = d_in[14];
  const void* mlpW1  = d_in[15];
  const void* mlpb1  = d_in[16];
  const void* mlpW2  = d_in[17];
  const void* mlpb2  = d_in[18];
  const void* mlpW3  = d_in[19];
  const void* mlpb3  = d_in[20];
  const void* predW0 = d_in[21];
  const void* predb0 = d_in[22];
  const void* predW1 = d_in[23];
  const void* predb1 = d_in[24];
  const void* outW   = d_in[25];
  const void* outb   = d_in[26];

  char* base = (char*)d_ws;
  size_t off = 0;
  auto alloc = [&](size_t bytes) -> char* {
    char* p = base + off;
    off = (off + bytes + 255) & ~(size_t)255;
    return p;
  };
  unsigned short* h16  = (unsigned short*)alloc((size_t)NN * HID * 2);
  unsigned short* t16  = (unsigned short*)alloc((size_t)NN * HID * 2);
  float* dinv4    = (float*)alloc((size_t)NN * 4 * 4);
  int*   cntp     = (int*)alloc((size_t)NN * CPAD * 4);
  int*   offs     = (int*)alloc((size_t)(NN + 1) * 4);
  int*   rank     = (int*)alloc((size_t)EE * 4);
  int*   bsum     = (int*)alloc((size_t)256 * 4);
  char*  csr_rec  = alloc((size_t)EE * 32);
  int*   csr_src  = (int*)alloc((size_t)EE * 4);
  float* csr_g    = (float*)alloc((size_t)NL * EE * 4);
  float* w_all4   = (float*)alloc((size_t)EE * 4 * 4);
  unsigned short* Wt    = (unsigned short*)alloc((size_t)NL * HID * HID * 2);
  float* bprime   = (float*)alloc((size_t)NL * HID * 4);
  unsigned short* tailW = (unsigned short*)alloc((size_t)622592 * 2);
  unsigned short* edgeW = (unsigned short*)alloc((size_t)256 * 32 * 2);
  int*   flag     = (int*)alloc(256);
  float* part     = (float*)alloc((size_t)GG * PCH * HID * 4);
  float* molf32   = (float*)alloc((size_t)GG * 256 * 4);
  float* m0       = (float*)alloc((size_t)GG * MH * 4);
  float* m1       = (float*)alloc((size_t)GG * MH * 4);
  float* cat      = (float*)alloc((size_t)GG * PIN * 4);
  float* p0       = (float*)alloc((size_t)GG * PH * 4);
  float* p1       = (float*)alloc((size_t)GG * PH * 4);

  hipMemsetAsync(cntp, 0, (size_t)NN * CPAD * 4, stream);
  hipMemsetAsync(molf32, 0, (size_t)GG * 256 * 4, stream);

  // dtype probe first — everything downstream branches on it
  probe_kernel<<<1, 64, 0, stream>>>((const unsigned short*)x, flag);

  // weight prep (fused layer weights + tail + edge)
  prep_fused_w<<<256, 256, 0, stream>>>(lin_W, gW, Wt, flag);
  prep_fused_b<<<NL, 128, 0, stream>>>(cbias, gW, gb, bprime, flag);
  prep_tail<<<(622592 + 255) / 256, 256, 0, stream>>>(mlpW0, mlpW1, mlpW2, mlpW3,
                                                      predW0, predW1, tailW, flag);
  prep_edge_w<<<32, 256, 0, stream>>>(mW1, mb1, edgeW, flag);

  // x -> bf16 layer state
  {
    int n8 = NN * HID / 8;
    cvt_to_bf16<<<(n8 + 255) / 256, 256, 0, stream>>>(x, h16, n8, flag);
  }
  // edge gates (MFMA) + fused CSR count (rank via padded atomics)
  edge_mlp_mfma<<<(EE + EMB - 1) / EMB, 256, 0, stream>>>(eattr, edgeW, mW2, mb2,
                                                          w_all4, ei, cntp, rank, flag);
  // CSR scan + atomic-free fill
  scan_phase1<<<SCAN_B, 256, 0, stream>>>(cntp, bsum);
  scan_phase2<<<1, 256, 0, stream>>>(bsum, offs);
  scan_phase3<<<SCAN_B, 256, 0, stream>>>(cntp, bsum, offs);
  fill_kernel<<<(EE + 255) / 256, 256, 0, stream>>>(ei, offs, rank,
                                                    (const float4*)w_all4, csr_rec);
  // degrees, then split records into SoA {src, per-layer scaled gates}
  deg_kernel<<<(NN + 255) / 256, 256, 0, stream>>>(offs, csr_rec, dinv4);
  csr_split_kernel<<<(EE + 255) / 256, 256, 0, stream>>>(csr_rec, dinv4,
                                                         csr_src, csr_g);

  // GCN layers (fused): aggregate(h16)->t16; gemm(t16, W'_l, b'_l, relu)->h16
  const int gemm_blocks = (NN + 63) / 64;  // 782
  for (int l = 0; l < NL; l++) {
    aggregate_kernel<<<NN, 64, 0, stream>>>(h16, offs, csr_src,
                                            csr_g + (size_t)l * EE, dinv4, l, t16);
    gemm_nodes_bf16<<<gemm_blocks, 256, 0, stream>>>(
        t16, Wt + (size_t)l * HID * HID, bprime + (size_t)l * HID, h16, 1);
  }

  // pooling -> cat[:, 0:128]  (2-phase, bf16 input)
  pool_partial<<<dim3(GG, PCH), 128, 0, stream>>>(h16, batch, part);
  pool_combine<<<GG, 128, 0, stream>>>(part, batch, cat);

  // molecular MLP -> cat[:, 128:256]  (MFMA tail, K-padded weights)
  cvt_molf<<<(GG * 50 + 255) / 256, 256, 0, stream>>>(molf, molf32, flag);
  gemm_tail_mfma<<<dim3(4, 4), 256, 0, stream>>>(molf32, 256, tailW + 0,      256, mlpb0, m0, 256, 1, flag);
  gemm_tail_mfma<<<dim3(4, 4), 256, 0, stream>>>(m0,     256, tailW + 65536,  256, mlpb1, m1, 256, 1, flag);
  gemm_tail_mfma<<<dim3(4, 4), 256, 0, stream>>>(m1,     256, tailW + 131072, 256, mlpb2, m0, 256, 1, flag);
  gemm_tail_mfma<<<dim3(4, 2), 256, 0, stream>>>(m0,     256, tailW + 196608, 256, mlpb3, cat + MOUT, 256, 1, flag);

  // predictor
  gemm_tail_mfma<<<dim3(4, 8), 256, 0, stream>>>(cat, 256, tailW + 229376, 256, predb0, p0, 512, 1, flag);
  gemm_tail_mfma<<<dim3(4, 8), 256, 0, stream>>>(p0,  512, tailW + 360448, 512, predb1, p1, 512, 1, flag);
  final_kernel<<<GG, 64, 0, stream>>>(p1, outW, outb, d_out, flag);
}

// Round 15
// 531.201 us; speedup vs baseline: 1.1329x; 1.0016x over previous
//
#include <hip/hip_runtime.h>
#include <hip/hip_bf16.h>

// ---------------------------------------------------------------------------
// PDNConv GNN, MI355X round 32 — RESUBMIT of round 31 (infra failure, no data).
// r30 WIN (532.0): count fused into edge_mlp (count_kernel deleted, net -10.5)
// BUT edge_mlp rose 42->52.5 (predicted 43-46). Diagnosis: the fused count's
// atomicAdd is issued FIRST, and vmcnt retires in issue order -> the first
// s_waitcnt for afrag/eattr loads implicitly waits for the contended atomic,
// putting ~ hundreds of cycles on every wave's prologue critical path.
// This round: move the count block to the EPILOGUE (after gate stores).
// Atomic latency drops behind all MFMA/gather work; only wave-retire tail
// exposed (hidden by ~65% occupancy). All else = round-30.
// ---------------------------------------------------------------------------

#define NN 50000
#define EE 600000
#define GG 256
#define HID 128
#define EDIM 16
#define EHID 64
#define NL 4
#define MIN_F 200
#define MH 256
#define MOUT 128
#define PH 512
#define PIN 256
#define SCAN_B 196  // ceil(NN/256)
#define PCH 8       // pooling chunks per graph
#define EMB 128     // edges per block (edge_mlp)
#define CPAD 16     // ints per counter line (64B)

typedef __hip_bfloat16 bf16;
typedef __attribute__((ext_vector_type(8))) short bf16x8;
typedef __attribute__((ext_vector_type(4))) float f32x4;

__device__ __forceinline__ float bfl(unsigned u) { return __uint_as_float(u << 16); }
__device__ __forceinline__ float bfh(unsigned u) { return __uint_as_float(u & 0xffff0000u); }
__device__ __forceinline__ float b2f(bf16 x) { return __bfloat162float(x); }
__device__ __forceinline__ float ldf(const void* p, long i, bool bf) {
  return bf ? __bfloat162float(((const bf16*)p)[i]) : ((const float*)p)[i];
}
__device__ __forceinline__ unsigned short f2bf_bits(float v) {
  bf16 h = __float2bfloat16(v);
  return *reinterpret_cast<unsigned short*>(&h);
}

// ---------------- dtype probe ------------------------------------------------
__global__ void probe_kernel(const unsigned short* __restrict__ xs, int* flag) {
  if (threadIdx.x == 0 && blockIdx.x == 0) {
    int sane = 0;
    for (int i = 0; i < 128; i++) {
      unsigned e = (xs[i] >> 7) & 0xFF;
      if (e >= 96 && e <= 159) sane++;
    }
    *flag = (sane >= 112) ? 1 : 0;  // 1 = bf16 inputs
  }
}

// ---------------- input -> bf16 conversion (8 elems/thread) -----------------
__global__ __launch_bounds__(256) void cvt_to_bf16(const void* __restrict__ in,
                                                   unsigned short* __restrict__ outp,
                                                   int n8, const int* __restrict__ flag) {
  bool bf = *flag != 0;
  int i = blockIdx.x * 256 + threadIdx.x;
  if (i >= n8) return;
  if (bf) {
    reinterpret_cast<uint4*>(outp)[i] = reinterpret_cast<const uint4*>(in)[i];
  } else {
    const float4* p = reinterpret_cast<const float4*>(in) + (size_t)i * 2;
    float4 v0 = p[0], v1 = p[1];
    ushort4 a, b;
    a.x = f2bf_bits(v0.x); a.y = f2bf_bits(v0.y);
    a.z = f2bf_bits(v0.z); a.w = f2bf_bits(v0.w);
    b.x = f2bf_bits(v1.x); b.y = f2bf_bits(v1.y);
    b.z = f2bf_bits(v1.z); b.w = f2bf_bits(v1.w);
    reinterpret_cast<ushort4*>(outp)[i * 2] = a;
    reinterpret_cast<ushort4*>(outp)[i * 2 + 1] = b;
  }
}

// ---------------- mol_features [G,200] -> padded f32 [G,256] ----------------
__global__ __launch_bounds__(256) void cvt_molf(const void* __restrict__ in,
                                                float* __restrict__ outp,
                                                const int* __restrict__ flag) {
  bool bf = *flag != 0;
  int i = blockIdx.x * 256 + threadIdx.x;  // GG*50
  if (i >= GG * 50) return;
  int row = i / 50, c4 = (i % 50) * 4;
  float4 v;
  if (bf) {
    const unsigned short* p = (const unsigned short*)in + (size_t)row * MIN_F + c4;
    uint2 u = *reinterpret_cast<const uint2*>(p);
    v.x = bfl(u.x); v.y = bfh(u.x); v.z = bfl(u.y); v.w = bfh(u.y);
  } else {
    v = *reinterpret_cast<const float4*>((const float*)in + (size_t)row * MIN_F + c4);
  }
  *reinterpret_cast<float4*>(&outp[(size_t)row * 256 + c4]) = v;
}

// ---------------- weight prep: fused W'_l = linW_l @ gW_l -> bf16 [n][k] ----
__global__ __launch_bounds__(256) void prep_fused_w(const void* __restrict__ lin_W,
                                                    const void* __restrict__ gW,
                                                    unsigned short* __restrict__ Wt,
                                                    const int* __restrict__ flag) {
  bool bf = *flag != 0;
  int idx = blockIdx.x * 256 + threadIdx.x;  // 0 .. 4*16384-1
  if (idx >= 4 * 16384) return;
  int l = idx >> 14;
  int rem = idx & 16383;
  int n = rem >> 7, k = rem & 127;  // Wt[n][k] = W'[k][n]
  float s = 0.f;
  long lb = (long)l * 16384;
  for (int m = 0; m < 128; m++)
    s += ldf(lin_W, lb + (long)k * 128 + m, bf) * ldf(gW, lb + (long)m * 128 + n, bf);
  Wt[idx] = f2bf_bits(s);
}

// b'_l[n] = gb_l[n] + sum_k cbias_l[k] * gW_l[k][n]   (f32)
__global__ __launch_bounds__(128) void prep_fused_b(const void* __restrict__ cbias,
                                                    const void* __restrict__ gW,
                                                    const void* __restrict__ gb,
                                                    float* __restrict__ bprime,
                                                    const int* __restrict__ flag) {
  bool bf = *flag != 0;
  int idx = blockIdx.x * 128 + threadIdx.x;  // 0 .. 4*128-1
  if (idx >= NL * HID) return;
  int l = idx >> 7, n = idx & 127;
  float s = ldf(gb, idx, bf);
  long lb = (long)l * 16384;
  for (int k = 0; k < 128; k++)
    s += ldf(cbias, (long)l * 128 + k, bf) * ldf(gW, lb + (long)k * 128 + n, bf);
  bprime[idx] = s;
}

// ---------------- weight prep: edge MLP W1 -> bf16 W1t[256 cols][32 K] ------
// k<16: W1; k==16: b1 (MFMA bias-fold); k>16: 0.
__global__ __launch_bounds__(256) void prep_edge_w(const void* __restrict__ mW1,
                                                   const void* __restrict__ mb1,
                                                   unsigned short* __restrict__ W1t,
                                                   const int* __restrict__ flag) {
  bool bf = *flag != 0;
  int idx = blockIdx.x * 256 + threadIdx.x;  // 256*32
  if (idx >= 256 * 32) return;
  int col = idx >> 5, k = idx & 31;
  float v = 0.f;
  if (k < EDIM) v = ldf(mW1, (long)(col >> 6) * (EDIM * EHID) + (long)k * EHID + (col & 63), bf);
  else if (k == EDIM) v = ldf(mb1, col, bf);
  W1t[idx] = f2bf_bits(v);
}

// ---------------- weight prep: tail (MLP+predictor) -> bf16 [N][Kp], K-pad --
__global__ __launch_bounds__(256) void prep_tail(
    const void* __restrict__ mlpW0, const void* __restrict__ mlpW1,
    const void* __restrict__ mlpW2, const void* __restrict__ mlpW3,
    const void* __restrict__ predW0, const void* __restrict__ predW1,
    unsigned short* __restrict__ T, const int* __restrict__ flag) {
  bool bf = *flag != 0;
  int idx = blockIdx.x * 256 + threadIdx.x;
  const void* src; int N, Kp, Ksrc, off;
  if      (idx < 65536)  { src = mlpW0;  N = 256; Kp = 256; Ksrc = 200; off = 0; }
  else if (idx < 131072) { src = mlpW1;  N = 256; Kp = 256; Ksrc = 256; off = 65536; }
  else if (idx < 196608) { src = mlpW2;  N = 256; Kp = 256; Ksrc = 256; off = 131072; }
  else if (idx < 229376) { src = mlpW3;  N = 128; Kp = 256; Ksrc = 256; off = 196608; }
  else if (idx < 360448) { src = predW0; N = 512; Kp = 256; Ksrc = 256; off = 229376; }
  else if (idx < 622592) { src = predW1; N = 512; Kp = 512; Ksrc = 512; off = 360448; }
  else return;
  int rem = idx - off;
  int n = rem / Kp, k = rem % Kp;
  float v = (k < Ksrc) ? ldf(src, (long)k * N + n, bf) : 0.f;
  T[idx] = f2bf_bits(v);
}

// ---------------- CSR scan (count fused into edge_mlp) ----------------------
__global__ __launch_bounds__(256) void scan_phase1(const int* __restrict__ cntp,
                                                   int* __restrict__ bsum) {
  __shared__ int red[256];
  int tid = threadIdx.x;
  int i = blockIdx.x * 256 + tid;
  red[tid] = (i < NN) ? cntp[(size_t)i * CPAD] : 0;
  __syncthreads();
  for (int off = 128; off > 0; off >>= 1) {
    if (tid < off) red[tid] += red[tid + off];
    __syncthreads();
  }
  if (tid == 0) bsum[blockIdx.x] = red[0];
}

__global__ __launch_bounds__(256) void scan_phase2(int* __restrict__ bsum,
                                                   int* __restrict__ offs) {
  __shared__ int buf[256];
  int tid = threadIdx.x;
  int v = (tid < SCAN_B) ? bsum[tid] : 0;
  buf[tid] = v;
  __syncthreads();
  for (int off = 1; off < 256; off <<= 1) {
    int t = (tid >= off) ? buf[tid - off] : 0;
    __syncthreads();
    buf[tid] += t;
    __syncthreads();
  }
  if (tid < SCAN_B) bsum[tid] = buf[tid] - v;  // exclusive block offsets
  if (tid == 255) offs[NN] = buf[255];
}

__global__ __launch_bounds__(256) void scan_phase3(const int* __restrict__ cntp,
                                                   const int* __restrict__ bsum,
                                                   int* __restrict__ offs) {
  __shared__ int buf[256];
  int tid = threadIdx.x;
  int i = blockIdx.x * 256 + tid;
  int v = (i < NN) ? cntp[(size_t)i * CPAD] : 0;
  buf[tid] = v;
  __syncthreads();
  for (int off = 1; off < 256; off <<= 1) {
    int t = (tid >= off) ? buf[tid - off] : 0;
    __syncthreads();
    buf[tid] += t;
    __syncthreads();
  }
  if (i < NN) offs[i] = bsum[blockIdx.x] + buf[tid] - v;
}

// fill: ATOMIC-FREE. pos = offs[c] + rank[e]; scatter 32B record {src, g4}.
__global__ __launch_bounds__(256) void fill_kernel(const int* __restrict__ ei,
                                                   const int* __restrict__ offs,
                                                   const int* __restrict__ rank,
                                                   const float4* __restrict__ w_all4,
                                                   char* __restrict__ csr_rec) {
  int e = blockIdx.x * 256 + threadIdx.x;
  if (e >= EE) return;
  int c = ei[EE + e];
  c = min(max(c, 0), NN - 1);
  int src = min(max(ei[e], 0), NN - 1);
  float4 g = w_all4[e];  // coalesced
  int pos = offs[c] + rank[e];
  pos = min(max(pos, 0), EE - 1);
  char* r = csr_rec + (size_t)pos * 32;
  *reinterpret_cast<int*>(r) = src;
  *reinterpret_cast<float4*>(r + 16) = g;
}

// ---------------- edge-gate MLP via MFMA + fused CSR count (epilogue) -------
// r20 form (swapped operands, 128 e/blk). The CSR count for this block's 128
// edges runs AFTER the gate stores: the contended atomic sits behind all
// MFMA/gather work in vmcnt issue order, so no downstream load waits on it.
__global__ __launch_bounds__(256) void edge_mlp_mfma(
    const void* __restrict__ eattr, const unsigned short* __restrict__ W1t,
    const void* __restrict__ mW2, const void* __restrict__ mb2,
    float* __restrict__ w_all4, const int* __restrict__ ei,
    int* __restrict__ cntp, int* __restrict__ rank,
    const int* __restrict__ flag) {
  bool bf = *flag != 0;
  int tid = threadIdx.x;
  int wave = tid >> 6, lane = tid & 63;  // wave == layer index
  int l15 = lane & 15, quad = lane >> 4;
  int ebase = blockIdx.x * EMB;

  bf16x8 afrag[4];
#pragma unroll
  for (int t = 0; t < 4; t++)
    afrag[t] =
        *reinterpret_cast<const bf16x8*>(&W1t[((wave * 4 + t) * 16 + l15) * 32 + quad * 8]);

  float w2v[16];
#pragma unroll
  for (int t = 0; t < 4; t++)
#pragma unroll
    for (int r = 0; r < 4; r++)
      w2v[t * 4 + r] = ldf(mW2, wave * 64 + t * 16 + quad * 4 + r, bf);
  float b2 = ldf(mb2, wave, bf);

  bf16x8 bconst = (bf16x8){0, 0, 0, 0, 0, 0, 0, 0};
  if (quad == 2) bconst[0] = (short)0x3F80;  // k=16 element = bf16(1.0)

  int rowbytes = bf ? EDIM * 2 : EDIM * 4;
  const char* p = (const char*)eattr + (size_t)(ebase + l15) * rowbytes +
                  (size_t)quad * (rowbytes >> 1);
  int fragstep = 16 * rowbytes;

  auto loadb = [&](int fb, const char* pp) -> bf16x8 {
    bf16x8 v = bconst;
    if (quad < 2 && fb < EE) {
      if (bf) {
        v = *reinterpret_cast<const bf16x8*>(pp);
      } else {
        const float4* q = reinterpret_cast<const float4*>(pp);
        float4 v0 = q[0], v1 = q[1];
        v[0] = (short)f2bf_bits(v0.x); v[1] = (short)f2bf_bits(v0.y);
        v[2] = (short)f2bf_bits(v0.z); v[3] = (short)f2bf_bits(v0.w);
        v[4] = (short)f2bf_bits(v1.x); v[5] = (short)f2bf_bits(v1.y);
        v[6] = (short)f2bf_bits(v1.z); v[7] = (short)f2bf_bits(v1.w);
      }
    }
    return v;
  };

  bf16x8 bcur = loadb(ebase, p);
#pragma unroll 2
  for (int f = 0; f < EMB / 16; f++) {
    int fbase = ebase + f * 16;
    p += fragstep;
    bf16x8 bnxt = loadb(fbase + 16, p);  // prefetch next fragment
    if (fbase < EE) {
      float s0 = 0.f, s1 = 0.f, s2 = 0.f, s3 = 0.f;
#define DO_T(T, S)                                                            \
  {                                                                           \
    f32x4 acc = __builtin_amdgcn_mfma_f32_16x16x32_bf16(                      \
        afrag[T], bcur, (f32x4){0.f, 0.f, 0.f, 0.f}, 0, 0, 0);                \
    S = fmaf(fmaxf(acc.x, 0.f), w2v[T * 4 + 0], S);                           \
    S = fmaf(fmaxf(acc.y, 0.f), w2v[T * 4 + 1], S);                           \
    S = fmaf(fmaxf(acc.z, 0.f), w2v[T * 4 + 2], S);                           \
    S = fmaf(fmaxf(acc.w, 0.f), w2v[T * 4 + 3], S);                           \
  }
      DO_T(0, s0) DO_T(1, s1) DO_T(2, s2) DO_T(3, s3)
#undef DO_T
      float s = (s0 + s1) + (s2 + s3);
      s += __shfl_xor(s, 16);  // combine quads 0<->1, 2<->3
      s += __shfl_xor(s, 32);  // combine halves
      if (quad == 0) {
        float g = 1.f / (1.f + __expf(-(s + b2)));
        w_all4[(size_t)(fbase + l15) * 4 + wave] = g;
      }
    }
    bcur = bnxt;
  }

  // ---- fused CSR count, EPILOGUE (threads 0..127 -> this block's edges) ----
  {
    int ecnt = min(EMB, EE - ebase);
    if (tid < ecnt) {
      int e = ebase + tid;
      int c = ei[EE + e];
      c = min(max(c, 0), NN - 1);
      rank[e] = atomicAdd(&cntp[(size_t)c * CPAD], 1);
    }
  }
}

// ---------------- degree / dinv per layer (reads 32B records) ---------------
__global__ __launch_bounds__(256) void deg_kernel(const int* __restrict__ offs,
                                                  const char* __restrict__ csr_rec,
                                                  float* __restrict__ dinv4) {
  int n = blockIdx.x * 256 + threadIdx.x;
  if (n >= NN) return;
  int s = offs[n], e = offs[n + 1];
  float d0 = 1.f, d1 = 1.f, d2 = 1.f, d3 = 1.f;  // self-loop weight 1.0
  for (int k = s; k < e; k++) {
    float4 g = *reinterpret_cast<const float4*>(csr_rec + (size_t)k * 32 + 16);
    d0 += g.x; d1 += g.y; d2 += g.z; d3 += g.w;
  }
  float4 o;
  o.x = rsqrtf(d0); o.y = rsqrtf(d1); o.z = rsqrtf(d2); o.w = rsqrtf(d3);
  reinterpret_cast<float4*>(dinv4)[n] = o;
}

// split: record -> SoA {csr_src[k], csr_g[l][k] = g_l * dinv_l[src]}
__global__ __launch_bounds__(256) void csr_split_kernel(const char* __restrict__ csr_rec,
                                                        const float* __restrict__ dinv4,
                                                        int* __restrict__ csr_src,
                                                        float* __restrict__ csr_g) {
  int k = blockIdx.x * 256 + threadIdx.x;
  if (k >= EE) return;
  const char* r = csr_rec + (size_t)k * 32;
  int s = *reinterpret_cast<const int*>(r);
  s = min(max(s, 0), NN - 1);
  float4 d = reinterpret_cast<const float4*>(dinv4)[s];
  float4 g = *reinterpret_cast<const float4*>(r + 16);
  csr_src[k] = s;
  csr_g[k] = g.x * d.x;
  csr_g[(size_t)EE + k] = g.y * d.y;
  csr_g[2 * (size_t)EE + k] = g.z * d.z;
  csr_g[3 * (size_t)EE + k] = g.w * d.w;
}

// ---------------- node GEMM via MFMA: bf16 in/out, f32 bias -----------------
__global__ __launch_bounds__(256) void gemm_nodes_bf16(
    const unsigned short* __restrict__ A16, const unsigned short* __restrict__ Wt,
    const float* __restrict__ bias, unsigned short* __restrict__ out16,
    int relu) {
  __shared__ alignas(16) unsigned short sA[64 * 136];
  __shared__ alignas(16) unsigned short sW[128 * 136];
  int tid = threadIdx.x;
  int rbase = blockIdx.x * 64;

#pragma unroll
  for (int p = 0; p < 8; p++) {
    int idx8 = p * 256 + tid;
    int n = idx8 >> 4, kc = idx8 & 15;
    uint4 v = reinterpret_cast<const uint4*>(Wt)[idx8];
    *reinterpret_cast<uint4*>(&sW[n * 136 + kc * 8]) = v;
  }
#pragma unroll
  for (int p = 0; p < 4; p++) {
    int idx8 = p * 256 + tid;
    int m = idx8 >> 4, kc = idx8 & 15;
    int row = rbase + m;
    uint4 v = make_uint4(0u, 0u, 0u, 0u);
    if (row < NN)
      v = *reinterpret_cast<const uint4*>(&A16[(size_t)row * HID + kc * 8]);
    *reinterpret_cast<uint4*>(&sA[m * 136 + kc * 8]) = v;
  }
  __syncthreads();

  int wave = tid >> 6, lane = tid & 63;
  int l15 = lane & 15, quad = lane >> 4;
  int mstrip = wave * 16;

  f32x4 acc[8];
#pragma unroll
  for (int t = 0; t < 8; t++) acc[t] = (f32x4){0.f, 0.f, 0.f, 0.f};

#pragma unroll
  for (int ks = 0; ks < 4; ks++) {
    int k0 = ks * 32 + quad * 8;
    bf16x8 a = *reinterpret_cast<const bf16x8*>(&sA[(mstrip + l15) * 136 + k0]);
#pragma unroll
    for (int t = 0; t < 8; t++) {
      bf16x8 b = *reinterpret_cast<const bf16x8*>(&sW[(t * 16 + l15) * 136 + k0]);
      acc[t] = __builtin_amdgcn_mfma_f32_16x16x32_bf16(a, b, acc[t], 0, 0, 0);
    }
  }

#pragma unroll
  for (int t = 0; t < 8; t++) {
    int n = t * 16 + l15;
    float bv = bias ? bias[n] : 0.f;
#pragma unroll
    for (int r = 0; r < 4; r++) {
      int row = rbase + mstrip + quad * 4 + r;
      if (row < NN) {
        float o = acc[t][r] + bv;
        if (relu) o = fmaxf(o, 0.f);
        out16[(size_t)row * HID + n] = f2bf_bits(o);
      }
    }
  }
}

// ---------------- tail GEMM via MFMA ----------------------------------------
__global__ __launch_bounds__(256) void gemm_tail_mfma(
    const float* __restrict__ A, int lda, const unsigned short* __restrict__ Wt,
    int Kp, const void* __restrict__ bias, float* __restrict__ outp, int ldo,
    int relu, const int* __restrict__ flag) {
  __shared__ alignas(16) unsigned short sA[64 * 264];
  __shared__ alignas(16) unsigned short sW[64 * 264];
  int tid = threadIdx.x;
  int rbase = blockIdx.x * 64;
  int nbase = blockIdx.y * 64;
  int wave = tid >> 6, lane = tid & 63;
  int l15 = lane & 15, quad = lane >> 4;
  int mstrip = wave * 16;

  f32x4 acc[4];
#pragma unroll
  for (int t = 0; t < 4; t++) acc[t] = (f32x4){0.f, 0.f, 0.f, 0.f};

  for (int kc = 0; kc < Kp; kc += 256) {
#pragma unroll 4
    for (int p = 0; p < 16; p++) {
      int idx = p * 1024 + tid * 4;
      int m = idx >> 8, k = idx & 255;
      float4 v = *reinterpret_cast<const float4*>(&A[(size_t)(rbase + m) * lda + kc + k]);
      ushort4 b;
      b.x = f2bf_bits(v.x); b.y = f2bf_bits(v.y);
      b.z = f2bf_bits(v.z); b.w = f2bf_bits(v.w);
      *reinterpret_cast<ushort4*>(&sA[m * 264 + k]) = b;
    }
#pragma unroll 4
    for (int p = 0; p < 8; p++) {
      int idx8 = p * 256 + tid;
      int n = idx8 >> 5, kk = (idx8 & 31) * 8;
      uint4 v = *reinterpret_cast<const uint4*>(&Wt[(size_t)(nbase + n) * Kp + kc + kk]);
      *reinterpret_cast<uint4*>(&sW[n * 264 + kk]) = v;
    }
    __syncthreads();
#pragma unroll
    for (int ks = 0; ks < 8; ks++) {
      int k0 = ks * 32 + quad * 8;
      bf16x8 a = *reinterpret_cast<const bf16x8*>(&sA[(mstrip + l15) * 264 + k0]);
#pragma unroll
      for (int nt = 0; nt < 4; nt++) {
        bf16x8 b = *reinterpret_cast<const bf16x8*>(&sW[(nt * 16 + l15) * 264 + k0]);
        acc[nt] = __builtin_amdgcn_mfma_f32_16x16x32_bf16(a, b, acc[nt], 0, 0, 0);
      }
    }
    __syncthreads();
  }

  bool bf = *flag != 0;
#pragma unroll
  for (int nt = 0; nt < 4; nt++) {
    int col = nbase + nt * 16 + l15;
    float bv = ldf(bias, col, bf);
#pragma unroll
    for (int r = 0; r < 4; r++) {
      int row = rbase + mstrip + quad * 4 + r;
      float o = acc[nt][r] + bv;
      if (relu) o = fmaxf(o, 0.f);
      outp[(size_t)row * ldo + col] = o;
    }
  }
}

// ---------------- aggregation: 1 wave/node, SoA staging ---------------------
__global__ __launch_bounds__(64) void aggregate_kernel(
    const unsigned short* __restrict__ h16, const int* __restrict__ offs,
    const int* __restrict__ csr_src, const float* __restrict__ csr_gl,
    const float* __restrict__ dinv4, int layer,
    unsigned short* __restrict__ out16) {
  int n = blockIdx.x;
  int lane = threadIdx.x;      // 0..63
  int grp = lane >> 4;         // j-slot
  int c16 = lane & 15;         // 16B channel chunk (8 bf16)
  __shared__ int s_src[64];
  __shared__ float s_val[64];
  int start = offs[n], end = offs[n + 1];
  float a0 = 0.f, a1 = 0.f, a2 = 0.f, a3 = 0.f;
  float a4 = 0.f, a5 = 0.f, a6 = 0.f, a7 = 0.f;
  for (int base = start; base < end; base += 64) {
    int k = base + lane;
    if (k < end) {
      s_src[lane] = min(max(csr_src[k], 0), NN - 1);
      s_val[lane] = csr_gl[k];
    }
    __syncthreads();
    int m = min(64, end - base);
    for (int j = grp; j < m; j += 4) {
      float v = s_val[j];
      uint4 u = *reinterpret_cast<const uint4*>(&h16[(size_t)s_src[j] * HID + c16 * 8]);
      a0 = fmaf(v, bfl(u.x), a0); a1 = fmaf(v, bfh(u.x), a1);
      a2 = fmaf(v, bfl(u.y), a2); a3 = fmaf(v, bfh(u.y), a3);
      a4 = fmaf(v, bfl(u.z), a4); a5 = fmaf(v, bfh(u.z), a5);
      a6 = fmaf(v, bfl(u.w), a6); a7 = fmaf(v, bfh(u.w), a7);
    }
    __syncthreads();
  }
  // combine the 4 j-slot groups (no barriers — in-wave shuffles)
  a0 += __shfl_xor(a0, 16); a1 += __shfl_xor(a1, 16);
  a2 += __shfl_xor(a2, 16); a3 += __shfl_xor(a3, 16);
  a4 += __shfl_xor(a4, 16); a5 += __shfl_xor(a5, 16);
  a6 += __shfl_xor(a6, 16); a7 += __shfl_xor(a7, 16);
  a0 += __shfl_xor(a0, 32); a1 += __shfl_xor(a1, 32);
  a2 += __shfl_xor(a2, 32); a3 += __shfl_xor(a3, 32);
  a4 += __shfl_xor(a4, 32); a5 += __shfl_xor(a5, 32);
  a6 += __shfl_xor(a6, 32); a7 += __shfl_xor(a7, 32);
  if (grp == 0) {
    float dn = dinv4[(size_t)n * 4 + layer];
    float dn2 = dn * dn;
    uint4 su = *reinterpret_cast<const uint4*>(&h16[(size_t)n * HID + c16 * 8]);
    ushort4 o0, o1v;
    o0.x  = f2bf_bits(dn * a0 + dn2 * bfl(su.x));
    o0.y  = f2bf_bits(dn * a1 + dn2 * bfh(su.x));
    o0.z  = f2bf_bits(dn * a2 + dn2 * bfl(su.y));
    o0.w  = f2bf_bits(dn * a3 + dn2 * bfh(su.y));
    o1v.x = f2bf_bits(dn * a4 + dn2 * bfl(su.z));
    o1v.y = f2bf_bits(dn * a5 + dn2 * bfh(su.z));
    o1v.z = f2bf_bits(dn * a6 + dn2 * bfl(su.w));
    o1v.w = f2bf_bits(dn * a7 + dn2 * bfh(su.w));
    *reinterpret_cast<ushort4*>(&out16[(size_t)n * HID + c16 * 8]) = o0;
    *reinterpret_cast<ushort4*>(&out16[(size_t)n * HID + c16 * 8 + 4]) = o1v;
  }
}

// ---------------- mean pool, 2-phase (bf16 input) ---------------------------
__global__ __launch_bounds__(128) void pool_partial(const unsigned short* __restrict__ h16,
                                                    const int* __restrict__ batch,
                                                    float* __restrict__ part) {
  int g = blockIdx.x, chunk = blockIdx.y, c = threadIdx.x;
  int lo = 0, hi = NN;
  while (lo < hi) { int mid = (lo + hi) >> 1; if (batch[mid] < g) lo = mid + 1; else hi = mid; }
  int start = lo;
  hi = NN;
  while (lo < hi) { int mid = (lo + hi) >> 1; if (batch[mid] < g + 1) lo = mid + 1; else hi = mid; }
  int end = lo;
  int len = end - start;
  int per = (len + PCH - 1) / PCH;
  int s = start + chunk * per;
  int e = min(s + per, end);
  float sum = 0.f;
  for (int n = s; n < e; n++) sum += bfl((unsigned)h16[(size_t)n * HID + c]);
  part[((size_t)g * PCH + chunk) * HID + c] = sum;
}

__global__ __launch_bounds__(128) void pool_combine(const float* __restrict__ part,
                                                    const int* __restrict__ batch,
                                                    float* __restrict__ cat) {
  int g = blockIdx.x, c = threadIdx.x;
  int lo = 0, hi = NN;
  while (lo < hi) { int mid = (lo + hi) >> 1; if (batch[mid] < g) lo = mid + 1; else hi = mid; }
  int start = lo;
  hi = NN;
  while (lo < hi) { int mid = (lo + hi) >> 1; if (batch[mid] < g + 1) lo = mid + 1; else hi = mid; }
  int end = lo;
  float s = 0.f;
#pragma unroll
  for (int k = 0; k < PCH; k++) s += part[((size_t)g * PCH + k) * HID + c];
  float cntf = (float)(end - start);
  cat[(size_t)g * PIN + c] = s / fmaxf(cntf, 1.f);
}

// ---------------- final [G,512] @ [512,1] + b -> out ------------------------
__global__ __launch_bounds__(64) void final_kernel(const float* __restrict__ A,
                                                   const void* __restrict__ W,
                                                   const void* __restrict__ b,
                                                   void* __restrict__ outp,
                                                   const int* __restrict__ flag) {
  bool bf = *flag != 0;
  int g = blockIdx.x, lane = threadIdx.x;
  float s = 0.f;
  for (int k = lane; k < PH; k += 64) s = fmaf(A[(size_t)g * PH + k], ldf(W, k, bf), s);
#pragma unroll
  for (int off = 32; off > 0; off >>= 1) s += __shfl_down(s, off);
  if (lane == 0) {
    float r = s + ldf(b, 0, bf);
    if (bf) ((bf16*)outp)[g] = __float2bfloat16(r);
    else    ((float*)outp)[g] = r;
  }
}

// ---------------------------------------------------------------------------
extern "C" void kernel_launch(void* const* d_in, const int* in_sizes, int n_in,
                              void* d_out, int out_size, void* d_ws, size_t ws_size,
                              hipStream_t stream) {
  const void* x      = d_in[0];
  const int*  ei     = (const int*)d_in[1];
  const void* eattr  = d_in[2];
  const int*  batch  = (const int*)d_in[3];
  const void* molf   = d_in[4];
  const void* lin_W  = d_in[5];
  const void* mW1    = d_in[6];
  const void* mb1    = d_in[7];
  const void* mW2    = d_in[8];
  const void* mb2    = d_in[9];
  const void* cbias  = d_in[10];
  const void* gW     = d_in[11];
  const void* gb     = d_in[12];
  const void* mlpW0  = d_in[13];
  const void* mlpb0  = d_in[14];
  const void* mlpW1  = d_in[15];
  const void* mlpb1  = d_in[16];
  const void* mlpW2  = d_in[17];
  const void* mlpb2  = d_in[18];
  const void* mlpW3  = d_in[19];
  const void* mlpb3  = d_in[20];
  const void* predW0 = d_in[21];
  const void* predb0 = d_in[22];
  const void* predW1 = d_in[23];
  const void* predb1 = d_in[24];
  const void* outW   = d_in[25];
  const void* outb   = d_in[26];

  char* base = (char*)d_ws;
  size_t off = 0;
  auto alloc = [&](size_t bytes) -> char* {
    char* p = base + off;
    off = (off + bytes + 255) & ~(size_t)255;
    return p;
  };
  unsigned short* h16  = (unsigned short*)alloc((size_t)NN * HID * 2);
  unsigned short* t16  = (unsigned short*)alloc((size_t)NN * HID * 2);
  float* dinv4    = (float*)alloc((size_t)NN * 4 * 4);
  int*   cntp     = (int*)alloc((size_t)NN * CPAD * 4);
  int*   offs     = (int*)alloc((size_t)(NN + 1) * 4);
  int*   rank     = (int*)alloc((size_t)EE * 4);
  int*   bsum     = (int*)alloc((size_t)256 * 4);
  char*  csr_rec  = alloc((size_t)EE * 32);
  int*   csr_src  = (int*)alloc((size_t)EE * 4);
  float* csr_g    = (float*)alloc((size_t)NL * EE * 4);
  float* w_all4   = (float*)alloc((size_t)EE * 4 * 4);
  unsigned short* Wt    = (unsigned short*)alloc((size_t)NL * HID * HID * 2);
  float* bprime   = (float*)alloc((size_t)NL * HID * 4);
  unsigned short* tailW = (unsigned short*)alloc((size_t)622592 * 2);
  unsigned short* edgeW = (unsigned short*)alloc((size_t)256 * 32 * 2);
  int*   flag     = (int*)alloc(256);
  float* part     = (float*)alloc((size_t)GG * PCH * HID * 4);
  float* molf32   = (float*)alloc((size_t)GG * 256 * 4);
  float* m0       = (float*)alloc((size_t)GG * MH * 4);
  float* m1       = (float*)alloc((size_t)GG * MH * 4);
  float* cat      = (float*)alloc((size_t)GG * PIN * 4);
  float* p0       = (float*)alloc((size_t)GG * PH * 4);
  float* p1       = (float*)alloc((size_t)GG * PH * 4);

  hipMemsetAsync(cntp, 0, (size_t)NN * CPAD * 4, stream);
  hipMemsetAsync(molf32, 0, (size_t)GG * 256 * 4, stream);

  // dtype probe first — everything downstream branches on it
  probe_kernel<<<1, 64, 0, stream>>>((const unsigned short*)x, flag);

  // weight prep (fused layer weights + tail + edge)
  prep_fused_w<<<256, 256, 0, stream>>>(lin_W, gW, Wt, flag);
  prep_fused_b<<<NL, 128, 0, stream>>>(cbias, gW, gb, bprime, flag);
  prep_tail<<<(622592 + 255) / 256, 256, 0, stream>>>(mlpW0, mlpW1, mlpW2, mlpW3,
                                                      predW0, predW1, tailW, flag);
  prep_edge_w<<<32, 256, 0, stream>>>(mW1, mb1, edgeW, flag);

  // x -> bf16 layer state
  {
    int n8 = NN * HID / 8;
    cvt_to_bf16<<<(n8 + 255) / 256, 256, 0, stream>>>(x, h16, n8, flag);
  }
  // edge gates (MFMA) + fused CSR count in epilogue
  edge_mlp_mfma<<<(EE + EMB - 1) / EMB, 256, 0, stream>>>(eattr, edgeW, mW2, mb2,
                                                          w_all4, ei, cntp, rank, flag);
  // CSR scan + atomic-free fill
  scan_phase1<<<SCAN_B, 256, 0, stream>>>(cntp, bsum);
  scan_phase2<<<1, 256, 0, stream>>>(bsum, offs);
  scan_phase3<<<SCAN_B, 256, 0, stream>>>(cntp, bsum, offs);
  fill_kernel<<<(EE + 255) / 256, 256, 0, stream>>>(ei, offs, rank,
                                                    (const float4*)w_all4, csr_rec);
  // degrees, then split records into SoA {src, per-layer scaled gates}
  deg_kernel<<<(NN + 255) / 256, 256, 0, stream>>>(offs, csr_rec, dinv4);
  csr_split_kernel<<<(EE + 255) / 256, 256, 0, stream>>>(csr_rec, dinv4,
                                                         csr_src, csr_g);

  // GCN layers (fused): aggregate(h16)->t16; gemm(t16, W'_l, b'_l, relu)->h16
  const int gemm_blocks = (NN + 63) / 64;  // 782
  for (int l = 0; l < NL; l++) {
    aggregate_kernel<<<NN, 64, 0, stream>>>(h16, offs, csr_src,
                                            csr_g + (size_t)l * EE, dinv4, l, t16);
    gemm_nodes_bf16<<<gemm_blocks, 256, 0, stream>>>(
        t16, Wt + (size_t)l * HID * HID, bprime + (size_t)l * HID, h16, 1);
  }

  // pooling -> cat[:, 0:128]  (2-phase, bf16 input)
  pool_partial<<<dim3(GG, PCH), 128, 0, stream>>>(h16, batch, part);
  pool_combine<<<GG, 128, 0, stream>>>(part, batch, cat);

  // molecular MLP -> cat[:, 128:256]  (MFMA tail, K-padded weights)
  cvt_molf<<<(GG * 50 + 255) / 256, 256, 0, stream>>>(molf, molf32, flag);
  gemm_tail_mfma<<<dim3(4, 4), 256, 0, stream>>>(molf32, 256, tailW + 0,      256, mlpb0, m0, 256, 1, flag);
  gemm_tail_mfma<<<dim3(4, 4), 256, 0, stream>>>(m0,     256, tailW + 65536,  256, mlpb1, m1, 256, 1, flag);
  gemm_tail_mfma<<<dim3(4, 4), 256, 0, stream>>>(m1,     256, tailW + 131072, 256, mlpb2, m0, 256, 1, flag);
  gemm_tail_mfma<<<dim3(4, 2), 256, 0, stream>>>(m0,     256, tailW + 196608, 256, mlpb3, cat + MOUT, 256, 1, flag);

  // predictor
  gemm_tail_mfma<<<dim3(4, 8), 256, 0, stream>>>(cat, 256, tailW + 229376, 256, predb0, p0, 512, 1, flag);
  gemm_tail_mfma<<<dim3(4, 8), 256, 0, stream>>>(p0,  512, tailW + 360448, 512, predb1, p1, 512, 1, flag);
  final_kernel<<<GG, 64, 0, stream>>>(p1, outW, outb, d_out, flag);
}